// Round 3
// baseline (428.027 us; speedup 1.0000x reference)
//
#include <hip/hip_runtime.h>
#include <hip/hip_bf16.h>

#define D_MODEL 1024
#define N_HEAD  16
#define D_K     64
#define FFN_DIM 4096
#define B_SZ    2
#define L_SEQ   2048
#define ROWS    (B_SZ * L_SEQ)   // 4096
#define PST     68               // Ps/Qs LDS row stride (shorts): proven 0-conflict (R9/R10)

typedef float  floatx4 __attribute__((ext_vector_type(4)));
typedef short  shortx8 __attribute__((ext_vector_type(8)));

__device__ __forceinline__ unsigned short f2bf(float f) {
    unsigned int u = __float_as_uint(f);
    unsigned int rounding = 0x7fffu + ((u >> 16) & 1u);
    return (unsigned short)((u + rounding) >> 16);
}
__device__ __forceinline__ float bf2f(unsigned short u) {
    return __uint_as_float(((unsigned int)u) << 16);
}

// async global->LDS 16B copy; LDS dest is wave-uniform base + lane*16
__device__ __forceinline__ void glds16(const unsigned short* g, unsigned short* l) {
    __builtin_amdgcn_global_load_lds(
        (const __attribute__((address_space(1))) unsigned int*)g,
        (__attribute__((address_space(3))) unsigned int*)l, 16, 0, 0);
}

// ---------- LayerNorm: one block per row of 1024, fp32 in -> bf16 out ----------
__global__ __launch_bounds__(256) void ln_kernel(const float* __restrict__ x,
                                                 const float* __restrict__ g,
                                                 const float* __restrict__ b,
                                                 unsigned short* __restrict__ out) {
    const int row = blockIdx.x;
    const int tid = threadIdx.x;
    const float* xr = x + (size_t)row * D_MODEL;
    float4 xv = *reinterpret_cast<const float4*>(&xr[tid * 4]);
    float v[4] = {xv.x, xv.y, xv.z, xv.w};
    float s = v[0] + v[1] + v[2] + v[3];
    float ss = v[0] * v[0] + v[1] * v[1] + v[2] * v[2] + v[3] * v[3];
    __shared__ float r1[256], r2[256];
    r1[tid] = s; r2[tid] = ss;
    __syncthreads();
    for (int off = 128; off > 0; off >>= 1) {
        if (tid < off) { r1[tid] += r1[tid + off]; r2[tid] += r2[tid + off]; }
        __syncthreads();
    }
    const float mean = r1[0] * (1.0f / D_MODEL);
    const float var  = r2[0] * (1.0f / D_MODEL) - mean * mean;
    const float inv  = rsqrtf(var + 1e-5f);
    unsigned short* orow = out + (size_t)row * D_MODEL;
    ushort4 o;
    o.x = f2bf((v[0] - mean) * inv * g[tid * 4 + 0] + b[tid * 4 + 0]);
    o.y = f2bf((v[1] - mean) * inv * g[tid * 4 + 1] + b[tid * 4 + 1]);
    o.z = f2bf((v[2] - mean) * inv * g[tid * 4 + 2] + b[tid * 4 + 2]);
    o.w = f2bf((v[3] - mean) * inv * g[tid * 4 + 3] + b[tid * 4 + 3]);
    *reinterpret_cast<ushort4*>(&orow[tid * 4]) = o;
}

// ---------- Transpose+cast: W fp32 [K][N] -> Wt bf16 [N][K] ----------
__global__ __launch_bounds__(256) void transpose_cast(const float* __restrict__ W,
                                                      unsigned short* __restrict__ Wt,
                                                      int K, int N) {
    __shared__ unsigned short T[32][33];
    const int t = threadIdx.x;
    const int k0 = blockIdx.y * 32, n0 = blockIdx.x * 32;
    const int kr = t >> 3, nc = (t & 7) * 4;
    float4 w = *reinterpret_cast<const float4*>(&W[(size_t)(k0 + kr) * N + n0 + nc]);
    T[kr][nc + 0] = f2bf(w.x); T[kr][nc + 1] = f2bf(w.y);
    T[kr][nc + 2] = f2bf(w.z); T[kr][nc + 3] = f2bf(w.w);
    __syncthreads();
    const int nr = t >> 3, kc = (t & 7) * 4;
    ushort4 o;
    o.x = T[kc + 0][nr]; o.y = T[kc + 1][nr];
    o.z = T[kc + 2][nr]; o.w = T[kc + 3][nr];
    *reinterpret_cast<ushort4*>(&Wt[(size_t)(n0 + nr) * K + k0 + kc]) = o;
}

// ---------- 4x square (1024x1024) transpose in one dispatch, z selects matrix ----------
__global__ __launch_bounds__(256) void transpose_cast4(const float* s0, const float* s1,
                                                       const float* s2, const float* s3,
                                                       unsigned short* d0, unsigned short* d1,
                                                       unsigned short* d2, unsigned short* d3) {
    const int z = blockIdx.z;
    const float* W = (z == 0) ? s0 : (z == 1) ? s1 : (z == 2) ? s2 : s3;
    unsigned short* Wt = (z == 0) ? d0 : (z == 1) ? d1 : (z == 2) ? d2 : d3;
    __shared__ unsigned short T[32][33];
    const int t = threadIdx.x;
    const int k0 = blockIdx.y * 32, n0 = blockIdx.x * 32;
    const int kr = t >> 3, nc = (t & 7) * 4;
    float4 w = *reinterpret_cast<const float4*>(&W[(size_t)(k0 + kr) * D_MODEL + n0 + nc]);
    T[kr][nc + 0] = f2bf(w.x); T[kr][nc + 1] = f2bf(w.y);
    T[kr][nc + 2] = f2bf(w.z); T[kr][nc + 3] = f2bf(w.w);
    __syncthreads();
    const int nr = t >> 3, kc = (t & 7) * 4;
    ushort4 o;
    o.x = T[kc + 0][nr]; o.y = T[kc + 1][nr];
    o.z = T[kc + 2][nr]; o.w = T[kc + 3][nr];
    *reinterpret_cast<ushort4*>(&Wt[(size_t)(n0 + nr) * D_MODEL + k0 + kc]) = o;
}

// ===== GEMM swizzle: tile = 128 rows x 32 shorts (4x16B chunks/row).
// LDS pos p holds global chunk (row=p>>2, kc=((p&3)-(row>>1))&3).
// Read of (R, kc) at p = R*4 + ((kc+(R>>1))&3) -> bank-group 2-way max (free).

// ---------- MFMA bf16 GEMM (async swizzled staging). A [M][K]; Wt [N][K]. 128x128, BK=32. ----------
template <int SILU, int HAS_RES, int OUT_BF16>
__global__ __launch_bounds__(256) void mfma_gemm(const unsigned short* __restrict__ A,
                                                 const unsigned short* __restrict__ Wt,
                                                 const float* __restrict__ bias,
                                                 const float* __restrict__ res,
                                                 void* __restrict__ outP,
                                                 int M, int N, int K) {
    __shared__ unsigned short As[128 * 32];
    __shared__ unsigned short Bs[128 * 32];
    const int tid  = threadIdx.x;
    const int lane = tid & 63;
    const int wave = tid >> 6;
    const int row0 = blockIdx.y * 128, col0 = blockIdx.x * 128;
    const int wr = (wave >> 1) * 64, wc = (wave & 1) * 64;

    floatx4 acc[4][4] = {};
    const int p0 = tid,       r0s = p0 >> 2, k0s = (((p0 & 3) - (r0s >> 1)) & 3) * 8;
    const int p1 = tid + 256, r1s = p1 >> 2, k1s = (((p1 & 3) - (r1s >> 1)) & 3) * 8;
    const int am = (lane & 15);

    int offA[4], offB[4];
#pragma unroll
    for (int i = 0; i < 4; ++i) {
        const int Ra = wr + i * 16 + am;
        offA[i] = Ra * 32 + (((lane >> 4) + (Ra >> 1)) & 3) * 8;
        const int Rb = wc + i * 16 + am;
        offB[i] = Rb * 32 + (((lane >> 4) + (Rb >> 1)) & 3) * 8;
    }

    for (int kt = 0; kt < K; kt += 32) {
        glds16(A  + (size_t)(row0 + r0s) * K + kt + k0s, &As[p0 * 8]);
        glds16(A  + (size_t)(row0 + r1s) * K + kt + k1s, &As[p1 * 8]);
        glds16(Wt + (size_t)(col0 + r0s) * K + kt + k0s, &Bs[p0 * 8]);
        glds16(Wt + (size_t)(col0 + r1s) * K + kt + k1s, &Bs[p1 * 8]);
        __syncthreads();
        shortx8 af[4], bf[4];
#pragma unroll
        for (int i = 0; i < 4; ++i)
            af[i] = *reinterpret_cast<const shortx8*>(&As[offA[i]]);
#pragma unroll
        for (int j = 0; j < 4; ++j)
            bf[j] = *reinterpret_cast<const shortx8*>(&Bs[offB[j]]);
#pragma unroll
        for (int i = 0; i < 4; ++i)
#pragma unroll
            for (int j = 0; j < 4; ++j)
                acc[i][j] = __builtin_amdgcn_mfma_f32_16x16x32_bf16(af[i], bf[j], acc[i][j], 0, 0, 0);
        __syncthreads();
    }

    const int cq = (lane >> 4) * 4;
    const int cn = lane & 15;
#pragma unroll
    for (int i = 0; i < 4; ++i) {
#pragma unroll
        for (int j = 0; j < 4; ++j) {
            const int n = col0 + wc + j * 16 + cn;
            const float bb = bias[n];
#pragma unroll
            for (int r = 0; r < 4; ++r) {
                const int m = row0 + wr + i * 16 + cq + r;
                float v = acc[i][j][r] + bb;
                if (SILU) v = v / (1.0f + __expf(-v));
                if (HAS_RES) v += res[(size_t)m * N + n];
                if (OUT_BF16) ((unsigned short*)outP)[(size_t)m * N + n] = f2bf(v);
                else          ((float*)outP)[(size_t)m * N + n] = v;
            }
        }
    }
}

// ---------- Fused QKV GEMM: N=3072 over concatenated [3072][1024] weights ----------
__global__ __launch_bounds__(256) void mfma_gemm_qkv(const unsigned short* __restrict__ A,
                                                     const unsigned short* __restrict__ Wt,
                                                     const float* __restrict__ bq,
                                                     const float* __restrict__ bk,
                                                     const float* __restrict__ bv,
                                                     unsigned short* __restrict__ qb,
                                                     unsigned short* __restrict__ kb,
                                                     unsigned short* __restrict__ vtb) {
    const int K = D_MODEL, M = ROWS;
    __shared__ unsigned short As[128 * 32];
    __shared__ unsigned short Bs[128 * 32];
    const int tid  = threadIdx.x;
    const int lane = tid & 63;
    const int wave = tid >> 6;
    const int row0 = blockIdx.y * 128, col0 = blockIdx.x * 128;
    const int wr = (wave >> 1) * 64, wc = (wave & 1) * 64;

    floatx4 acc[4][4] = {};
    const int p0 = tid,       r0s = p0 >> 2, k0s = (((p0 & 3) - (r0s >> 1)) & 3) * 8;
    const int p1 = tid + 256, r1s = p1 >> 2, k1s = (((p1 & 3) - (r1s >> 1)) & 3) * 8;
    const int am = (lane & 15);

    int offA[4], offB[4];
#pragma unroll
    for (int i = 0; i < 4; ++i) {
        const int Ra = wr + i * 16 + am;
        offA[i] = Ra * 32 + (((lane >> 4) + (Ra >> 1)) & 3) * 8;
        const int Rb = wc + i * 16 + am;
        offB[i] = Rb * 32 + (((lane >> 4) + (Rb >> 1)) & 3) * 8;
    }

    for (int kt = 0; kt < K; kt += 32) {
        glds16(A  + (size_t)(row0 + r0s) * K + kt + k0s, &As[p0 * 8]);
        glds16(A  + (size_t)(row0 + r1s) * K + kt + k1s, &As[p1 * 8]);
        glds16(Wt + (size_t)(col0 + r0s) * K + kt + k0s, &Bs[p0 * 8]);
        glds16(Wt + (size_t)(col0 + r1s) * K + kt + k1s, &Bs[p1 * 8]);
        __syncthreads();
        shortx8 af[4], bf[4];
#pragma unroll
        for (int i = 0; i < 4; ++i)
            af[i] = *reinterpret_cast<const shortx8*>(&As[offA[i]]);
#pragma unroll
        for (int j = 0; j < 4; ++j)
            bf[j] = *reinterpret_cast<const shortx8*>(&Bs[offB[j]]);
#pragma unroll
        for (int i = 0; i < 4; ++i)
#pragma unroll
            for (int j = 0; j < 4; ++j)
                acc[i][j] = __builtin_amdgcn_mfma_f32_16x16x32_bf16(af[i], bf[j], acc[i][j], 0, 0, 0);
        __syncthreads();
    }

    const int cq = (lane >> 4) * 4;
    const int cn = lane & 15;
    const int sel = col0 >> 10;                 // 0=Q 1=K 2=V (block-uniform)
    const int nbase = col0 & 1023;
    const float* bias = (sel == 0) ? bq : (sel == 1) ? bk : bv;
    // fold 1/sqrt(Dk) AND log2(e) into Q so attention uses exp2 directly (exact:
    // softmax(S) == softmax-base-2(S*log2e)); 0.125 * 1.4426950408889634
    const float scl = (sel == 0) ? 0.18033688511157292f : 1.0f;
#pragma unroll
    for (int i = 0; i < 4; ++i) {
#pragma unroll
        for (int j = 0; j < 4; ++j) {
            const int n = nbase + wc + j * 16 + cn;
            const float bb = bias[n];
            if (sel == 2) {
                const int m0 = row0 + wr + i * 16 + cq;
                ushort4 o;
                o.x = f2bf(acc[i][j][0] + bb);
                o.y = f2bf(acc[i][j][1] + bb);
                o.z = f2bf(acc[i][j][2] + bb);
                o.w = f2bf(acc[i][j][3] + bb);
                *reinterpret_cast<ushort4*>(&vtb[(size_t)n * M + m0]) = o;
            } else {
                unsigned short* dst = (sel == 0) ? qb : kb;
#pragma unroll
                for (int r = 0; r < 4; ++r) {
                    const int m = row0 + wr + i * 16 + cq + r;
                    dst[(size_t)m * D_MODEL + n] = f2bf((acc[i][j][r] + bb) * scl);
                }
            }
        }
    }
}

// ---------- Split-K GEMM: z = K-slice; raw bf16 partials (contiguous, stride M*N) ----------
__global__ __launch_bounds__(256) void mfma_gemm_splitk(const unsigned short* __restrict__ A,
                                                        const unsigned short* __restrict__ Wt,
                                                        unsigned short* __restrict__ parts,
                                                        int M, int N, int KS) {
    __shared__ unsigned short As[128 * 32];
    __shared__ unsigned short Bs[128 * 32];
    const int tid  = threadIdx.x;
    const int lane = tid & 63;
    const int wave = tid >> 6;
    const int row0 = blockIdx.y * 128, col0 = blockIdx.x * 128;
    const int wr = (wave >> 1) * 64, wc = (wave & 1) * 64;
    const int K = KS * gridDim.z;
    const int kbeg = blockIdx.z * KS;
    unsigned short* outp = parts + (size_t)blockIdx.z * M * N;

    floatx4 acc[4][4] = {};
    const int p0 = tid,       r0s = p0 >> 2, k0s = (((p0 & 3) - (r0s >> 1)) & 3) * 8;
    const int p1 = tid + 256, r1s = p1 >> 2, k1s = (((p1 & 3) - (r1s >> 1)) & 3) * 8;
    const int am = (lane & 15);

    int offA[4], offB[4];
#pragma unroll
    for (int i = 0; i < 4; ++i) {
        const int Ra = wr + i * 16 + am;
        offA[i] = Ra * 32 + (((lane >> 4) + (Ra >> 1)) & 3) * 8;
        const int Rb = wc + i * 16 + am;
        offB[i] = Rb * 32 + (((lane >> 4) + (Rb >> 1)) & 3) * 8;
    }

    for (int kt = kbeg; kt < kbeg + KS; kt += 32) {
        glds16(A  + (size_t)(row0 + r0s) * K + kt + k0s, &As[p0 * 8]);
        glds16(A  + (size_t)(row0 + r1s) * K + kt + k1s, &As[p1 * 8]);
        glds16(Wt + (size_t)(col0 + r0s) * K + kt + k0s, &Bs[p0 * 8]);
        glds16(Wt + (size_t)(col0 + r1s) * K + kt + k1s, &Bs[p1 * 8]);
        __syncthreads();
        shortx8 af[4], bf[4];
#pragma unroll
        for (int i = 0; i < 4; ++i)
            af[i] = *reinterpret_cast<const shortx8*>(&As[offA[i]]);
#pragma unroll
        for (int j = 0; j < 4; ++j)
            bf[j] = *reinterpret_cast<const shortx8*>(&Bs[offB[j]]);
#pragma unroll
        for (int i = 0; i < 4; ++i)
#pragma unroll
            for (int j = 0; j < 4; ++j)
                acc[i][j] = __builtin_amdgcn_mfma_f32_16x16x32_bf16(af[i], bf[j], acc[i][j], 0, 0, 0);
        __syncthreads();
    }

    const int cq = (lane >> 4) * 4;
    const int cn = lane & 15;
#pragma unroll
    for (int i = 0; i < 4; ++i)
#pragma unroll
        for (int j = 0; j < 4; ++j) {
            const int n = col0 + wc + j * 16 + cn;
#pragma unroll
            for (int r = 0; r < 4; ++r) {
                const int m = row0 + wr + i * 16 + cq + r;
                outp[(size_t)m * N + n] = f2bf(acc[i][j][r]);
            }
        }
}

// ---------- combine2: out = p0 + p1 + bias + res ----------
__global__ __launch_bounds__(256) void combine_kernel(const unsigned short* __restrict__ p0,
                                                      const unsigned short* __restrict__ p1,
                                                      const float* __restrict__ bias,
                                                      const float* __restrict__ res,
                                                      float* __restrict__ out) {
    const size_t e0 = ((size_t)blockIdx.x * 256 + threadIdx.x) * 4;
    const int col = (int)(e0 & 1023);
    ushort4 a = *reinterpret_cast<const ushort4*>(&p0[e0]);
    ushort4 b = *reinterpret_cast<const ushort4*>(&p1[e0]);
    float4 r = *reinterpret_cast<const float4*>(&res[e0]);
    float4 o;
    o.x = bf2f(a.x) + bf2f(b.x) + bias[col + 0] + r.x;
    o.y = bf2f(a.y) + bf2f(b.y) + bias[col + 1] + r.y;
    o.z = bf2f(a.z) + bf2f(b.z) + bias[col + 2] + r.z;
    o.w = bf2f(a.w) + bf2f(b.w) + bias[col + 3] + r.w;
    *reinterpret_cast<float4*>(&out[e0]) = o;
}

// ---------- combine4: out = p0 + p1 + p2 + p3 + bias + res ----------
__global__ __launch_bounds__(256) void combine4_kernel(const unsigned short* __restrict__ p0,
                                                       const unsigned short* __restrict__ p1,
                                                       const unsigned short* __restrict__ p2,
                                                       const unsigned short* __restrict__ p3,
                                                       const float* __restrict__ bias,
                                                       const float* __restrict__ res,
                                                       float* __restrict__ out) {
    const size_t e0 = ((size_t)blockIdx.x * 256 + threadIdx.x) * 4;
    const int col = (int)(e0 & 1023);
    ushort4 a = *reinterpret_cast<const ushort4*>(&p0[e0]);
    ushort4 b = *reinterpret_cast<const ushort4*>(&p1[e0]);
    ushort4 c = *reinterpret_cast<const ushort4*>(&p2[e0]);
    ushort4 d = *reinterpret_cast<const ushort4*>(&p3[e0]);
    float4 r = *reinterpret_cast<const float4*>(&res[e0]);
    float4 o;
    o.x = (bf2f(a.x) + bf2f(b.x)) + (bf2f(c.x) + bf2f(d.x)) + bias[col + 0] + r.x;
    o.y = (bf2f(a.y) + bf2f(b.y)) + (bf2f(c.y) + bf2f(d.y)) + bias[col + 1] + r.y;
    o.z = (bf2f(a.z) + bf2f(b.z)) + (bf2f(c.z) + bf2f(d.z)) + bias[col + 2] + r.z;
    o.w = (bf2f(a.w) + bf2f(b.w)) + (bf2f(c.w) + bf2f(d.w)) + bias[col + 3] + r.w;
    *reinterpret_cast<float4*>(&out[e0]) = o;
}

// ---------- MFMA attention: one block per (b, h, 64-q-tile); 4 waves, 16-row strip each.
// R3: reverted to the R0 structure (glds16 staging, single buffers, 34 KB LDS -> 4
// blocks/CU). R1 (LDS dbuf) lost occupancy; R2 (reg-staging) added staging VALU to a
// VALU-bound phase. Only surviving R1/R2 delta: exp2f with log2e folded into Q (exact).
__global__ __launch_bounds__(256) void attn_mfma(const unsigned short* __restrict__ Q,
                                                 const unsigned short* __restrict__ K,
                                                 const unsigned short* __restrict__ Vt,
                                                 const int* __restrict__ mask,
                                                 unsigned short* __restrict__ att) {
    const int tid  = threadIdx.x;
    const int lane = tid & 63;
    const int wave = tid >> 6;
    const int q0 = blockIdx.x * 64;
    const int h  = blockIdx.y;
    const int b  = blockIdx.z;

    __shared__ unsigned short Qs[64 * PST];
    __shared__ unsigned short Ks[64 * 64];
    __shared__ unsigned short Vs[64 * 64];
    __shared__ unsigned short Ps[64 * PST];
    __shared__ int mk[64];

    const int am = lane & 15;
    const int aq = (lane >> 4) * 8;
    const int cq = (lane >> 4) * 4;
    const int cn = lane & 15;

    // stage Q tile (once, via VGPR; padded layout)
    for (int c = tid; c < 512; c += 256) {
        const int r = c >> 3, off = (c & 7) * 8;
        *reinterpret_cast<uint4*>(&Qs[r * PST + off]) =
            *reinterpret_cast<const uint4*>(&Q[(size_t)(b * L_SEQ + q0 + r) * D_MODEL + h * D_K + off]);
    }

    // swizzled staging source precompute: LDS chunk p holds (row=p>>3, c8=((p&7)-row)&7)
    const int p0 = tid,       sr0 = p0 >> 3, sc0 = (((p0 & 7) - sr0) & 7) * 8;
    const int p1 = tid + 256, sr1 = p1 >> 3, sc1 = (((p1 & 7) - sr1) & 7) * 8;
    const unsigned short* K0 = K + (size_t)(b * L_SEQ + sr0) * D_MODEL + h * D_K + sc0;
    const unsigned short* K1 = K + (size_t)(b * L_SEQ + sr1) * D_MODEL + h * D_K + sc1;
    const unsigned short* V0 = Vt + (size_t)(h * D_K + sr0) * ROWS + b * L_SEQ + sc0;
    const unsigned short* V1 = Vt + (size_t)(h * D_K + sr1) * ROWS + b * L_SEQ + sc1;

    // fragment read offsets (loop-invariant): row R = t*16+am, chunk c8 = kt*4 + (lane>>4)
    int offF[2][4];
#pragma unroll
    for (int kt = 0; kt < 2; ++kt)
#pragma unroll
        for (int t = 0; t < 4; ++t) {
            const int R = t * 16 + am;
            offF[kt][t] = R * 64 + (((kt * 4 + (lane >> 4)) + R) & 7) * 8;
        }

    __syncthreads();

    shortx8 aQ[2];
    aQ[0] = *reinterpret_cast<const shortx8*>(&Qs[(wave * 16 + am) * PST + aq]);
    aQ[1] = *reinterpret_cast<const shortx8*>(&Qs[(wave * 16 + am) * PST + 32 + aq]);

    floatx4 oacc[4] = {};
    float lsum[4] = {0.0f, 0.0f, 0.0f, 0.0f};

    for (int j0 = 0; j0 < L_SEQ; j0 += 64) {
        __syncthreads();
        glds16(K0 + (size_t)j0 * D_MODEL, &Ks[p0 * 8]);
        glds16(K1 + (size_t)j0 * D_MODEL, &Ks[p1 * 8]);
        glds16(V0 + j0, &Vs[p0 * 8]);
        glds16(V1 + j0, &Vs[p1 * 8]);
        if (tid < 64) mk[tid] = mask[b * L_SEQ + j0 + tid];
        __syncthreads();

        floatx4 sacc[4] = {};
#pragma unroll
        for (int kt = 0; kt < 2; ++kt)
#pragma unroll
            for (int jt = 0; jt < 4; ++jt) {
                shortx8 bK = *reinterpret_cast<const shortx8*>(&Ks[offF[kt][jt]]);
                sacc[jt] = __builtin_amdgcn_mfma_f32_16x16x32_bf16(aQ[kt], bK, sacc[jt], 0, 0, 0);
            }
        // P = exp2(S) masked (Q pre-scaled by log2e/8); truncate-cast to bf16
#pragma unroll
        for (int jt = 0; jt < 4; ++jt) {
            const int mv = mk[jt * 16 + cn];
#pragma unroll
            for (int r = 0; r < 4; ++r) {
                float p = mv ? exp2f(sacc[jt][r]) : 0.0f;
                lsum[r] += p;
                Ps[(wave * 16 + cq + r) * PST + jt * 16 + cn] =
                    (unsigned short)(__float_as_uint(p) >> 16);
            }
        }
        // O += P x V (wave-private Ps rows)
#pragma unroll
        for (int kt = 0; kt < 2; ++kt) {
            shortx8 aP = *reinterpret_cast<const shortx8*>(&Ps[(wave * 16 + am) * PST + kt * 32 + aq]);
#pragma unroll
            for (int dt = 0; dt < 4; ++dt) {
                shortx8 bV = *reinterpret_cast<const shortx8*>(&Vs[offF[kt][dt]]);
                oacc[dt] = __builtin_amdgcn_mfma_f32_16x16x32_bf16(aP, bV, oacc[dt], 0, 0, 0);
            }
        }
    }

#pragma unroll
    for (int r = 0; r < 4; ++r) {
        float t = lsum[r];
        t += __shfl_xor(t, 1);
        t += __shfl_xor(t, 2);
        t += __shfl_xor(t, 4);
        t += __shfl_xor(t, 8);
        lsum[r] = 1.0f / t;
    }
#pragma unroll
    for (int dt = 0; dt < 4; ++dt)
#pragma unroll
        for (int r = 0; r < 4; ++r) {
            att[(size_t)(b * L_SEQ + q0 + wave * 16 + cq + r) * D_MODEL + h * D_K + dt * 16 + cn] =
                f2bf(oacc[dt][r] * lsum[r]);
        }
}

extern "C" void kernel_launch(void* const* d_in, const int* in_sizes, int n_in,
                              void* d_out, int out_size, void* d_ws, size_t ws_size,
                              hipStream_t stream) {
    const float* x     = (const float*)d_in[0];
    const int*   mask  = (const int*)d_in[1];
    const float* ln1_g = (const float*)d_in[2];
    const float* ln1_b = (const float*)d_in[3];
    const float* Wq    = (const float*)d_in[4];
    const float* bq    = (const float*)d_in[5];
    const float* Wk    = (const float*)d_in[6];
    const float* bk    = (const float*)d_in[7];
    const float* Wv    = (const float*)d_in[8];
    const float* bv    = (const float*)d_in[9];
    const float* Wo    = (const float*)d_in[10];
    const float* bo    = (const float*)d_in[11];
    const float* ln2_g = (const float*)d_in[12];
    const float* ln2_b = (const float*)d_in[13];
    const float* W1    = (const float*)d_in[14];
    const float* b1    = (const float*)d_in[15];
    const float* W2    = (const float*)d_in[16];
    const float* b2    = (const float*)d_in[17];
    float* out = (float*)d_out;

    // ---- workspace map (byte offsets; 72 MB footprint, aliasing verified per stage) ----
    // 0-8    nx (LN1 out) -> ao_p0 -> nx2 (LN2 out) -> ffn2_p0
    // 8-16   free         -> ao_p1                  -> ffn2_p1
    // 16-24  qb           -> W1T                    -> ffn2_p2
    // 24-32  kb           -> free                   -> ffn2_p3
    // 32-40  vtb          -> h[0:8MB]
    // 40-48  attb         -> h[8:16MB]
    // 48-64  free         -> h[16:32MB]
    // 64-70  WqkvT        -> W2T[0:6MB]
    // 70-72  WoT          -> W2T[6:8MB]
    char* base = (char*)d_ws;
    const size_t MB = 1024 * 1024;
    const size_t SZ = (size_t)ROWS * D_MODEL;               // 4M elements

    unsigned short* nx    = (unsigned short*)(base + 0);        // LN out bf16 (8 MB)
    unsigned short* qb    = (unsigned short*)(base + 16 * MB);  // Q bf16 (pre-scaled)
    unsigned short* kb    = (unsigned short*)(base + 24 * MB);  // K bf16
    unsigned short* vtb   = (unsigned short*)(base + 32 * MB);  // V^T bf16
    unsigned short* attb  = (unsigned short*)(base + 40 * MB);  // att bf16
    unsigned short* parts = (unsigned short*)(base + 0);        // splitk partials (ao: 2x8MB; ffn2: 4x8MB)
    unsigned short* h     = (unsigned short*)(base + 32 * MB);  // FFN hidden bf16 (32 MB)
    unsigned short* WqkvT = (unsigned short*)(base + 64 * MB);  // concat [3072][1024]
    unsigned short* WqT   = WqkvT;
    unsigned short* WkT   = WqkvT + (size_t)D_MODEL * D_MODEL;
    unsigned short* WvT   = WkT + (size_t)D_MODEL * D_MODEL;
    unsigned short* WoT   = (unsigned short*)(base + 70 * MB);
    unsigned short* W1T   = (unsigned short*)(base + 16 * MB);  // after qb dead
    unsigned short* W2T   = (unsigned short*)(base + 64 * MB);  // after WqkvT/WoT dead
    unsigned short* nx2   = nx;
    float* x1 = out;                                            // residual stream in d_out

    ln_kernel<<<ROWS, 256, 0, stream>>>(x, ln1_g, ln1_b, nx);

    transpose_cast4<<<dim3(32, 32, 4), 256, 0, stream>>>(Wq, Wk, Wv, Wo, WqT, WkT, WvT, WoT);

    mfma_gemm_qkv<<<dim3(3072 / 128, ROWS / 128), 256, 0, stream>>>(
        nx, WqkvT, bq, bk, bv, qb, kb, vtb);

    attn_mfma<<<dim3(L_SEQ / 64, N_HEAD, B_SZ), 256, 0, stream>>>(qb, kb, vtb, mask, attb);

    transpose_cast<<<dim3(FFN_DIM / 32, D_MODEL / 32), 256, 0, stream>>>(W1, W1T, D_MODEL, FFN_DIM);

    // attn-out projection: split-K x2 (grid 512 = 2 blocks/CU vs 256 = 1) + combine
    mfma_gemm_splitk<<<dim3(D_MODEL / 128, ROWS / 128, 2), 256, 0, stream>>>(
        attb, WoT, parts, ROWS, D_MODEL, D_MODEL / 2);
    combine_kernel<<<(ROWS * D_MODEL) / 1024, 256, 0, stream>>>(
        parts, parts + SZ, bo, x, x1);

    // W2 transpose AFTER attn-out (frees the 64-72 MB weight region for W2T)
    transpose_cast<<<dim3(D_MODEL / 32, FFN_DIM / 32), 256, 0, stream>>>(W2, W2T, FFN_DIM, D_MODEL);

    ln_kernel<<<ROWS, 256, 0, stream>>>(x1, ln2_g, ln2_b, nx2);

    mfma_gemm<1, 0, 1><<<dim3(FFN_DIM / 128, ROWS / 128), 256, 0, stream>>>(
        nx2, W1T, b1, nullptr, h, ROWS, FFN_DIM, D_MODEL);

    // FFN2: split-K x4 (grid 1024 = 4 blocks/CU vs 512 = 2) + combine4
    mfma_gemm_splitk<<<dim3(D_MODEL / 128, ROWS / 128, 4), 256, 0, stream>>>(
        h, W2T, parts, ROWS, D_MODEL, FFN_DIM / 4);
    combine4_kernel<<<(ROWS * D_MODEL) / 1024, 256, 0, stream>>>(
        parts, parts + SZ, parts + 2 * SZ, parts + 3 * SZ, b2, x1, out);
}

// Round 4
// 412.502 us; speedup vs baseline: 1.0376x; 1.0376x over previous
//
#include <hip/hip_runtime.h>
#include <hip/hip_bf16.h>

#define D_MODEL 1024
#define N_HEAD  16
#define D_K     64
#define FFN_DIM 4096
#define B_SZ    2
#define L_SEQ   2048
#define ROWS    (B_SZ * L_SEQ)   // 4096
#define PST     68               // Ps/Qs LDS row stride (shorts): proven 0-conflict (R9/R10)

typedef float  floatx4 __attribute__((ext_vector_type(4)));
typedef short  shortx8 __attribute__((ext_vector_type(8)));

__device__ __forceinline__ unsigned short f2bf(float f) {
    unsigned int u = __float_as_uint(f);
    unsigned int rounding = 0x7fffu + ((u >> 16) & 1u);
    return (unsigned short)((u + rounding) >> 16);
}
__device__ __forceinline__ float bf2f(unsigned short u) {
    return __uint_as_float(((unsigned int)u) << 16);
}

// async global->LDS 16B copy; LDS dest is wave-uniform base + lane*16
__device__ __forceinline__ void glds16(const unsigned short* g, unsigned short* l) {
    __builtin_amdgcn_global_load_lds(
        (const __attribute__((address_space(1))) unsigned int*)g,
        (__attribute__((address_space(3))) unsigned int*)l, 16, 0, 0);
}

// ---------- LayerNorm: one block per row of 1024, fp32 in -> bf16 out ----------
__global__ __launch_bounds__(256) void ln_kernel(const float* __restrict__ x,
                                                 const float* __restrict__ g,
                                                 const float* __restrict__ b,
                                                 unsigned short* __restrict__ out) {
    const int row = blockIdx.x;
    const int tid = threadIdx.x;
    const float* xr = x + (size_t)row * D_MODEL;
    float4 xv = *reinterpret_cast<const float4*>(&xr[tid * 4]);
    float v[4] = {xv.x, xv.y, xv.z, xv.w};
    float s = v[0] + v[1] + v[2] + v[3];
    float ss = v[0] * v[0] + v[1] * v[1] + v[2] * v[2] + v[3] * v[3];
    __shared__ float r1[256], r2[256];
    r1[tid] = s; r2[tid] = ss;
    __syncthreads();
    for (int off = 128; off > 0; off >>= 1) {
        if (tid < off) { r1[tid] += r1[tid + off]; r2[tid] += r2[tid + off]; }
        __syncthreads();
    }
    const float mean = r1[0] * (1.0f / D_MODEL);
    const float var  = r2[0] * (1.0f / D_MODEL) - mean * mean;
    const float inv  = rsqrtf(var + 1e-5f);
    unsigned short* orow = out + (size_t)row * D_MODEL;
    ushort4 o;
    o.x = f2bf((v[0] - mean) * inv * g[tid * 4 + 0] + b[tid * 4 + 0]);
    o.y = f2bf((v[1] - mean) * inv * g[tid * 4 + 1] + b[tid * 4 + 1]);
    o.z = f2bf((v[2] - mean) * inv * g[tid * 4 + 2] + b[tid * 4 + 2]);
    o.w = f2bf((v[3] - mean) * inv * g[tid * 4 + 3] + b[tid * 4 + 3]);
    *reinterpret_cast<ushort4*>(&orow[tid * 4]) = o;
}

// ---------- Transpose+cast: W fp32 [K][N] -> Wt bf16 [N][K] ----------
__global__ __launch_bounds__(256) void transpose_cast(const float* __restrict__ W,
                                                      unsigned short* __restrict__ Wt,
                                                      int K, int N) {
    __shared__ unsigned short T[32][33];
    const int t = threadIdx.x;
    const int k0 = blockIdx.y * 32, n0 = blockIdx.x * 32;
    const int kr = t >> 3, nc = (t & 7) * 4;
    float4 w = *reinterpret_cast<const float4*>(&W[(size_t)(k0 + kr) * N + n0 + nc]);
    T[kr][nc + 0] = f2bf(w.x); T[kr][nc + 1] = f2bf(w.y);
    T[kr][nc + 2] = f2bf(w.z); T[kr][nc + 3] = f2bf(w.w);
    __syncthreads();
    const int nr = t >> 3, kc = (t & 7) * 4;
    ushort4 o;
    o.x = T[kc + 0][nr]; o.y = T[kc + 1][nr];
    o.z = T[kc + 2][nr]; o.w = T[kc + 3][nr];
    *reinterpret_cast<ushort4*>(&Wt[(size_t)(n0 + nr) * K + k0 + kc]) = o;
}

// ---------- 4x square (1024x1024) transpose in one dispatch, z selects matrix ----------
__global__ __launch_bounds__(256) void transpose_cast4(const float* s0, const float* s1,
                                                       const float* s2, const float* s3,
                                                       unsigned short* d0, unsigned short* d1,
                                                       unsigned short* d2, unsigned short* d3) {
    const int z = blockIdx.z;
    const float* W = (z == 0) ? s0 : (z == 1) ? s1 : (z == 2) ? s2 : s3;
    unsigned short* Wt = (z == 0) ? d0 : (z == 1) ? d1 : (z == 2) ? d2 : d3;
    __shared__ unsigned short T[32][33];
    const int t = threadIdx.x;
    const int k0 = blockIdx.y * 32, n0 = blockIdx.x * 32;
    const int kr = t >> 3, nc = (t & 7) * 4;
    float4 w = *reinterpret_cast<const float4*>(&W[(size_t)(k0 + kr) * D_MODEL + n0 + nc]);
    T[kr][nc + 0] = f2bf(w.x); T[kr][nc + 1] = f2bf(w.y);
    T[kr][nc + 2] = f2bf(w.z); T[kr][nc + 3] = f2bf(w.w);
    __syncthreads();
    const int nr = t >> 3, kc = (t & 7) * 4;
    ushort4 o;
    o.x = T[kc + 0][nr]; o.y = T[kc + 1][nr];
    o.z = T[kc + 2][nr]; o.w = T[kc + 3][nr];
    *reinterpret_cast<ushort4*>(&Wt[(size_t)(n0 + nr) * D_MODEL + k0 + kc]) = o;
}

// ===== GEMM swizzle: tile = 128 rows x 32 shorts (4x16B chunks/row).
// LDS pos p holds global chunk (row=p>>2, kc=((p&3)-(row>>1))&3).
// Read of (R, kc) at p = R*4 + ((kc+(R>>1))&3) -> bank-group 2-way max (free).

// ---------- MFMA bf16 GEMM (async swizzled staging). A [M][K]; Wt [N][K]. 128x128, BK=32. ----------
template <int SILU, int HAS_RES, int OUT_BF16>
__global__ __launch_bounds__(256) void mfma_gemm(const unsigned short* __restrict__ A,
                                                 const unsigned short* __restrict__ Wt,
                                                 const float* __restrict__ bias,
                                                 const float* __restrict__ res,
                                                 void* __restrict__ outP,
                                                 int M, int N, int K) {
    __shared__ unsigned short As[128 * 32];
    __shared__ unsigned short Bs[128 * 32];
    const int tid  = threadIdx.x;
    const int lane = tid & 63;
    const int wave = tid >> 6;
    const int row0 = blockIdx.y * 128, col0 = blockIdx.x * 128;
    const int wr = (wave >> 1) * 64, wc = (wave & 1) * 64;

    floatx4 acc[4][4] = {};
    const int p0 = tid,       r0s = p0 >> 2, k0s = (((p0 & 3) - (r0s >> 1)) & 3) * 8;
    const int p1 = tid + 256, r1s = p1 >> 2, k1s = (((p1 & 3) - (r1s >> 1)) & 3) * 8;
    const int am = (lane & 15);

    int offA[4], offB[4];
#pragma unroll
    for (int i = 0; i < 4; ++i) {
        const int Ra = wr + i * 16 + am;
        offA[i] = Ra * 32 + (((lane >> 4) + (Ra >> 1)) & 3) * 8;
        const int Rb = wc + i * 16 + am;
        offB[i] = Rb * 32 + (((lane >> 4) + (Rb >> 1)) & 3) * 8;
    }

    for (int kt = 0; kt < K; kt += 32) {
        glds16(A  + (size_t)(row0 + r0s) * K + kt + k0s, &As[p0 * 8]);
        glds16(A  + (size_t)(row0 + r1s) * K + kt + k1s, &As[p1 * 8]);
        glds16(Wt + (size_t)(col0 + r0s) * K + kt + k0s, &Bs[p0 * 8]);
        glds16(Wt + (size_t)(col0 + r1s) * K + kt + k1s, &Bs[p1 * 8]);
        __syncthreads();
        shortx8 af[4], bf[4];
#pragma unroll
        for (int i = 0; i < 4; ++i)
            af[i] = *reinterpret_cast<const shortx8*>(&As[offA[i]]);
#pragma unroll
        for (int j = 0; j < 4; ++j)
            bf[j] = *reinterpret_cast<const shortx8*>(&Bs[offB[j]]);
#pragma unroll
        for (int i = 0; i < 4; ++i)
#pragma unroll
            for (int j = 0; j < 4; ++j)
                acc[i][j] = __builtin_amdgcn_mfma_f32_16x16x32_bf16(af[i], bf[j], acc[i][j], 0, 0, 0);
        __syncthreads();
    }

    const int cq = (lane >> 4) * 4;
    const int cn = lane & 15;
#pragma unroll
    for (int i = 0; i < 4; ++i) {
#pragma unroll
        for (int j = 0; j < 4; ++j) {
            const int n = col0 + wc + j * 16 + cn;
            const float bb = bias[n];
#pragma unroll
            for (int r = 0; r < 4; ++r) {
                const int m = row0 + wr + i * 16 + cq + r;
                float v = acc[i][j][r] + bb;
                if (SILU) v = v / (1.0f + __expf(-v));
                if (HAS_RES) v += res[(size_t)m * N + n];
                if (OUT_BF16) ((unsigned short*)outP)[(size_t)m * N + n] = f2bf(v);
                else          ((float*)outP)[(size_t)m * N + n] = v;
            }
        }
    }
}

// ---------- Fused QKV GEMM: N=3072 over concatenated [3072][1024] weights ----------
__global__ __launch_bounds__(256) void mfma_gemm_qkv(const unsigned short* __restrict__ A,
                                                     const unsigned short* __restrict__ Wt,
                                                     const float* __restrict__ bq,
                                                     const float* __restrict__ bk,
                                                     const float* __restrict__ bv,
                                                     unsigned short* __restrict__ qb,
                                                     unsigned short* __restrict__ kb,
                                                     unsigned short* __restrict__ vtb) {
    const int K = D_MODEL, M = ROWS;
    __shared__ unsigned short As[128 * 32];
    __shared__ unsigned short Bs[128 * 32];
    const int tid  = threadIdx.x;
    const int lane = tid & 63;
    const int wave = tid >> 6;
    const int row0 = blockIdx.y * 128, col0 = blockIdx.x * 128;
    const int wr = (wave >> 1) * 64, wc = (wave & 1) * 64;

    floatx4 acc[4][4] = {};
    const int p0 = tid,       r0s = p0 >> 2, k0s = (((p0 & 3) - (r0s >> 1)) & 3) * 8;
    const int p1 = tid + 256, r1s = p1 >> 2, k1s = (((p1 & 3) - (r1s >> 1)) & 3) * 8;
    const int am = (lane & 15);

    int offA[4], offB[4];
#pragma unroll
    for (int i = 0; i < 4; ++i) {
        const int Ra = wr + i * 16 + am;
        offA[i] = Ra * 32 + (((lane >> 4) + (Ra >> 1)) & 3) * 8;
        const int Rb = wc + i * 16 + am;
        offB[i] = Rb * 32 + (((lane >> 4) + (Rb >> 1)) & 3) * 8;
    }

    for (int kt = 0; kt < K; kt += 32) {
        glds16(A  + (size_t)(row0 + r0s) * K + kt + k0s, &As[p0 * 8]);
        glds16(A  + (size_t)(row0 + r1s) * K + kt + k1s, &As[p1 * 8]);
        glds16(Wt + (size_t)(col0 + r0s) * K + kt + k0s, &Bs[p0 * 8]);
        glds16(Wt + (size_t)(col0 + r1s) * K + kt + k1s, &Bs[p1 * 8]);
        __syncthreads();
        shortx8 af[4], bf[4];
#pragma unroll
        for (int i = 0; i < 4; ++i)
            af[i] = *reinterpret_cast<const shortx8*>(&As[offA[i]]);
#pragma unroll
        for (int j = 0; j < 4; ++j)
            bf[j] = *reinterpret_cast<const shortx8*>(&Bs[offB[j]]);
#pragma unroll
        for (int i = 0; i < 4; ++i)
#pragma unroll
            for (int j = 0; j < 4; ++j)
                acc[i][j] = __builtin_amdgcn_mfma_f32_16x16x32_bf16(af[i], bf[j], acc[i][j], 0, 0, 0);
        __syncthreads();
    }

    const int cq = (lane >> 4) * 4;
    const int cn = lane & 15;
    const int sel = col0 >> 10;                 // 0=Q 1=K 2=V (block-uniform)
    const int nbase = col0 & 1023;
    const float* bias = (sel == 0) ? bq : (sel == 1) ? bk : bv;
    // fold 1/sqrt(Dk) AND log2(e) into Q so attention uses a single v_exp_f32
    // (exact: softmax(S) == softmax-base-2(S*log2e)); 0.125 * 1.4426950408889634
    const float scl = (sel == 0) ? 0.18033688511157292f : 1.0f;
#pragma unroll
    for (int i = 0; i < 4; ++i) {
#pragma unroll
        for (int j = 0; j < 4; ++j) {
            const int n = nbase + wc + j * 16 + cn;
            const float bb = bias[n];
            if (sel == 2) {
                const int m0 = row0 + wr + i * 16 + cq;
                ushort4 o;
                o.x = f2bf(acc[i][j][0] + bb);
                o.y = f2bf(acc[i][j][1] + bb);
                o.z = f2bf(acc[i][j][2] + bb);
                o.w = f2bf(acc[i][j][3] + bb);
                *reinterpret_cast<ushort4*>(&vtb[(size_t)n * M + m0]) = o;
            } else {
                unsigned short* dst = (sel == 0) ? qb : kb;
#pragma unroll
                for (int r = 0; r < 4; ++r) {
                    const int m = row0 + wr + i * 16 + cq + r;
                    dst[(size_t)m * D_MODEL + n] = f2bf((acc[i][j][r] + bb) * scl);
                }
            }
        }
    }
}

// ---------- Split-K GEMM: z = K-slice; raw bf16 partials ----------
__global__ __launch_bounds__(256) void mfma_gemm_splitk(const unsigned short* __restrict__ A,
                                                        const unsigned short* __restrict__ Wt,
                                                        unsigned short* __restrict__ parts,
                                                        int M, int N, int KS) {
    __shared__ unsigned short As[128 * 32];
    __shared__ unsigned short Bs[128 * 32];
    const int tid  = threadIdx.x;
    const int lane = tid & 63;
    const int wave = tid >> 6;
    const int row0 = blockIdx.y * 128, col0 = blockIdx.x * 128;
    const int wr = (wave >> 1) * 64, wc = (wave & 1) * 64;
    const int K = KS * gridDim.z;
    const int kbeg = blockIdx.z * KS;
    unsigned short* outp = parts + (size_t)blockIdx.z * M * N;

    floatx4 acc[4][4] = {};
    const int p0 = tid,       r0s = p0 >> 2, k0s = (((p0 & 3) - (r0s >> 1)) & 3) * 8;
    const int p1 = tid + 256, r1s = p1 >> 2, k1s = (((p1 & 3) - (r1s >> 1)) & 3) * 8;
    const int am = (lane & 15);

    int offA[4], offB[4];
#pragma unroll
    for (int i = 0; i < 4; ++i) {
        const int Ra = wr + i * 16 + am;
        offA[i] = Ra * 32 + (((lane >> 4) + (Ra >> 1)) & 3) * 8;
        const int Rb = wc + i * 16 + am;
        offB[i] = Rb * 32 + (((lane >> 4) + (Rb >> 1)) & 3) * 8;
    }

    for (int kt = kbeg; kt < kbeg + KS; kt += 32) {
        glds16(A  + (size_t)(row0 + r0s) * K + kt + k0s, &As[p0 * 8]);
        glds16(A  + (size_t)(row0 + r1s) * K + kt + k1s, &As[p1 * 8]);
        glds16(Wt + (size_t)(col0 + r0s) * K + kt + k0s, &Bs[p0 * 8]);
        glds16(Wt + (size_t)(col0 + r1s) * K + kt + k1s, &Bs[p1 * 8]);
        __syncthreads();
        shortx8 af[4], bf[4];
#pragma unroll
        for (int i = 0; i < 4; ++i)
            af[i] = *reinterpret_cast<const shortx8*>(&As[offA[i]]);
#pragma unroll
        for (int j = 0; j < 4; ++j)
            bf[j] = *reinterpret_cast<const shortx8*>(&Bs[offB[j]]);
#pragma unroll
        for (int i = 0; i < 4; ++i)
#pragma unroll
            for (int j = 0; j < 4; ++j)
                acc[i][j] = __builtin_amdgcn_mfma_f32_16x16x32_bf16(af[i], bf[j], acc[i][j], 0, 0, 0);
        __syncthreads();
    }

    const int cq = (lane >> 4) * 4;
    const int cn = lane & 15;
#pragma unroll
    for (int i = 0; i < 4; ++i)
#pragma unroll
        for (int j = 0; j < 4; ++j) {
            const int n = col0 + wc + j * 16 + cn;
#pragma unroll
            for (int r = 0; r < 4; ++r) {
                const int m = row0 + wr + i * 16 + cq + r;
                outp[(size_t)m * N + n] = f2bf(acc[i][j][r]);
            }
        }
}

// ---------- combine: out = p0 + p1 + bias + res ----------
__global__ __launch_bounds__(256) void combine_kernel(const unsigned short* __restrict__ p0,
                                                      const unsigned short* __restrict__ p1,
                                                      const float* __restrict__ bias,
                                                      const float* __restrict__ res,
                                                      float* __restrict__ out) {
    const size_t e0 = ((size_t)blockIdx.x * 256 + threadIdx.x) * 4;
    const int col = (int)(e0 & 1023);
    ushort4 a = *reinterpret_cast<const ushort4*>(&p0[e0]);
    ushort4 b = *reinterpret_cast<const ushort4*>(&p1[e0]);
    float4 r = *reinterpret_cast<const float4*>(&res[e0]);
    float4 o;
    o.x = bf2f(a.x) + bf2f(b.x) + bias[col + 0] + r.x;
    o.y = bf2f(a.y) + bf2f(b.y) + bias[col + 1] + r.y;
    o.z = bf2f(a.z) + bf2f(b.z) + bias[col + 2] + r.z;
    o.w = bf2f(a.w) + bf2f(b.w) + bias[col + 3] + r.w;
    *reinterpret_cast<float4*>(&out[e0]) = o;
}

// ---------- MFMA attention: one block per (b, h, 64-q-tile); 4 waves, 16-row strip each.
// R4: exact R0 structure (glds16 staging, single buffers, 34 KB LDS -> 4 blocks/CU).
// Lessons: R1 LDS-dbuf lost occupancy (4->3 blocks/CU); R2 reg-staging added VALU to a
// VALU-heavy phase; R3 exp2f is the slow IEEE ocml path (VALU 39->53%). Only delta vs
// R0: single-instruction exp2 via __builtin_amdgcn_exp2f, scale folded into Q upstream.
__global__ __launch_bounds__(256) void attn_mfma(const unsigned short* __restrict__ Q,
                                                 const unsigned short* __restrict__ K,
                                                 const unsigned short* __restrict__ Vt,
                                                 const int* __restrict__ mask,
                                                 unsigned short* __restrict__ att) {
    const int tid  = threadIdx.x;
    const int lane = tid & 63;
    const int wave = tid >> 6;
    const int q0 = blockIdx.x * 64;
    const int h  = blockIdx.y;
    const int b  = blockIdx.z;

    __shared__ unsigned short Qs[64 * PST];
    __shared__ unsigned short Ks[64 * 64];
    __shared__ unsigned short Vs[64 * 64];
    __shared__ unsigned short Ps[64 * PST];
    __shared__ int mk[64];

    const int am = lane & 15;
    const int aq = (lane >> 4) * 8;
    const int cq = (lane >> 4) * 4;
    const int cn = lane & 15;

    // stage Q tile (once, via VGPR; padded layout)
    for (int c = tid; c < 512; c += 256) {
        const int r = c >> 3, off = (c & 7) * 8;
        *reinterpret_cast<uint4*>(&Qs[r * PST + off]) =
            *reinterpret_cast<const uint4*>(&Q[(size_t)(b * L_SEQ + q0 + r) * D_MODEL + h * D_K + off]);
    }

    // swizzled staging source precompute: LDS chunk p holds (row=p>>3, c8=((p&7)-row)&7)
    const int p0 = tid,       sr0 = p0 >> 3, sc0 = (((p0 & 7) - sr0) & 7) * 8;
    const int p1 = tid + 256, sr1 = p1 >> 3, sc1 = (((p1 & 7) - sr1) & 7) * 8;
    const unsigned short* K0 = K + (size_t)(b * L_SEQ + sr0) * D_MODEL + h * D_K + sc0;
    const unsigned short* K1 = K + (size_t)(b * L_SEQ + sr1) * D_MODEL + h * D_K + sc1;
    const unsigned short* V0 = Vt + (size_t)(h * D_K + sr0) * ROWS + b * L_SEQ + sc0;
    const unsigned short* V1 = Vt + (size_t)(h * D_K + sr1) * ROWS + b * L_SEQ + sc1;

    // fragment read offsets (loop-invariant): row R = t*16+am, chunk c8 = kt*4 + (lane>>4)
    int offF[2][4];
#pragma unroll
    for (int kt = 0; kt < 2; ++kt)
#pragma unroll
        for (int t = 0; t < 4; ++t) {
            const int R = t * 16 + am;
            offF[kt][t] = R * 64 + (((kt * 4 + (lane >> 4)) + R) & 7) * 8;
        }

    __syncthreads();

    shortx8 aQ[2];
    aQ[0] = *reinterpret_cast<const shortx8*>(&Qs[(wave * 16 + am) * PST + aq]);
    aQ[1] = *reinterpret_cast<const shortx8*>(&Qs[(wave * 16 + am) * PST + 32 + aq]);

    floatx4 oacc[4] = {};
    float lsum[4] = {0.0f, 0.0f, 0.0f, 0.0f};

    for (int j0 = 0; j0 < L_SEQ; j0 += 64) {
        __syncthreads();
        glds16(K0 + (size_t)j0 * D_MODEL, &Ks[p0 * 8]);
        glds16(K1 + (size_t)j0 * D_MODEL, &Ks[p1 * 8]);
        glds16(V0 + j0, &Vs[p0 * 8]);
        glds16(V1 + j0, &Vs[p1 * 8]);
        if (tid < 64) mk[tid] = mask[b * L_SEQ + j0 + tid];
        __syncthreads();

        floatx4 sacc[4] = {};
#pragma unroll
        for (int kt = 0; kt < 2; ++kt)
#pragma unroll
            for (int jt = 0; jt < 4; ++jt) {
                shortx8 bK = *reinterpret_cast<const shortx8*>(&Ks[offF[kt][jt]]);
                sacc[jt] = __builtin_amdgcn_mfma_f32_16x16x32_bf16(aQ[kt], bK, sacc[jt], 0, 0, 0);
            }
        // P = exp2(S) masked (Q pre-scaled by log2e/8 -> single v_exp_f32);
        // truncate-cast to bf16
#pragma unroll
        for (int jt = 0; jt < 4; ++jt) {
            const int mv = mk[jt * 16 + cn];
#pragma unroll
            for (int r = 0; r < 4; ++r) {
                float p = mv ? __builtin_amdgcn_exp2f(sacc[jt][r]) : 0.0f;
                lsum[r] += p;
                Ps[(wave * 16 + cq + r) * PST + jt * 16 + cn] =
                    (unsigned short)(__float_as_uint(p) >> 16);
            }
        }
        // O += P x V (wave-private Ps rows)
#pragma unroll
        for (int kt = 0; kt < 2; ++kt) {
            shortx8 aP = *reinterpret_cast<const shortx8*>(&Ps[(wave * 16 + am) * PST + kt * 32 + aq]);
#pragma unroll
            for (int dt = 0; dt < 4; ++dt) {
                shortx8 bV = *reinterpret_cast<const shortx8*>(&Vs[offF[kt][dt]]);
                oacc[dt] = __builtin_amdgcn_mfma_f32_16x16x32_bf16(aP, bV, oacc[dt], 0, 0, 0);
            }
        }
    }

#pragma unroll
    for (int r = 0; r < 4; ++r) {
        float t = lsum[r];
        t += __shfl_xor(t, 1);
        t += __shfl_xor(t, 2);
        t += __shfl_xor(t, 4);
        t += __shfl_xor(t, 8);
        lsum[r] = 1.0f / t;
    }
#pragma unroll
    for (int dt = 0; dt < 4; ++dt)
#pragma unroll
        for (int r = 0; r < 4; ++r) {
            att[(size_t)(b * L_SEQ + q0 + wave * 16 + cq + r) * D_MODEL + h * D_K + dt * 16 + cn] =
                f2bf(oacc[dt][r] * lsum[r]);
        }
}

extern "C" void kernel_launch(void* const* d_in, const int* in_sizes, int n_in,
                              void* d_out, int out_size, void* d_ws, size_t ws_size,
                              hipStream_t stream) {
    const float* x     = (const float*)d_in[0];
    const int*   mask  = (const int*)d_in[1];
    const float* ln1_g = (const float*)d_in[2];
    const float* ln1_b = (const float*)d_in[3];
    const float* Wq    = (const float*)d_in[4];
    const float* bq    = (const float*)d_in[5];
    const float* Wk    = (const float*)d_in[6];
    const float* bk    = (const float*)d_in[7];
    const float* Wv    = (const float*)d_in[8];
    const float* bv    = (const float*)d_in[9];
    const float* Wo    = (const float*)d_in[10];
    const float* bo    = (const float*)d_in[11];
    const float* ln2_g = (const float*)d_in[12];
    const float* ln2_b = (const float*)d_in[13];
    const float* W1    = (const float*)d_in[14];
    const float* b1    = (const float*)d_in[15];
    const float* W2    = (const float*)d_in[16];
    const float* b2    = (const float*)d_in[17];
    float* out = (float*)d_out;

    float* ws = (float*)d_ws;
    const size_t SZ = (size_t)ROWS * D_MODEL;  // 4M elements; fp32 slot = 16 MB

    unsigned short* nx  = (unsigned short*)(ws + 0 * SZ);   // 0-8 MB: LN1/LN2 out bf16
    unsigned short* qb  = (unsigned short*)(ws + 1 * SZ);   // 16-24: Q bf16 (pre-scaled)
    unsigned short* kb  = qb + SZ;                          // 24-32: K bf16
    unsigned short* vtb = (unsigned short*)(ws + 2 * SZ);   // 32-40: V^T bf16
    unsigned short* attb = vtb + SZ;                        // 40-48: att bf16
    float* x1  = out;                                       // residual stream in d_out
    unsigned short* nx2 = nx;                               // slot0 reuse
    unsigned short* h = (unsigned short*)(ws + 2 * SZ);     // 32-64: FFN hidden bf16
    unsigned short* parts = (unsigned short*)(ws + 0 * SZ); // 0-16: FFN2 split-K partials

    unsigned short* WqkvT = (unsigned short*)(ws + 4 * SZ); // 64-70: concat [3072][1024]
    unsigned short* WqT = WqkvT;
    unsigned short* WkT = WqkvT + (size_t)D_MODEL * D_MODEL;
    unsigned short* WvT = WkT + (size_t)D_MODEL * D_MODEL;
    unsigned short* WoT = WvT + (size_t)D_MODEL * D_MODEL;  // 70-72
    unsigned short* W1T = (unsigned short*)(ws + 1 * SZ);   // 16-24 (qb/kb dead after attn)
    unsigned short* W2T = W1T + (size_t)D_MODEL * FFN_DIM;  // 24-32

    ln_kernel<<<ROWS, 256, 0, stream>>>(x, ln1_g, ln1_b, nx);

    transpose_cast4<<<dim3(32, 32, 4), 256, 0, stream>>>(Wq, Wk, Wv, Wo, WqT, WkT, WvT, WoT);

    mfma_gemm_qkv<<<dim3(3072 / 128, ROWS / 128), 256, 0, stream>>>(
        nx, WqkvT, bq, bk, bv, qb, kb, vtb);

    attn_mfma<<<dim3(L_SEQ / 64, N_HEAD, B_SZ), 256, 0, stream>>>(qb, kb, vtb, mask, attb);

    transpose_cast<<<dim3(FFN_DIM / 32, D_MODEL / 32), 256, 0, stream>>>(W1, W1T, D_MODEL, FFN_DIM);
    transpose_cast<<<dim3(D_MODEL / 32, FFN_DIM / 32), 256, 0, stream>>>(W2, W2T, FFN_DIM, D_MODEL);

    mfma_gemm<0, 1, 0><<<dim3(D_MODEL / 128, ROWS / 128), 256, 0, stream>>>(
        attb, WoT, bo, x, x1, ROWS, D_MODEL, D_MODEL);

    ln_kernel<<<ROWS, 256, 0, stream>>>(x1, ln2_g, ln2_b, nx2);

    mfma_gemm<1, 0, 1><<<dim3(FFN_DIM / 128, ROWS / 128), 256, 0, stream>>>(
        nx2, W1T, b1, nullptr, h, ROWS, FFN_DIM, D_MODEL);

    mfma_gemm_splitk<<<dim3(D_MODEL / 128, ROWS / 128, 2), 256, 0, stream>>>(
        h, W2T, parts, ROWS, D_MODEL, FFN_DIM / 2);
    combine_kernel<<<(ROWS * D_MODEL) / 1024, 256, 0, stream>>>(
        parts, parts + SZ, b2, x1, out);
}

// Round 5
// 408.605 us; speedup vs baseline: 1.0475x; 1.0095x over previous
//
#include <hip/hip_runtime.h>
#include <hip/hip_bf16.h>

#define D_MODEL 1024
#define N_HEAD  16
#define D_K     64
#define FFN_DIM 4096
#define B_SZ    2
#define L_SEQ   2048
#define ROWS    (B_SZ * L_SEQ)   // 4096
#define PST     68               // Ps/Qs LDS row stride (shorts): proven 0-conflict (R9/R10)

typedef float  floatx4 __attribute__((ext_vector_type(4)));
typedef short  shortx8 __attribute__((ext_vector_type(8)));

__device__ __forceinline__ unsigned short f2bf(float f) {
    unsigned int u = __float_as_uint(f);
    unsigned int rounding = 0x7fffu + ((u >> 16) & 1u);
    return (unsigned short)((u + rounding) >> 16);
}
__device__ __forceinline__ float bf2f(unsigned short u) {
    return __uint_as_float(((unsigned int)u) << 16);
}

// async global->LDS 16B copy; LDS dest is wave-uniform base + lane*16
__device__ __forceinline__ void glds16(const unsigned short* g, unsigned short* l) {
    __builtin_amdgcn_global_load_lds(
        (const __attribute__((address_space(1))) unsigned int*)g,
        (__attribute__((address_space(3))) unsigned int*)l, 16, 0, 0);
}

// ---------- LayerNorm: one block per row of 1024, fp32 in -> bf16 out ----------
__global__ __launch_bounds__(256) void ln_kernel(const float* __restrict__ x,
                                                 const float* __restrict__ g,
                                                 const float* __restrict__ b,
                                                 unsigned short* __restrict__ out) {
    const int row = blockIdx.x;
    const int tid = threadIdx.x;
    const float* xr = x + (size_t)row * D_MODEL;
    float4 xv = *reinterpret_cast<const float4*>(&xr[tid * 4]);
    float v[4] = {xv.x, xv.y, xv.z, xv.w};
    float s = v[0] + v[1] + v[2] + v[3];
    float ss = v[0] * v[0] + v[1] * v[1] + v[2] * v[2] + v[3] * v[3];
    __shared__ float r1[256], r2[256];
    r1[tid] = s; r2[tid] = ss;
    __syncthreads();
    for (int off = 128; off > 0; off >>= 1) {
        if (tid < off) { r1[tid] += r1[tid + off]; r2[tid] += r2[tid + off]; }
        __syncthreads();
    }
    const float mean = r1[0] * (1.0f / D_MODEL);
    const float var  = r2[0] * (1.0f / D_MODEL) - mean * mean;
    const float inv  = rsqrtf(var + 1e-5f);
    unsigned short* orow = out + (size_t)row * D_MODEL;
    ushort4 o;
    o.x = f2bf((v[0] - mean) * inv * g[tid * 4 + 0] + b[tid * 4 + 0]);
    o.y = f2bf((v[1] - mean) * inv * g[tid * 4 + 1] + b[tid * 4 + 1]);
    o.z = f2bf((v[2] - mean) * inv * g[tid * 4 + 2] + b[tid * 4 + 2]);
    o.w = f2bf((v[3] - mean) * inv * g[tid * 4 + 3] + b[tid * 4 + 3]);
    *reinterpret_cast<ushort4*>(&orow[tid * 4]) = o;
}

// ---------- Transpose+cast: W fp32 [K][N] -> Wt bf16 [N][K] ----------
__global__ __launch_bounds__(256) void transpose_cast(const float* __restrict__ W,
                                                      unsigned short* __restrict__ Wt,
                                                      int K, int N) {
    __shared__ unsigned short T[32][33];
    const int t = threadIdx.x;
    const int k0 = blockIdx.y * 32, n0 = blockIdx.x * 32;
    const int kr = t >> 3, nc = (t & 7) * 4;
    float4 w = *reinterpret_cast<const float4*>(&W[(size_t)(k0 + kr) * N + n0 + nc]);
    T[kr][nc + 0] = f2bf(w.x); T[kr][nc + 1] = f2bf(w.y);
    T[kr][nc + 2] = f2bf(w.z); T[kr][nc + 3] = f2bf(w.w);
    __syncthreads();
    const int nr = t >> 3, kc = (t & 7) * 4;
    ushort4 o;
    o.x = T[kc + 0][nr]; o.y = T[kc + 1][nr];
    o.z = T[kc + 2][nr]; o.w = T[kc + 3][nr];
    *reinterpret_cast<ushort4*>(&Wt[(size_t)(n0 + nr) * K + k0 + kc]) = o;
}

// ---------- 4x square (1024x1024) transpose in one dispatch, z selects matrix ----------
__global__ __launch_bounds__(256) void transpose_cast4(const float* s0, const float* s1,
                                                       const float* s2, const float* s3,
                                                       unsigned short* d0, unsigned short* d1,
                                                       unsigned short* d2, unsigned short* d3) {
    const int z = blockIdx.z;
    const float* W = (z == 0) ? s0 : (z == 1) ? s1 : (z == 2) ? s2 : s3;
    unsigned short* Wt = (z == 0) ? d0 : (z == 1) ? d1 : (z == 2) ? d2 : d3;
    __shared__ unsigned short T[32][33];
    const int t = threadIdx.x;
    const int k0 = blockIdx.y * 32, n0 = blockIdx.x * 32;
    const int kr = t >> 3, nc = (t & 7) * 4;
    float4 w = *reinterpret_cast<const float4*>(&W[(size_t)(k0 + kr) * D_MODEL + n0 + nc]);
    T[kr][nc + 0] = f2bf(w.x); T[kr][nc + 1] = f2bf(w.y);
    T[kr][nc + 2] = f2bf(w.z); T[kr][nc + 3] = f2bf(w.w);
    __syncthreads();
    const int nr = t >> 3, kc = (t & 7) * 4;
    ushort4 o;
    o.x = T[kc + 0][nr]; o.y = T[kc + 1][nr];
    o.z = T[kc + 2][nr]; o.w = T[kc + 3][nr];
    *reinterpret_cast<ushort4*>(&Wt[(size_t)(n0 + nr) * D_MODEL + k0 + kc]) = o;
}

// ===== GEMM swizzle: tile = 128 rows x 32 shorts (4x16B chunks/row).
// LDS pos p holds global chunk (row=p>>2, kc=((p&3)-(row>>1))&3).
// Read of (R, kc) at p = R*4 + ((kc+(R>>1))&3) -> bank-group 2-way max (free).

// ---------- MFMA bf16 GEMM (async swizzled staging). A [M][K]; Wt [N][K]. 128x128, BK=32. ----------
template <int SILU, int HAS_RES, int OUT_BF16>
__global__ __launch_bounds__(256) void mfma_gemm(const unsigned short* __restrict__ A,
                                                 const unsigned short* __restrict__ Wt,
                                                 const float* __restrict__ bias,
                                                 const float* __restrict__ res,
                                                 void* __restrict__ outP,
                                                 int M, int N, int K) {
    __shared__ unsigned short As[128 * 32];
    __shared__ unsigned short Bs[128 * 32];
    const int tid  = threadIdx.x;
    const int lane = tid & 63;
    const int wave = tid >> 6;
    const int row0 = blockIdx.y * 128, col0 = blockIdx.x * 128;
    const int wr = (wave >> 1) * 64, wc = (wave & 1) * 64;

    floatx4 acc[4][4] = {};
    const int p0 = tid,       r0s = p0 >> 2, k0s = (((p0 & 3) - (r0s >> 1)) & 3) * 8;
    const int p1 = tid + 256, r1s = p1 >> 2, k1s = (((p1 & 3) - (r1s >> 1)) & 3) * 8;
    const int am = (lane & 15);

    int offA[4], offB[4];
#pragma unroll
    for (int i = 0; i < 4; ++i) {
        const int Ra = wr + i * 16 + am;
        offA[i] = Ra * 32 + (((lane >> 4) + (Ra >> 1)) & 3) * 8;
        const int Rb = wc + i * 16 + am;
        offB[i] = Rb * 32 + (((lane >> 4) + (Rb >> 1)) & 3) * 8;
    }

    for (int kt = 0; kt < K; kt += 32) {
        glds16(A  + (size_t)(row0 + r0s) * K + kt + k0s, &As[p0 * 8]);
        glds16(A  + (size_t)(row0 + r1s) * K + kt + k1s, &As[p1 * 8]);
        glds16(Wt + (size_t)(col0 + r0s) * K + kt + k0s, &Bs[p0 * 8]);
        glds16(Wt + (size_t)(col0 + r1s) * K + kt + k1s, &Bs[p1 * 8]);
        __syncthreads();
        shortx8 af[4], bf[4];
#pragma unroll
        for (int i = 0; i < 4; ++i)
            af[i] = *reinterpret_cast<const shortx8*>(&As[offA[i]]);
#pragma unroll
        for (int j = 0; j < 4; ++j)
            bf[j] = *reinterpret_cast<const shortx8*>(&Bs[offB[j]]);
#pragma unroll
        for (int i = 0; i < 4; ++i)
#pragma unroll
            for (int j = 0; j < 4; ++j)
                acc[i][j] = __builtin_amdgcn_mfma_f32_16x16x32_bf16(af[i], bf[j], acc[i][j], 0, 0, 0);
        __syncthreads();
    }

    const int cq = (lane >> 4) * 4;
    const int cn = lane & 15;
#pragma unroll
    for (int i = 0; i < 4; ++i) {
#pragma unroll
        for (int j = 0; j < 4; ++j) {
            const int n = col0 + wc + j * 16 + cn;
            const float bb = bias[n];
#pragma unroll
            for (int r = 0; r < 4; ++r) {
                const int m = row0 + wr + i * 16 + cq + r;
                float v = acc[i][j][r] + bb;
                if (SILU) v = v / (1.0f + __expf(-v));
                if (HAS_RES) v += res[(size_t)m * N + n];
                if (OUT_BF16) ((unsigned short*)outP)[(size_t)m * N + n] = f2bf(v);
                else          ((float*)outP)[(size_t)m * N + n] = v;
            }
        }
    }
}

// ---------- Fused QKV GEMM: N=3072 over concatenated [3072][1024] weights ----------
__global__ __launch_bounds__(256) void mfma_gemm_qkv(const unsigned short* __restrict__ A,
                                                     const unsigned short* __restrict__ Wt,
                                                     const float* __restrict__ bq,
                                                     const float* __restrict__ bk,
                                                     const float* __restrict__ bv,
                                                     unsigned short* __restrict__ qb,
                                                     unsigned short* __restrict__ kb,
                                                     unsigned short* __restrict__ vtb) {
    const int K = D_MODEL, M = ROWS;
    __shared__ unsigned short As[128 * 32];
    __shared__ unsigned short Bs[128 * 32];
    const int tid  = threadIdx.x;
    const int lane = tid & 63;
    const int wave = tid >> 6;
    const int row0 = blockIdx.y * 128, col0 = blockIdx.x * 128;
    const int wr = (wave >> 1) * 64, wc = (wave & 1) * 64;

    floatx4 acc[4][4] = {};
    const int p0 = tid,       r0s = p0 >> 2, k0s = (((p0 & 3) - (r0s >> 1)) & 3) * 8;
    const int p1 = tid + 256, r1s = p1 >> 2, k1s = (((p1 & 3) - (r1s >> 1)) & 3) * 8;
    const int am = (lane & 15);

    int offA[4], offB[4];
#pragma unroll
    for (int i = 0; i < 4; ++i) {
        const int Ra = wr + i * 16 + am;
        offA[i] = Ra * 32 + (((lane >> 4) + (Ra >> 1)) & 3) * 8;
        const int Rb = wc + i * 16 + am;
        offB[i] = Rb * 32 + (((lane >> 4) + (Rb >> 1)) & 3) * 8;
    }

    for (int kt = 0; kt < K; kt += 32) {
        glds16(A  + (size_t)(row0 + r0s) * K + kt + k0s, &As[p0 * 8]);
        glds16(A  + (size_t)(row0 + r1s) * K + kt + k1s, &As[p1 * 8]);
        glds16(Wt + (size_t)(col0 + r0s) * K + kt + k0s, &Bs[p0 * 8]);
        glds16(Wt + (size_t)(col0 + r1s) * K + kt + k1s, &Bs[p1 * 8]);
        __syncthreads();
        shortx8 af[4], bf[4];
#pragma unroll
        for (int i = 0; i < 4; ++i)
            af[i] = *reinterpret_cast<const shortx8*>(&As[offA[i]]);
#pragma unroll
        for (int j = 0; j < 4; ++j)
            bf[j] = *reinterpret_cast<const shortx8*>(&Bs[offB[j]]);
#pragma unroll
        for (int i = 0; i < 4; ++i)
#pragma unroll
            for (int j = 0; j < 4; ++j)
                acc[i][j] = __builtin_amdgcn_mfma_f32_16x16x32_bf16(af[i], bf[j], acc[i][j], 0, 0, 0);
        __syncthreads();
    }

    const int cq = (lane >> 4) * 4;
    const int cn = lane & 15;
    const int sel = col0 >> 10;                 // 0=Q 1=K 2=V (block-uniform)
    const int nbase = col0 & 1023;
    const float* bias = (sel == 0) ? bq : (sel == 1) ? bk : bv;
    // fold 1/sqrt(Dk) AND log2(e) into Q so attention uses a single v_exp_f32
    // (exact: softmax(S) == softmax-base-2(S*log2e)); 0.125 * 1.4426950408889634
    const float scl = (sel == 0) ? 0.18033688511157292f : 1.0f;
#pragma unroll
    for (int i = 0; i < 4; ++i) {
#pragma unroll
        for (int j = 0; j < 4; ++j) {
            const int n = nbase + wc + j * 16 + cn;
            const float bb = bias[n];
            if (sel == 2) {
                const int m0 = row0 + wr + i * 16 + cq;
                ushort4 o;
                o.x = f2bf(acc[i][j][0] + bb);
                o.y = f2bf(acc[i][j][1] + bb);
                o.z = f2bf(acc[i][j][2] + bb);
                o.w = f2bf(acc[i][j][3] + bb);
                *reinterpret_cast<ushort4*>(&vtb[(size_t)n * M + m0]) = o;
            } else {
                unsigned short* dst = (sel == 0) ? qb : kb;
#pragma unroll
                for (int r = 0; r < 4; ++r) {
                    const int m = row0 + wr + i * 16 + cq + r;
                    dst[(size_t)m * D_MODEL + n] = f2bf((acc[i][j][r] + bb) * scl);
                }
            }
        }
    }
}

// ---------- Split-K GEMM: z = K-slice; raw bf16 partials ----------
__global__ __launch_bounds__(256) void mfma_gemm_splitk(const unsigned short* __restrict__ A,
                                                        const unsigned short* __restrict__ Wt,
                                                        unsigned short* __restrict__ parts,
                                                        int M, int N, int KS) {
    __shared__ unsigned short As[128 * 32];
    __shared__ unsigned short Bs[128 * 32];
    const int tid  = threadIdx.x;
    const int lane = tid & 63;
    const int wave = tid >> 6;
    const int row0 = blockIdx.y * 128, col0 = blockIdx.x * 128;
    const int wr = (wave >> 1) * 64, wc = (wave & 1) * 64;
    const int K = KS * gridDim.z;
    const int kbeg = blockIdx.z * KS;
    unsigned short* outp = parts + (size_t)blockIdx.z * M * N;

    floatx4 acc[4][4] = {};
    const int p0 = tid,       r0s = p0 >> 2, k0s = (((p0 & 3) - (r0s >> 1)) & 3) * 8;
    const int p1 = tid + 256, r1s = p1 >> 2, k1s = (((p1 & 3) - (r1s >> 1)) & 3) * 8;
    const int am = (lane & 15);

    int offA[4], offB[4];
#pragma unroll
    for (int i = 0; i < 4; ++i) {
        const int Ra = wr + i * 16 + am;
        offA[i] = Ra * 32 + (((lane >> 4) + (Ra >> 1)) & 3) * 8;
        const int Rb = wc + i * 16 + am;
        offB[i] = Rb * 32 + (((lane >> 4) + (Rb >> 1)) & 3) * 8;
    }

    for (int kt = kbeg; kt < kbeg + KS; kt += 32) {
        glds16(A  + (size_t)(row0 + r0s) * K + kt + k0s, &As[p0 * 8]);
        glds16(A  + (size_t)(row0 + r1s) * K + kt + k1s, &As[p1 * 8]);
        glds16(Wt + (size_t)(col0 + r0s) * K + kt + k0s, &Bs[p0 * 8]);
        glds16(Wt + (size_t)(col0 + r1s) * K + kt + k1s, &Bs[p1 * 8]);
        __syncthreads();
        shortx8 af[4], bf[4];
#pragma unroll
        for (int i = 0; i < 4; ++i)
            af[i] = *reinterpret_cast<const shortx8*>(&As[offA[i]]);
#pragma unroll
        for (int j = 0; j < 4; ++j)
            bf[j] = *reinterpret_cast<const shortx8*>(&Bs[offB[j]]);
#pragma unroll
        for (int i = 0; i < 4; ++i)
#pragma unroll
            for (int j = 0; j < 4; ++j)
                acc[i][j] = __builtin_amdgcn_mfma_f32_16x16x32_bf16(af[i], bf[j], acc[i][j], 0, 0, 0);
        __syncthreads();
    }

    const int cq = (lane >> 4) * 4;
    const int cn = lane & 15;
#pragma unroll
    for (int i = 0; i < 4; ++i)
#pragma unroll
        for (int j = 0; j < 4; ++j) {
            const int n = col0 + wc + j * 16 + cn;
#pragma unroll
            for (int r = 0; r < 4; ++r) {
                const int m = row0 + wr + i * 16 + cq + r;
                outp[(size_t)m * N + n] = f2bf(acc[i][j][r]);
            }
        }
}

// ---------- combine: out = p0 + p1 + bias + res ----------
__global__ __launch_bounds__(256) void combine_kernel(const unsigned short* __restrict__ p0,
                                                      const unsigned short* __restrict__ p1,
                                                      const float* __restrict__ bias,
                                                      const float* __restrict__ res,
                                                      float* __restrict__ out) {
    const size_t e0 = ((size_t)blockIdx.x * 256 + threadIdx.x) * 4;
    const int col = (int)(e0 & 1023);
    ushort4 a = *reinterpret_cast<const ushort4*>(&p0[e0]);
    ushort4 b = *reinterpret_cast<const ushort4*>(&p1[e0]);
    float4 r = *reinterpret_cast<const float4*>(&res[e0]);
    float4 o;
    o.x = bf2f(a.x) + bf2f(b.x) + bias[col + 0] + r.x;
    o.y = bf2f(a.y) + bf2f(b.y) + bias[col + 1] + r.y;
    o.z = bf2f(a.z) + bf2f(b.z) + bias[col + 2] + r.z;
    o.w = bf2f(a.w) + bf2f(b.w) + bias[col + 3] + r.w;
    *reinterpret_cast<float4*>(&out[e0]) = o;
}

// ---------- MFMA attention: R5 = QBLK 64 -> 128 (8 waves, 512 threads).
// Same sync structure as R0/R4 (glds16 staging, 2 barriers/tile): each staged 64-row
// K/V tile now serves 128 q-rows -> compute-per-drain doubles, K/V re-issue traffic
// halves, barrier count per unit work halves. Per-wave code unchanged (16-row strip).
// LDS ~50 KB -> grid 512 blocks = 2 blocks/CU x 8 waves = 16 waves/CU (same as R4).
// Exp path: single v_exp_f32 (Q pre-scaled by log2e/8 upstream).
__global__ __launch_bounds__(512) void attn_mfma(const unsigned short* __restrict__ Q,
                                                 const unsigned short* __restrict__ K,
                                                 const unsigned short* __restrict__ Vt,
                                                 const int* __restrict__ mask,
                                                 unsigned short* __restrict__ att) {
    const int tid  = threadIdx.x;
    const int lane = tid & 63;
    const int wave = tid >> 6;          // 0..7
    const int q0 = blockIdx.x * 128;
    const int h  = blockIdx.y;
    const int b  = blockIdx.z;

    __shared__ unsigned short Qs[128 * PST];
    __shared__ unsigned short Ks[64 * 64];
    __shared__ unsigned short Vs[64 * 64];
    __shared__ unsigned short Ps[128 * PST];
    __shared__ int mk[64];

    const int am = lane & 15;
    const int aq = (lane >> 4) * 8;
    const int cq = (lane >> 4) * 4;
    const int cn = lane & 15;

    // stage Q tile (once, via VGPR; padded layout): 128 rows x 8 chunks = 1024 chunks
    for (int c = tid; c < 1024; c += 512) {
        const int r = c >> 3, off = (c & 7) * 8;
        *reinterpret_cast<uint4*>(&Qs[r * PST + off]) =
            *reinterpret_cast<const uint4*>(&Q[(size_t)(b * L_SEQ + q0 + r) * D_MODEL + h * D_K + off]);
    }

    // swizzled staging: LDS chunk p holds (row=p>>3, c8=((p&7)-row)&7); 512 chunks,
    // exactly one per thread for each of Ks and Vs.
    const int p0 = tid, sr0 = p0 >> 3, sc0 = (((p0 & 7) - sr0) & 7) * 8;
    const unsigned short* K0 = K + (size_t)(b * L_SEQ + sr0) * D_MODEL + h * D_K + sc0;
    const unsigned short* V0 = Vt + (size_t)(h * D_K + sr0) * ROWS + b * L_SEQ + sc0;

    // fragment read offsets (loop-invariant): row R = t*16+am, chunk c8 = kt*4 + (lane>>4)
    int offF[2][4];
#pragma unroll
    for (int kt = 0; kt < 2; ++kt)
#pragma unroll
        for (int t = 0; t < 4; ++t) {
            const int R = t * 16 + am;
            offF[kt][t] = R * 64 + (((kt * 4 + (lane >> 4)) + R) & 7) * 8;
        }

    __syncthreads();

    shortx8 aQ[2];
    aQ[0] = *reinterpret_cast<const shortx8*>(&Qs[(wave * 16 + am) * PST + aq]);
    aQ[1] = *reinterpret_cast<const shortx8*>(&Qs[(wave * 16 + am) * PST + 32 + aq]);

    floatx4 oacc[4] = {};
    float lsum[4] = {0.0f, 0.0f, 0.0f, 0.0f};

    for (int j0 = 0; j0 < L_SEQ; j0 += 64) {
        __syncthreads();
        glds16(K0 + (size_t)j0 * D_MODEL, &Ks[p0 * 8]);
        glds16(V0 + j0, &Vs[p0 * 8]);
        if (tid < 64) mk[tid] = mask[b * L_SEQ + j0 + tid];
        __syncthreads();

        floatx4 sacc[4] = {};
#pragma unroll
        for (int kt = 0; kt < 2; ++kt)
#pragma unroll
            for (int jt = 0; jt < 4; ++jt) {
                shortx8 bK = *reinterpret_cast<const shortx8*>(&Ks[offF[kt][jt]]);
                sacc[jt] = __builtin_amdgcn_mfma_f32_16x16x32_bf16(aQ[kt], bK, sacc[jt], 0, 0, 0);
            }
        // P = exp2(S) masked (Q pre-scaled by log2e/8 -> single v_exp_f32);
        // truncate-cast to bf16
#pragma unroll
        for (int jt = 0; jt < 4; ++jt) {
            const int mv = mk[jt * 16 + cn];
#pragma unroll
            for (int r = 0; r < 4; ++r) {
                float p = mv ? __builtin_amdgcn_exp2f(sacc[jt][r]) : 0.0f;
                lsum[r] += p;
                Ps[(wave * 16 + cq + r) * PST + jt * 16 + cn] =
                    (unsigned short)(__float_as_uint(p) >> 16);
            }
        }
        // O += P x V (wave-private Ps rows)
#pragma unroll
        for (int kt = 0; kt < 2; ++kt) {
            shortx8 aP = *reinterpret_cast<const shortx8*>(&Ps[(wave * 16 + am) * PST + kt * 32 + aq]);
#pragma unroll
            for (int dt = 0; dt < 4; ++dt) {
                shortx8 bV = *reinterpret_cast<const shortx8*>(&Vs[offF[kt][dt]]);
                oacc[dt] = __builtin_amdgcn_mfma_f32_16x16x32_bf16(aP, bV, oacc[dt], 0, 0, 0);
            }
        }
    }

#pragma unroll
    for (int r = 0; r < 4; ++r) {
        float t = lsum[r];
        t += __shfl_xor(t, 1);
        t += __shfl_xor(t, 2);
        t += __shfl_xor(t, 4);
        t += __shfl_xor(t, 8);
        lsum[r] = 1.0f / t;
    }
#pragma unroll
    for (int dt = 0; dt < 4; ++dt)
#pragma unroll
        for (int r = 0; r < 4; ++r) {
            att[(size_t)(b * L_SEQ + q0 + wave * 16 + cq + r) * D_MODEL + h * D_K + dt * 16 + cn] =
                f2bf(oacc[dt][r] * lsum[r]);
        }
}

extern "C" void kernel_launch(void* const* d_in, const int* in_sizes, int n_in,
                              void* d_out, int out_size, void* d_ws, size_t ws_size,
                              hipStream_t stream) {
    const float* x     = (const float*)d_in[0];
    const int*   mask  = (const int*)d_in[1];
    const float* ln1_g = (const float*)d_in[2];
    const float* ln1_b = (const float*)d_in[3];
    const float* Wq    = (const float*)d_in[4];
    const float* bq    = (const float*)d_in[5];
    const float* Wk    = (const float*)d_in[6];
    const float* bk    = (const float*)d_in[7];
    const float* Wv    = (const float*)d_in[8];
    const float* bv    = (const float*)d_in[9];
    const float* Wo    = (const float*)d_in[10];
    const float* bo    = (const float*)d_in[11];
    const float* ln2_g = (const float*)d_in[12];
    const float* ln2_b = (const float*)d_in[13];
    const float* W1    = (const float*)d_in[14];
    const float* b1    = (const float*)d_in[15];
    const float* W2    = (const float*)d_in[16];
    const float* b2    = (const float*)d_in[17];
    float* out = (float*)d_out;

    float* ws = (float*)d_ws;
    const size_t SZ = (size_t)ROWS * D_MODEL;  // 4M elements; fp32 slot = 16 MB

    unsigned short* nx  = (unsigned short*)(ws + 0 * SZ);   // 0-8 MB: LN1/LN2 out bf16
    unsigned short* qb  = (unsigned short*)(ws + 1 * SZ);   // 16-24: Q bf16 (pre-scaled)
    unsigned short* kb  = qb + SZ;                          // 24-32: K bf16
    unsigned short* vtb = (unsigned short*)(ws + 2 * SZ);   // 32-40: V^T bf16
    unsigned short* attb = vtb + SZ;                        // 40-48: att bf16
    float* x1  = out;                                       // residual stream in d_out
    unsigned short* nx2 = nx;                               // slot0 reuse
    unsigned short* h = (unsigned short*)(ws + 2 * SZ);     // 32-64: FFN hidden bf16
    unsigned short* parts = (unsigned short*)(ws + 0 * SZ); // 0-16: FFN2 split-K partials

    unsigned short* WqkvT = (unsigned short*)(ws + 4 * SZ); // 64-70: concat [3072][1024]
    unsigned short* WqT = WqkvT;
    unsigned short* WkT = WqkvT + (size_t)D_MODEL * D_MODEL;
    unsigned short* WvT = WkT + (size_t)D_MODEL * D_MODEL;
    unsigned short* WoT = WvT + (size_t)D_MODEL * D_MODEL;  // 70-72
    unsigned short* W1T = (unsigned short*)(ws + 1 * SZ);   // 16-24 (qb/kb dead after attn)
    unsigned short* W2T = W1T + (size_t)D_MODEL * FFN_DIM;  // 24-32

    ln_kernel<<<ROWS, 256, 0, stream>>>(x, ln1_g, ln1_b, nx);

    transpose_cast4<<<dim3(32, 32, 4), 256, 0, stream>>>(Wq, Wk, Wv, Wo, WqT, WkT, WvT, WoT);

    mfma_gemm_qkv<<<dim3(3072 / 128, ROWS / 128), 256, 0, stream>>>(
        nx, WqkvT, bq, bk, bv, qb, kb, vtb);

    attn_mfma<<<dim3(L_SEQ / 128, N_HEAD, B_SZ), 512, 0, stream>>>(qb, kb, vtb, mask, attb);

    transpose_cast<<<dim3(FFN_DIM / 32, D_MODEL / 32), 256, 0, stream>>>(W1, W1T, D_MODEL, FFN_DIM);
    transpose_cast<<<dim3(D_MODEL / 32, FFN_DIM / 32), 256, 0, stream>>>(W2, W2T, FFN_DIM, D_MODEL);

    mfma_gemm<0, 1, 0><<<dim3(D_MODEL / 128, ROWS / 128), 256, 0, stream>>>(
        attb, WoT, bo, x, x1, ROWS, D_MODEL, D_MODEL);

    ln_kernel<<<ROWS, 256, 0, stream>>>(x1, ln2_g, ln2_b, nx2);

    mfma_gemm<1, 0, 1><<<dim3(FFN_DIM / 128, ROWS / 128), 256, 0, stream>>>(
        nx2, W1T, b1, nullptr, h, ROWS, FFN_DIM, D_MODEL);

    mfma_gemm_splitk<<<dim3(D_MODEL / 128, ROWS / 128, 2), 256, 0, stream>>>(
        h, W2T, parts, ROWS, D_MODEL, FFN_DIM / 2);
    combine_kernel<<<(ROWS * D_MODEL) / 1024, 256, 0, stream>>>(
        parts, parts + SZ, b2, x1, out);
}

// Round 6
// 393.618 us; speedup vs baseline: 1.0874x; 1.0381x over previous
//
#include <hip/hip_runtime.h>
#include <hip/hip_bf16.h>

#define D_MODEL 1024
#define N_HEAD  16
#define D_K     64
#define FFN_DIM 4096
#define B_SZ    2
#define L_SEQ   2048
#define ROWS    (B_SZ * L_SEQ)   // 4096
#define PST     68               // Ps/Qs LDS row stride (shorts): proven 0-conflict (R9/R10)

typedef float  floatx4 __attribute__((ext_vector_type(4)));
typedef short  shortx8 __attribute__((ext_vector_type(8)));

__device__ __forceinline__ unsigned short f2bf(float f) {
    unsigned int u = __float_as_uint(f);
    unsigned int rounding = 0x7fffu + ((u >> 16) & 1u);
    return (unsigned short)((u + rounding) >> 16);
}
__device__ __forceinline__ float bf2f(unsigned short u) {
    return __uint_as_float(((unsigned int)u) << 16);
}

// async global->LDS 16B copy; LDS dest is wave-uniform base + lane*16
__device__ __forceinline__ void glds16(const unsigned short* g, unsigned short* l) {
    __builtin_amdgcn_global_load_lds(
        (const __attribute__((address_space(1))) unsigned int*)g,
        (__attribute__((address_space(3))) unsigned int*)l, 16, 0, 0);
}

// ---- T1: XCD-chunked blockIdx remap. Assumes linear wg id round-robins the 8 XCDs
// (id%8 = XCD, per learn_hip m09/m157). Each XCD then owns a contiguous chunk of tile
// space, decoded as groups of 8 col-tiles x consecutive row-tiles, so blocks sharing
// A-row strips / B-col panels co-reside in one XCD's 4 MB L2. Bijective when
// nwg%8==0 and gx%8==0 (all our grids). Pure permutation -> correctness-safe.
__device__ __forceinline__ void xcd_remap_gemm(int& bx, int& by, int& bz) {
    const int gx = gridDim.x, gy = gridDim.y, gz = gridDim.z;
    const int o = blockIdx.x + gx * (blockIdx.y + gy * blockIdx.z);
    const int nwg = gx * gy * gz;
    const int t = (o & 7) * (nwg >> 3) + (o >> 3);
    const int zsz = gx * gy;
    bz = t / zsz;
    const int w = t - bz * zsz;
    const int grp = w / (8 * gy);
    const int in  = w - grp * (8 * gy);
    by = in >> 3;
    bx = grp * 8 + (in & 7);
}

// ---------- LayerNorm: one block per row of 1024, fp32 in -> bf16 out ----------
__global__ __launch_bounds__(256) void ln_kernel(const float* __restrict__ x,
                                                 const float* __restrict__ g,
                                                 const float* __restrict__ b,
                                                 unsigned short* __restrict__ out) {
    const int row = blockIdx.x;
    const int tid = threadIdx.x;
    const float* xr = x + (size_t)row * D_MODEL;
    float4 xv = *reinterpret_cast<const float4*>(&xr[tid * 4]);
    float v[4] = {xv.x, xv.y, xv.z, xv.w};
    float s = v[0] + v[1] + v[2] + v[3];
    float ss = v[0] * v[0] + v[1] * v[1] + v[2] * v[2] + v[3] * v[3];
    __shared__ float r1[256], r2[256];
    r1[tid] = s; r2[tid] = ss;
    __syncthreads();
    for (int off = 128; off > 0; off >>= 1) {
        if (tid < off) { r1[tid] += r1[tid + off]; r2[tid] += r2[tid + off]; }
        __syncthreads();
    }
    const float mean = r1[0] * (1.0f / D_MODEL);
    const float var  = r2[0] * (1.0f / D_MODEL) - mean * mean;
    const float inv  = rsqrtf(var + 1e-5f);
    unsigned short* orow = out + (size_t)row * D_MODEL;
    ushort4 o;
    o.x = f2bf((v[0] - mean) * inv * g[tid * 4 + 0] + b[tid * 4 + 0]);
    o.y = f2bf((v[1] - mean) * inv * g[tid * 4 + 1] + b[tid * 4 + 1]);
    o.z = f2bf((v[2] - mean) * inv * g[tid * 4 + 2] + b[tid * 4 + 2]);
    o.w = f2bf((v[3] - mean) * inv * g[tid * 4 + 3] + b[tid * 4 + 3]);
    *reinterpret_cast<ushort4*>(&orow[tid * 4]) = o;
}

// ---------- Transpose+cast: W fp32 [K][N] -> Wt bf16 [N][K] ----------
__global__ __launch_bounds__(256) void transpose_cast(const float* __restrict__ W,
                                                      unsigned short* __restrict__ Wt,
                                                      int K, int N) {
    __shared__ unsigned short T[32][33];
    const int t = threadIdx.x;
    const int k0 = blockIdx.y * 32, n0 = blockIdx.x * 32;
    const int kr = t >> 3, nc = (t & 7) * 4;
    float4 w = *reinterpret_cast<const float4*>(&W[(size_t)(k0 + kr) * N + n0 + nc]);
    T[kr][nc + 0] = f2bf(w.x); T[kr][nc + 1] = f2bf(w.y);
    T[kr][nc + 2] = f2bf(w.z); T[kr][nc + 3] = f2bf(w.w);
    __syncthreads();
    const int nr = t >> 3, kc = (t & 7) * 4;
    ushort4 o;
    o.x = T[kc + 0][nr]; o.y = T[kc + 1][nr];
    o.z = T[kc + 2][nr]; o.w = T[kc + 3][nr];
    *reinterpret_cast<ushort4*>(&Wt[(size_t)(n0 + nr) * K + k0 + kc]) = o;
}

// ---------- 4x square (1024x1024) transpose in one dispatch, z selects matrix ----------
__global__ __launch_bounds__(256) void transpose_cast4(const float* s0, const float* s1,
                                                       const float* s2, const float* s3,
                                                       unsigned short* d0, unsigned short* d1,
                                                       unsigned short* d2, unsigned short* d3) {
    const int z = blockIdx.z;
    const float* W = (z == 0) ? s0 : (z == 1) ? s1 : (z == 2) ? s2 : s3;
    unsigned short* Wt = (z == 0) ? d0 : (z == 1) ? d1 : (z == 2) ? d2 : d3;
    __shared__ unsigned short T[32][33];
    const int t = threadIdx.x;
    const int k0 = blockIdx.y * 32, n0 = blockIdx.x * 32;
    const int kr = t >> 3, nc = (t & 7) * 4;
    float4 w = *reinterpret_cast<const float4*>(&W[(size_t)(k0 + kr) * D_MODEL + n0 + nc]);
    T[kr][nc + 0] = f2bf(w.x); T[kr][nc + 1] = f2bf(w.y);
    T[kr][nc + 2] = f2bf(w.z); T[kr][nc + 3] = f2bf(w.w);
    __syncthreads();
    const int nr = t >> 3, kc = (t & 7) * 4;
    ushort4 o;
    o.x = T[kc + 0][nr]; o.y = T[kc + 1][nr];
    o.z = T[kc + 2][nr]; o.w = T[kc + 3][nr];
    *reinterpret_cast<ushort4*>(&Wt[(size_t)(n0 + nr) * D_MODEL + k0 + kc]) = o;
}

// ===== GEMM swizzle: tile = 128 rows x 32 shorts (4x16B chunks/row).
// LDS pos p holds global chunk (row=p>>2, kc=((p&3)-(row>>1))&3).
// Read of (R, kc) at p = R*4 + ((kc+(R>>1))&3) -> bank-group 2-way max (free).

// ---------- MFMA bf16 GEMM (async swizzled staging). A [M][K]; Wt [N][K]. 128x128, BK=32. ----------
template <int SILU, int HAS_RES, int OUT_BF16>
__global__ __launch_bounds__(256) void mfma_gemm(const unsigned short* __restrict__ A,
                                                 const unsigned short* __restrict__ Wt,
                                                 const float* __restrict__ bias,
                                                 const float* __restrict__ res,
                                                 void* __restrict__ outP,
                                                 int M, int N, int K) {
    __shared__ unsigned short As[128 * 32];
    __shared__ unsigned short Bs[128 * 32];
    const int tid  = threadIdx.x;
    const int lane = tid & 63;
    const int wave = tid >> 6;
    int bx, by, bz;
    xcd_remap_gemm(bx, by, bz);
    const int row0 = by * 128, col0 = bx * 128;
    const int wr = (wave >> 1) * 64, wc = (wave & 1) * 64;

    floatx4 acc[4][4] = {};
    const int p0 = tid,       r0s = p0 >> 2, k0s = (((p0 & 3) - (r0s >> 1)) & 3) * 8;
    const int p1 = tid + 256, r1s = p1 >> 2, k1s = (((p1 & 3) - (r1s >> 1)) & 3) * 8;
    const int am = (lane & 15);

    int offA[4], offB[4];
#pragma unroll
    for (int i = 0; i < 4; ++i) {
        const int Ra = wr + i * 16 + am;
        offA[i] = Ra * 32 + (((lane >> 4) + (Ra >> 1)) & 3) * 8;
        const int Rb = wc + i * 16 + am;
        offB[i] = Rb * 32 + (((lane >> 4) + (Rb >> 1)) & 3) * 8;
    }

    for (int kt = 0; kt < K; kt += 32) {
        glds16(A  + (size_t)(row0 + r0s) * K + kt + k0s, &As[p0 * 8]);
        glds16(A  + (size_t)(row0 + r1s) * K + kt + k1s, &As[p1 * 8]);
        glds16(Wt + (size_t)(col0 + r0s) * K + kt + k0s, &Bs[p0 * 8]);
        glds16(Wt + (size_t)(col0 + r1s) * K + kt + k1s, &Bs[p1 * 8]);
        __syncthreads();
        shortx8 af[4], bf[4];
#pragma unroll
        for (int i = 0; i < 4; ++i)
            af[i] = *reinterpret_cast<const shortx8*>(&As[offA[i]]);
#pragma unroll
        for (int j = 0; j < 4; ++j)
            bf[j] = *reinterpret_cast<const shortx8*>(&Bs[offB[j]]);
#pragma unroll
        for (int i = 0; i < 4; ++i)
#pragma unroll
            for (int j = 0; j < 4; ++j)
                acc[i][j] = __builtin_amdgcn_mfma_f32_16x16x32_bf16(af[i], bf[j], acc[i][j], 0, 0, 0);
        __syncthreads();
    }

    const int cq = (lane >> 4) * 4;
    const int cn = lane & 15;
#pragma unroll
    for (int i = 0; i < 4; ++i) {
#pragma unroll
        for (int j = 0; j < 4; ++j) {
            const int n = col0 + wc + j * 16 + cn;
            const float bb = bias[n];
#pragma unroll
            for (int r = 0; r < 4; ++r) {
                const int m = row0 + wr + i * 16 + cq + r;
                float v = acc[i][j][r] + bb;
                if (SILU) v = v / (1.0f + __expf(-v));
                if (HAS_RES) v += res[(size_t)m * N + n];
                if (OUT_BF16) ((unsigned short*)outP)[(size_t)m * N + n] = f2bf(v);
                else          ((float*)outP)[(size_t)m * N + n] = v;
            }
        }
    }
}

// ---------- Fused QKV GEMM: N=3072 over concatenated [3072][1024] weights ----------
__global__ __launch_bounds__(256) void mfma_gemm_qkv(const unsigned short* __restrict__ A,
                                                     const unsigned short* __restrict__ Wt,
                                                     const float* __restrict__ bq,
                                                     const float* __restrict__ bk,
                                                     const float* __restrict__ bv,
                                                     unsigned short* __restrict__ qb,
                                                     unsigned short* __restrict__ kb,
                                                     unsigned short* __restrict__ vtb) {
    const int K = D_MODEL, M = ROWS;
    __shared__ unsigned short As[128 * 32];
    __shared__ unsigned short Bs[128 * 32];
    const int tid  = threadIdx.x;
    const int lane = tid & 63;
    const int wave = tid >> 6;
    int bx, by, bz;
    xcd_remap_gemm(bx, by, bz);
    const int row0 = by * 128, col0 = bx * 128;
    const int wr = (wave >> 1) * 64, wc = (wave & 1) * 64;

    floatx4 acc[4][4] = {};
    const int p0 = tid,       r0s = p0 >> 2, k0s = (((p0 & 3) - (r0s >> 1)) & 3) * 8;
    const int p1 = tid + 256, r1s = p1 >> 2, k1s = (((p1 & 3) - (r1s >> 1)) & 3) * 8;
    const int am = (lane & 15);

    int offA[4], offB[4];
#pragma unroll
    for (int i = 0; i < 4; ++i) {
        const int Ra = wr + i * 16 + am;
        offA[i] = Ra * 32 + (((lane >> 4) + (Ra >> 1)) & 3) * 8;
        const int Rb = wc + i * 16 + am;
        offB[i] = Rb * 32 + (((lane >> 4) + (Rb >> 1)) & 3) * 8;
    }

    for (int kt = 0; kt < K; kt += 32) {
        glds16(A  + (size_t)(row0 + r0s) * K + kt + k0s, &As[p0 * 8]);
        glds16(A  + (size_t)(row0 + r1s) * K + kt + k1s, &As[p1 * 8]);
        glds16(Wt + (size_t)(col0 + r0s) * K + kt + k0s, &Bs[p0 * 8]);
        glds16(Wt + (size_t)(col0 + r1s) * K + kt + k1s, &Bs[p1 * 8]);
        __syncthreads();
        shortx8 af[4], bf[4];
#pragma unroll
        for (int i = 0; i < 4; ++i)
            af[i] = *reinterpret_cast<const shortx8*>(&As[offA[i]]);
#pragma unroll
        for (int j = 0; j < 4; ++j)
            bf[j] = *reinterpret_cast<const shortx8*>(&Bs[offB[j]]);
#pragma unroll
        for (int i = 0; i < 4; ++i)
#pragma unroll
            for (int j = 0; j < 4; ++j)
                acc[i][j] = __builtin_amdgcn_mfma_f32_16x16x32_bf16(af[i], bf[j], acc[i][j], 0, 0, 0);
        __syncthreads();
    }

    const int cq = (lane >> 4) * 4;
    const int cn = lane & 15;
    const int sel = col0 >> 10;                 // 0=Q 1=K 2=V (block-uniform)
    const int nbase = col0 & 1023;
    const float* bias = (sel == 0) ? bq : (sel == 1) ? bk : bv;
    // fold 1/sqrt(Dk) AND log2(e) into Q so attention uses a single v_exp_f32
    // (exact: softmax(S) == softmax-base-2(S*log2e)); 0.125 * 1.4426950408889634
    const float scl = (sel == 0) ? 0.18033688511157292f : 1.0f;
#pragma unroll
    for (int i = 0; i < 4; ++i) {
#pragma unroll
        for (int j = 0; j < 4; ++j) {
            const int n = nbase + wc + j * 16 + cn;
            const float bb = bias[n];
            if (sel == 2) {
                const int m0 = row0 + wr + i * 16 + cq;
                ushort4 o;
                o.x = f2bf(acc[i][j][0] + bb);
                o.y = f2bf(acc[i][j][1] + bb);
                o.z = f2bf(acc[i][j][2] + bb);
                o.w = f2bf(acc[i][j][3] + bb);
                *reinterpret_cast<ushort4*>(&vtb[(size_t)n * M + m0]) = o;
            } else {
                unsigned short* dst = (sel == 0) ? qb : kb;
#pragma unroll
                for (int r = 0; r < 4; ++r) {
                    const int m = row0 + wr + i * 16 + cq + r;
                    dst[(size_t)m * D_MODEL + n] = f2bf((acc[i][j][r] + bb) * scl);
                }
            }
        }
    }
}

// ---------- Split-K GEMM: z = K-slice; raw bf16 partials ----------
__global__ __launch_bounds__(256) void mfma_gemm_splitk(const unsigned short* __restrict__ A,
                                                        const unsigned short* __restrict__ Wt,
                                                        unsigned short* __restrict__ parts,
                                                        int M, int N, int KS) {
    __shared__ unsigned short As[128 * 32];
    __shared__ unsigned short Bs[128 * 32];
    const int tid  = threadIdx.x;
    const int lane = tid & 63;
    const int wave = tid >> 6;
    int bx, by, bz;
    xcd_remap_gemm(bx, by, bz);
    const int row0 = by * 128, col0 = bx * 128;
    const int wr = (wave >> 1) * 64, wc = (wave & 1) * 64;
    const int K = KS * gridDim.z;
    const int kbeg = bz * KS;
    unsigned short* outp = parts + (size_t)bz * M * N;

    floatx4 acc[4][4] = {};
    const int p0 = tid,       r0s = p0 >> 2, k0s = (((p0 & 3) - (r0s >> 1)) & 3) * 8;
    const int p1 = tid + 256, r1s = p1 >> 2, k1s = (((p1 & 3) - (r1s >> 1)) & 3) * 8;
    const int am = (lane & 15);

    int offA[4], offB[4];
#pragma unroll
    for (int i = 0; i < 4; ++i) {
        const int Ra = wr + i * 16 + am;
        offA[i] = Ra * 32 + (((lane >> 4) + (Ra >> 1)) & 3) * 8;
        const int Rb = wc + i * 16 + am;
        offB[i] = Rb * 32 + (((lane >> 4) + (Rb >> 1)) & 3) * 8;
    }

    for (int kt = kbeg; kt < kbeg + KS; kt += 32) {
        glds16(A  + (size_t)(row0 + r0s) * K + kt + k0s, &As[p0 * 8]);
        glds16(A  + (size_t)(row0 + r1s) * K + kt + k1s, &As[p1 * 8]);
        glds16(Wt + (size_t)(col0 + r0s) * K + kt + k0s, &Bs[p0 * 8]);
        glds16(Wt + (size_t)(col0 + r1s) * K + kt + k1s, &Bs[p1 * 8]);
        __syncthreads();
        shortx8 af[4], bf[4];
#pragma unroll
        for (int i = 0; i < 4; ++i)
            af[i] = *reinterpret_cast<const shortx8*>(&As[offA[i]]);
#pragma unroll
        for (int j = 0; j < 4; ++j)
            bf[j] = *reinterpret_cast<const shortx8*>(&Bs[offB[j]]);
#pragma unroll
        for (int i = 0; i < 4; ++i)
#pragma unroll
            for (int j = 0; j < 4; ++j)
                acc[i][j] = __builtin_amdgcn_mfma_f32_16x16x32_bf16(af[i], bf[j], acc[i][j], 0, 0, 0);
        __syncthreads();
    }

    const int cq = (lane >> 4) * 4;
    const int cn = lane & 15;
#pragma unroll
    for (int i = 0; i < 4; ++i)
#pragma unroll
        for (int j = 0; j < 4; ++j) {
            const int n = col0 + wc + j * 16 + cn;
#pragma unroll
            for (int r = 0; r < 4; ++r) {
                const int m = row0 + wr + i * 16 + cq + r;
                outp[(size_t)m * N + n] = f2bf(acc[i][j][r]);
            }
        }
}

// ---------- combine: out = p0 + p1 + bias + res ----------
__global__ __launch_bounds__(256) void combine_kernel(const unsigned short* __restrict__ p0,
                                                      const unsigned short* __restrict__ p1,
                                                      const float* __restrict__ bias,
                                                      const float* __restrict__ res,
                                                      float* __restrict__ out) {
    const size_t e0 = ((size_t)blockIdx.x * 256 + threadIdx.x) * 4;
    const int col = (int)(e0 & 1023);
    ushort4 a = *reinterpret_cast<const ushort4*>(&p0[e0]);
    ushort4 b = *reinterpret_cast<const ushort4*>(&p1[e0]);
    float4 r = *reinterpret_cast<const float4*>(&res[e0]);
    float4 o;
    o.x = bf2f(a.x) + bf2f(b.x) + bias[col + 0] + r.x;
    o.y = bf2f(a.y) + bf2f(b.y) + bias[col + 1] + r.y;
    o.z = bf2f(a.z) + bf2f(b.z) + bias[col + 2] + r.z;
    o.w = bf2f(a.w) + bf2f(b.w) + bias[col + 3] + r.w;
    *reinterpret_cast<float4*>(&out[e0]) = o;
}

// ---------- MFMA attention: R5 structure (QBLK=128, 8 waves) + R6 XCD-chunked remap.
// Chunk of 64 consecutive tiles = 16 q-tiles x 4 heads (one batch) -> per-XCD K/V
// working set 4 x 512 KB = 2 MB, fits the XCD's 4 MB L2.
__global__ __launch_bounds__(512) void attn_mfma(const unsigned short* __restrict__ Q,
                                                 const unsigned short* __restrict__ K,
                                                 const unsigned short* __restrict__ Vt,
                                                 const int* __restrict__ mask,
                                                 unsigned short* __restrict__ att) {
    const int tid  = threadIdx.x;
    const int lane = tid & 63;
    const int wave = tid >> 6;          // 0..7
    // plain chunked XCD remap (row-major decode: q-tile fastest -> chunk shares K/V)
    const int o = blockIdx.x + gridDim.x * (blockIdx.y + gridDim.y * blockIdx.z);
    const int nwg = gridDim.x * gridDim.y * gridDim.z;
    const int t = (o & 7) * (nwg >> 3) + (o >> 3);
    const int qx = t % gridDim.x;
    const int h  = (t / gridDim.x) % gridDim.y;
    const int b  = t / (gridDim.x * gridDim.y);
    const int q0 = qx * 128;

    __shared__ unsigned short Qs[128 * PST];
    __shared__ unsigned short Ks[64 * 64];
    __shared__ unsigned short Vs[64 * 64];
    __shared__ unsigned short Ps[128 * PST];
    __shared__ int mk[64];

    const int am = lane & 15;
    const int aq = (lane >> 4) * 8;
    const int cq = (lane >> 4) * 4;
    const int cn = lane & 15;

    // stage Q tile (once, via VGPR; padded layout): 128 rows x 8 chunks = 1024 chunks
    for (int c = tid; c < 1024; c += 512) {
        const int r = c >> 3, off = (c & 7) * 8;
        *reinterpret_cast<uint4*>(&Qs[r * PST + off]) =
            *reinterpret_cast<const uint4*>(&Q[(size_t)(b * L_SEQ + q0 + r) * D_MODEL + h * D_K + off]);
    }

    // swizzled staging: LDS chunk p holds (row=p>>3, c8=((p&7)-row)&7); 512 chunks,
    // exactly one per thread for each of Ks and Vs.
    const int p0 = tid, sr0 = p0 >> 3, sc0 = (((p0 & 7) - sr0) & 7) * 8;
    const unsigned short* K0 = K + (size_t)(b * L_SEQ + sr0) * D_MODEL + h * D_K + sc0;
    const unsigned short* V0 = Vt + (size_t)(h * D_K + sr0) * ROWS + b * L_SEQ + sc0;

    // fragment read offsets (loop-invariant): row R = t*16+am, chunk c8 = kt*4 + (lane>>4)
    int offF[2][4];
#pragma unroll
    for (int kt = 0; kt < 2; ++kt)
#pragma unroll
        for (int tt = 0; tt < 4; ++tt) {
            const int R = tt * 16 + am;
            offF[kt][tt] = R * 64 + (((kt * 4 + (lane >> 4)) + R) & 7) * 8;
        }

    __syncthreads();

    shortx8 aQ[2];
    aQ[0] = *reinterpret_cast<const shortx8*>(&Qs[(wave * 16 + am) * PST + aq]);
    aQ[1] = *reinterpret_cast<const shortx8*>(&Qs[(wave * 16 + am) * PST + 32 + aq]);

    floatx4 oacc[4] = {};
    float lsum[4] = {0.0f, 0.0f, 0.0f, 0.0f};

    for (int j0 = 0; j0 < L_SEQ; j0 += 64) {
        __syncthreads();
        glds16(K0 + (size_t)j0 * D_MODEL, &Ks[p0 * 8]);
        glds16(V0 + j0, &Vs[p0 * 8]);
        if (tid < 64) mk[tid] = mask[b * L_SEQ + j0 + tid];
        __syncthreads();

        floatx4 sacc[4] = {};
#pragma unroll
        for (int kt = 0; kt < 2; ++kt)
#pragma unroll
            for (int jt = 0; jt < 4; ++jt) {
                shortx8 bK = *reinterpret_cast<const shortx8*>(&Ks[offF[kt][jt]]);
                sacc[jt] = __builtin_amdgcn_mfma_f32_16x16x32_bf16(aQ[kt], bK, sacc[jt], 0, 0, 0);
            }
        // P = exp2(S) masked (Q pre-scaled by log2e/8 -> single v_exp_f32);
        // truncate-cast to bf16
#pragma unroll
        for (int jt = 0; jt < 4; ++jt) {
            const int mv = mk[jt * 16 + cn];
#pragma unroll
            for (int r = 0; r < 4; ++r) {
                float p = mv ? __builtin_amdgcn_exp2f(sacc[jt][r]) : 0.0f;
                lsum[r] += p;
                Ps[(wave * 16 + cq + r) * PST + jt * 16 + cn] =
                    (unsigned short)(__float_as_uint(p) >> 16);
            }
        }
        // O += P x V (wave-private Ps rows)
#pragma unroll
        for (int kt = 0; kt < 2; ++kt) {
            shortx8 aP = *reinterpret_cast<const shortx8*>(&Ps[(wave * 16 + am) * PST + kt * 32 + aq]);
#pragma unroll
            for (int dt = 0; dt < 4; ++dt) {
                shortx8 bV = *reinterpret_cast<const shortx8*>(&Vs[offF[kt][dt]]);
                oacc[dt] = __builtin_amdgcn_mfma_f32_16x16x32_bf16(aP, bV, oacc[dt], 0, 0, 0);
            }
        }
    }

#pragma unroll
    for (int r = 0; r < 4; ++r) {
        float t2 = lsum[r];
        t2 += __shfl_xor(t2, 1);
        t2 += __shfl_xor(t2, 2);
        t2 += __shfl_xor(t2, 4);
        t2 += __shfl_xor(t2, 8);
        lsum[r] = 1.0f / t2;
    }
#pragma unroll
    for (int dt = 0; dt < 4; ++dt)
#pragma unroll
        for (int r = 0; r < 4; ++r) {
            att[(size_t)(b * L_SEQ + q0 + wave * 16 + cq + r) * D_MODEL + h * D_K + dt * 16 + cn] =
                f2bf(oacc[dt][r] * lsum[r]);
        }
}

extern "C" void kernel_launch(void* const* d_in, const int* in_sizes, int n_in,
                              void* d_out, int out_size, void* d_ws, size_t ws_size,
                              hipStream_t stream) {
    const float* x     = (const float*)d_in[0];
    const int*   mask  = (const int*)d_in[1];
    const float* ln1_g = (const float*)d_in[2];
    const float* ln1_b = (const float*)d_in[3];
    const float* Wq    = (const float*)d_in[4];
    const float* bq    = (const float*)d_in[5];
    const float* Wk    = (const float*)d_in[6];
    const float* bk    = (const float*)d_in[7];
    const float* Wv    = (const float*)d_in[8];
    const float* bv    = (const float*)d_in[9];
    const float* Wo    = (const float*)d_in[10];
    const float* bo    = (const float*)d_in[11];
    const float* ln2_g = (const float*)d_in[12];
    const float* ln2_b = (const float*)d_in[13];
    const float* W1    = (const float*)d_in[14];
    const float* b1    = (const float*)d_in[15];
    const float* W2    = (const float*)d_in[16];
    const float* b2    = (const float*)d_in[17];
    float* out = (float*)d_out;

    float* ws = (float*)d_ws;
    const size_t SZ = (size_t)ROWS * D_MODEL;  // 4M elements; fp32 slot = 16 MB

    unsigned short* nx  = (unsigned short*)(ws + 0 * SZ);   // 0-8 MB: LN1/LN2 out bf16
    unsigned short* qb  = (unsigned short*)(ws + 1 * SZ);   // 16-24: Q bf16 (pre-scaled)
    unsigned short* kb  = qb + SZ;                          // 24-32: K bf16
    unsigned short* vtb = (unsigned short*)(ws + 2 * SZ);   // 32-40: V^T bf16
    unsigned short* attb = vtb + SZ;                        // 40-48: att bf16
    float* x1  = out;                                       // residual stream in d_out
    unsigned short* nx2 = nx;                               // slot0 reuse
    unsigned short* h = (unsigned short*)(ws + 2 * SZ);     // 32-64: FFN hidden bf16
    unsigned short* parts = (unsigned short*)(ws + 0 * SZ); // 0-16: FFN2 split-K partials

    unsigned short* WqkvT = (unsigned short*)(ws + 4 * SZ); // 64-70: concat [3072][1024]
    unsigned short* WqT = WqkvT;
    unsigned short* WkT = WqkvT + (size_t)D_MODEL * D_MODEL;
    unsigned short* WvT = WkT + (size_t)D_MODEL * D_MODEL;
    unsigned short* WoT = WvT + (size_t)D_MODEL * D_MODEL;  // 70-72
    unsigned short* W1T = (unsigned short*)(ws + 1 * SZ);   // 16-24 (qb/kb dead after attn)
    unsigned short* W2T = W1T + (size_t)D_MODEL * FFN_DIM;  // 24-32

    ln_kernel<<<ROWS, 256, 0, stream>>>(x, ln1_g, ln1_b, nx);

    transpose_cast4<<<dim3(32, 32, 4), 256, 0, stream>>>(Wq, Wk, Wv, Wo, WqT, WkT, WvT, WoT);

    mfma_gemm_qkv<<<dim3(3072 / 128, ROWS / 128), 256, 0, stream>>>(
        nx, WqkvT, bq, bk, bv, qb, kb, vtb);

    attn_mfma<<<dim3(L_SEQ / 128, N_HEAD, B_SZ), 512, 0, stream>>>(qb, kb, vtb, mask, attb);

    transpose_cast<<<dim3(FFN_DIM / 32, D_MODEL / 32), 256, 0, stream>>>(W1, W1T, D_MODEL, FFN_DIM);
    transpose_cast<<<dim3(D_MODEL / 32, FFN_DIM / 32), 256, 0, stream>>>(W2, W2T, FFN_DIM, D_MODEL);

    mfma_gemm<0, 1, 0><<<dim3(D_MODEL / 128, ROWS / 128), 256, 0, stream>>>(
        attb, WoT, bo, x, x1, ROWS, D_MODEL, D_MODEL);

    ln_kernel<<<ROWS, 256, 0, stream>>>(x1, ln2_g, ln2_b, nx2);

    mfma_gemm<1, 0, 1><<<dim3(FFN_DIM / 128, ROWS / 128), 256, 0, stream>>>(
        nx2, W1T, b1, nullptr, h, ROWS, FFN_DIM, D_MODEL);

    mfma_gemm_splitk<<<dim3(D_MODEL / 128, ROWS / 128, 2), 256, 0, stream>>>(
        h, W2T, parts, ROWS, D_MODEL, FFN_DIM / 2);
    combine_kernel<<<(ROWS * D_MODEL) / 1024, 256, 0, stream>>>(
        parts, parts + SZ, b2, x1, out);
}

// Round 7
// 371.342 us; speedup vs baseline: 1.1526x; 1.0600x over previous
//
#include <hip/hip_runtime.h>
#include <hip/hip_bf16.h>

#define D_MODEL 1024
#define N_HEAD  16
#define D_K     64
#define FFN_DIM 4096
#define B_SZ    2
#define L_SEQ   2048
#define ROWS    (B_SZ * L_SEQ)   // 4096
#define PST     68               // Ps/Qs LDS row stride (shorts): proven 0-conflict (R9/R10)

typedef float  floatx4 __attribute__((ext_vector_type(4)));
typedef short  shortx8 __attribute__((ext_vector_type(8)));

__device__ __forceinline__ unsigned short f2bf(float f) {
    unsigned int u = __float_as_uint(f);
    unsigned int rounding = 0x7fffu + ((u >> 16) & 1u);
    return (unsigned short)((u + rounding) >> 16);
}
__device__ __forceinline__ float bf2f(unsigned short u) {
    return __uint_as_float(((unsigned int)u) << 16);
}

// async global->LDS 16B copy; LDS dest is wave-uniform base + lane*16
__device__ __forceinline__ void glds16(const unsigned short* g, unsigned short* l) {
    __builtin_amdgcn_global_load_lds(
        (const __attribute__((address_space(1))) unsigned int*)g,
        (__attribute__((address_space(3))) unsigned int*)l, 16, 0, 0);
}

// ---- T1: XCD-chunked blockIdx remap (R6, verified: attn FETCH 69.7->12.4 MB).
// Linear wg id round-robins the 8 XCDs (id%8 = XCD). Decode groups of 8 col-tiles x
// consecutive row-tiles so blocks sharing A-strips/B-panels co-reside per-XCD L2.
// Bijective when nwg%8==0 and gx%8==0 (all our grids).
__device__ __forceinline__ void xcd_remap_gemm(int& bx, int& by, int& bz) {
    const int gx = gridDim.x, gy = gridDim.y, gz = gridDim.z;
    const int o = blockIdx.x + gx * (blockIdx.y + gy * blockIdx.z);
    const int nwg = gx * gy * gz;
    const int t = (o & 7) * (nwg >> 3) + (o >> 3);
    const int zsz = gx * gy;
    bz = t / zsz;
    const int w = t - bz * zsz;
    const int grp = w / (8 * gy);
    const int in  = w - grp * (8 * gy);
    by = in >> 3;
    bx = grp * 8 + (in & 7);
}

// ---------- LayerNorm: one block per row of 1024, fp32 in -> bf16 out ----------
__global__ __launch_bounds__(256) void ln_kernel(const float* __restrict__ x,
                                                 const float* __restrict__ g,
                                                 const float* __restrict__ b,
                                                 unsigned short* __restrict__ out) {
    const int row = blockIdx.x;
    const int tid = threadIdx.x;
    const float* xr = x + (size_t)row * D_MODEL;
    float4 xv = *reinterpret_cast<const float4*>(&xr[tid * 4]);
    float v[4] = {xv.x, xv.y, xv.z, xv.w};
    float s = v[0] + v[1] + v[2] + v[3];
    float ss = v[0] * v[0] + v[1] * v[1] + v[2] * v[2] + v[3] * v[3];
    __shared__ float r1[256], r2[256];
    r1[tid] = s; r2[tid] = ss;
    __syncthreads();
    for (int off = 128; off > 0; off >>= 1) {
        if (tid < off) { r1[tid] += r1[tid + off]; r2[tid] += r2[tid + off]; }
        __syncthreads();
    }
    const float mean = r1[0] * (1.0f / D_MODEL);
    const float var  = r2[0] * (1.0f / D_MODEL) - mean * mean;
    const float inv  = rsqrtf(var + 1e-5f);
    unsigned short* orow = out + (size_t)row * D_MODEL;
    ushort4 o;
    o.x = f2bf((v[0] - mean) * inv * g[tid * 4 + 0] + b[tid * 4 + 0]);
    o.y = f2bf((v[1] - mean) * inv * g[tid * 4 + 1] + b[tid * 4 + 1]);
    o.z = f2bf((v[2] - mean) * inv * g[tid * 4 + 2] + b[tid * 4 + 2]);
    o.w = f2bf((v[3] - mean) * inv * g[tid * 4 + 3] + b[tid * 4 + 3]);
    *reinterpret_cast<ushort4*>(&orow[tid * 4]) = o;
}

// ---------- Transpose+cast: W fp32 [K][N] -> Wt bf16 [N][K] ----------
__global__ __launch_bounds__(256) void transpose_cast(const float* __restrict__ W,
                                                      unsigned short* __restrict__ Wt,
                                                      int K, int N) {
    __shared__ unsigned short T[32][33];
    const int t = threadIdx.x;
    const int k0 = blockIdx.y * 32, n0 = blockIdx.x * 32;
    const int kr = t >> 3, nc = (t & 7) * 4;
    float4 w = *reinterpret_cast<const float4*>(&W[(size_t)(k0 + kr) * N + n0 + nc]);
    T[kr][nc + 0] = f2bf(w.x); T[kr][nc + 1] = f2bf(w.y);
    T[kr][nc + 2] = f2bf(w.z); T[kr][nc + 3] = f2bf(w.w);
    __syncthreads();
    const int nr = t >> 3, kc = (t & 7) * 4;
    ushort4 o;
    o.x = T[kc + 0][nr]; o.y = T[kc + 1][nr];
    o.z = T[kc + 2][nr]; o.w = T[kc + 3][nr];
    *reinterpret_cast<ushort4*>(&Wt[(size_t)(n0 + nr) * K + k0 + kc]) = o;
}

// ---------- 4x square (1024x1024) transpose in one dispatch, z selects matrix ----------
__global__ __launch_bounds__(256) void transpose_cast4(const float* s0, const float* s1,
                                                       const float* s2, const float* s3,
                                                       unsigned short* d0, unsigned short* d1,
                                                       unsigned short* d2, unsigned short* d3) {
    const int z = blockIdx.z;
    const float* W = (z == 0) ? s0 : (z == 1) ? s1 : (z == 2) ? s2 : s3;
    unsigned short* Wt = (z == 0) ? d0 : (z == 1) ? d1 : (z == 2) ? d2 : d3;
    __shared__ unsigned short T[32][33];
    const int t = threadIdx.x;
    const int k0 = blockIdx.y * 32, n0 = blockIdx.x * 32;
    const int kr = t >> 3, nc = (t & 7) * 4;
    float4 w = *reinterpret_cast<const float4*>(&W[(size_t)(k0 + kr) * D_MODEL + n0 + nc]);
    T[kr][nc + 0] = f2bf(w.x); T[kr][nc + 1] = f2bf(w.y);
    T[kr][nc + 2] = f2bf(w.z); T[kr][nc + 3] = f2bf(w.w);
    __syncthreads();
    const int nr = t >> 3, kc = (t & 7) * 4;
    ushort4 o;
    o.x = T[kc + 0][nr]; o.y = T[kc + 1][nr];
    o.z = T[kc + 2][nr]; o.w = T[kc + 3][nr];
    *reinterpret_cast<ushort4*>(&Wt[(size_t)(n0 + nr) * D_MODEL + k0 + kc]) = o;
}

// ===== R7 GEMM tile: 128 rows x 64 shorts (BK=64), 8x16B chunks/row. Swizzle is the
// attn Ks/Vs pattern (proven 0-conflict): LDS pos p holds (row=p>>3, c8=((p&7)-row)&7);
// read of (R, c8) at R*64 + ((c8+R)&7)*8. Halves barrier/vmcnt-drain count vs BK=32.

// ---------- MFMA bf16 GEMM (async swizzled staging). A [M][K]; Wt [N][K]. 128x128, BK=64. ----------
template <int SILU, int HAS_RES, int OUT_BF16>
__global__ __launch_bounds__(256) void mfma_gemm(const unsigned short* __restrict__ A,
                                                 const unsigned short* __restrict__ Wt,
                                                 const float* __restrict__ bias,
                                                 const float* __restrict__ res,
                                                 void* __restrict__ outP,
                                                 int M, int N, int K) {
    __shared__ unsigned short As[128 * 64];
    __shared__ unsigned short Bs[128 * 64];
    const int tid  = threadIdx.x;
    const int lane = tid & 63;
    const int wave = tid >> 6;
    int bx, by, bz;
    xcd_remap_gemm(bx, by, bz);
    const int row0 = by * 128, col0 = bx * 128;
    const int wr = (wave >> 1) * 64, wc = (wave & 1) * 64;

    floatx4 acc[4][4] = {};
    const int am = (lane & 15);

    // staging source offsets: 4 positions/thread/matrix
    size_t sA[4], sB[4];
#pragma unroll
    for (int q = 0; q < 4; ++q) {
        const int p = tid + q * 256;
        const int rs = p >> 3, c8 = (((p & 7) - rs) & 7) * 8;
        sA[q] = (size_t)(row0 + rs) * K + c8;
        sB[q] = (size_t)(col0 + rs) * K + c8;
    }

    int offA[2][4], offB[2][4];
#pragma unroll
    for (int kk = 0; kk < 2; ++kk)
#pragma unroll
        for (int i = 0; i < 4; ++i) {
            const int Ra = wr + i * 16 + am;
            offA[kk][i] = Ra * 64 + (((kk * 4 + (lane >> 4)) + Ra) & 7) * 8;
            const int Rb = wc + i * 16 + am;
            offB[kk][i] = Rb * 64 + (((kk * 4 + (lane >> 4)) + Rb) & 7) * 8;
        }

    for (int kt = 0; kt < K; kt += 64) {
#pragma unroll
        for (int q = 0; q < 4; ++q) {
            glds16(A  + sA[q] + kt, &As[(tid + q * 256) * 8]);
            glds16(Wt + sB[q] + kt, &Bs[(tid + q * 256) * 8]);
        }
        __syncthreads();
#pragma unroll
        for (int kk = 0; kk < 2; ++kk) {
            shortx8 af[4], bf[4];
#pragma unroll
            for (int i = 0; i < 4; ++i)
                af[i] = *reinterpret_cast<const shortx8*>(&As[offA[kk][i]]);
#pragma unroll
            for (int j = 0; j < 4; ++j)
                bf[j] = *reinterpret_cast<const shortx8*>(&Bs[offB[kk][j]]);
#pragma unroll
            for (int i = 0; i < 4; ++i)
#pragma unroll
                for (int j = 0; j < 4; ++j)
                    acc[i][j] = __builtin_amdgcn_mfma_f32_16x16x32_bf16(af[i], bf[j], acc[i][j], 0, 0, 0);
        }
        __syncthreads();
    }

    const int cq = (lane >> 4) * 4;
    const int cn = lane & 15;
#pragma unroll
    for (int i = 0; i < 4; ++i) {
#pragma unroll
        for (int j = 0; j < 4; ++j) {
            const int n = col0 + wc + j * 16 + cn;
            const float bb = bias[n];
#pragma unroll
            for (int r = 0; r < 4; ++r) {
                const int m = row0 + wr + i * 16 + cq + r;
                float v = acc[i][j][r] + bb;
                if (SILU) v = v / (1.0f + __expf(-v));
                if (HAS_RES) v += res[(size_t)m * N + n];
                if (OUT_BF16) ((unsigned short*)outP)[(size_t)m * N + n] = f2bf(v);
                else          ((float*)outP)[(size_t)m * N + n] = v;
            }
        }
    }
}

// ---------- Fused QKV GEMM: N=3072 over concatenated [3072][1024] weights ----------
__global__ __launch_bounds__(256) void mfma_gemm_qkv(const unsigned short* __restrict__ A,
                                                     const unsigned short* __restrict__ Wt,
                                                     const float* __restrict__ bq,
                                                     const float* __restrict__ bk,
                                                     const float* __restrict__ bv,
                                                     unsigned short* __restrict__ qb,
                                                     unsigned short* __restrict__ kb,
                                                     unsigned short* __restrict__ vtb) {
    const int K = D_MODEL, M = ROWS;
    __shared__ unsigned short As[128 * 64];
    __shared__ unsigned short Bs[128 * 64];
    const int tid  = threadIdx.x;
    const int lane = tid & 63;
    const int wave = tid >> 6;
    int bx, by, bz;
    xcd_remap_gemm(bx, by, bz);
    const int row0 = by * 128, col0 = bx * 128;
    const int wr = (wave >> 1) * 64, wc = (wave & 1) * 64;

    floatx4 acc[4][4] = {};
    const int am = (lane & 15);

    size_t sA[4], sB[4];
#pragma unroll
    for (int q = 0; q < 4; ++q) {
        const int p = tid + q * 256;
        const int rs = p >> 3, c8 = (((p & 7) - rs) & 7) * 8;
        sA[q] = (size_t)(row0 + rs) * K + c8;
        sB[q] = (size_t)(col0 + rs) * K + c8;
    }

    int offA[2][4], offB[2][4];
#pragma unroll
    for (int kk = 0; kk < 2; ++kk)
#pragma unroll
        for (int i = 0; i < 4; ++i) {
            const int Ra = wr + i * 16 + am;
            offA[kk][i] = Ra * 64 + (((kk * 4 + (lane >> 4)) + Ra) & 7) * 8;
            const int Rb = wc + i * 16 + am;
            offB[kk][i] = Rb * 64 + (((kk * 4 + (lane >> 4)) + Rb) & 7) * 8;
        }

    for (int kt = 0; kt < K; kt += 64) {
#pragma unroll
        for (int q = 0; q < 4; ++q) {
            glds16(A  + sA[q] + kt, &As[(tid + q * 256) * 8]);
            glds16(Wt + sB[q] + kt, &Bs[(tid + q * 256) * 8]);
        }
        __syncthreads();
#pragma unroll
        for (int kk = 0; kk < 2; ++kk) {
            shortx8 af[4], bf[4];
#pragma unroll
            for (int i = 0; i < 4; ++i)
                af[i] = *reinterpret_cast<const shortx8*>(&As[offA[kk][i]]);
#pragma unroll
            for (int j = 0; j < 4; ++j)
                bf[j] = *reinterpret_cast<const shortx8*>(&Bs[offB[kk][j]]);
#pragma unroll
            for (int i = 0; i < 4; ++i)
#pragma unroll
                for (int j = 0; j < 4; ++j)
                    acc[i][j] = __builtin_amdgcn_mfma_f32_16x16x32_bf16(af[i], bf[j], acc[i][j], 0, 0, 0);
        }
        __syncthreads();
    }

    const int cq = (lane >> 4) * 4;
    const int cn = lane & 15;
    const int sel = col0 >> 10;                 // 0=Q 1=K 2=V (block-uniform)
    const int nbase = col0 & 1023;
    const float* bias = (sel == 0) ? bq : (sel == 1) ? bk : bv;
    // fold 1/sqrt(Dk) AND log2(e) into Q so attention uses a single v_exp_f32
    // (exact: softmax(S) == softmax-base-2(S*log2e)); 0.125 * 1.4426950408889634
    const float scl = (sel == 0) ? 0.18033688511157292f : 1.0f;
#pragma unroll
    for (int i = 0; i < 4; ++i) {
#pragma unroll
        for (int j = 0; j < 4; ++j) {
            const int n = nbase + wc + j * 16 + cn;
            const float bb = bias[n];
            if (sel == 2) {
                const int m0 = row0 + wr + i * 16 + cq;
                ushort4 o;
                o.x = f2bf(acc[i][j][0] + bb);
                o.y = f2bf(acc[i][j][1] + bb);
                o.z = f2bf(acc[i][j][2] + bb);
                o.w = f2bf(acc[i][j][3] + bb);
                *reinterpret_cast<ushort4*>(&vtb[(size_t)n * M + m0]) = o;
            } else {
                unsigned short* dst = (sel == 0) ? qb : kb;
#pragma unroll
                for (int r = 0; r < 4; ++r) {
                    const int m = row0 + wr + i * 16 + cq + r;
                    dst[(size_t)m * D_MODEL + n] = f2bf((acc[i][j][r] + bb) * scl);
                }
            }
        }
    }
}

// ---------- Split-K GEMM: z = K-slice; raw bf16 partials ----------
__global__ __launch_bounds__(256) void mfma_gemm_splitk(const unsigned short* __restrict__ A,
                                                        const unsigned short* __restrict__ Wt,
                                                        unsigned short* __restrict__ parts,
                                                        int M, int N, int KS) {
    __shared__ unsigned short As[128 * 64];
    __shared__ unsigned short Bs[128 * 64];
    const int tid  = threadIdx.x;
    const int lane = tid & 63;
    const int wave = tid >> 6;
    int bx, by, bz;
    xcd_remap_gemm(bx, by, bz);
    const int row0 = by * 128, col0 = bx * 128;
    const int wr = (wave >> 1) * 64, wc = (wave & 1) * 64;
    const int K = KS * gridDim.z;
    const int kbeg = bz * KS;
    unsigned short* outp = parts + (size_t)bz * M * N;

    floatx4 acc[4][4] = {};
    const int am = (lane & 15);

    size_t sA[4], sB[4];
#pragma unroll
    for (int q = 0; q < 4; ++q) {
        const int p = tid + q * 256;
        const int rs = p >> 3, c8 = (((p & 7) - rs) & 7) * 8;
        sA[q] = (size_t)(row0 + rs) * K + c8;
        sB[q] = (size_t)(col0 + rs) * K + c8;
    }

    int offA[2][4], offB[2][4];
#pragma unroll
    for (int kk = 0; kk < 2; ++kk)
#pragma unroll
        for (int i = 0; i < 4; ++i) {
            const int Ra = wr + i * 16 + am;
            offA[kk][i] = Ra * 64 + (((kk * 4 + (lane >> 4)) + Ra) & 7) * 8;
            const int Rb = wc + i * 16 + am;
            offB[kk][i] = Rb * 64 + (((kk * 4 + (lane >> 4)) + Rb) & 7) * 8;
        }

    for (int kt = kbeg; kt < kbeg + KS; kt += 64) {
#pragma unroll
        for (int q = 0; q < 4; ++q) {
            glds16(A  + sA[q] + kt, &As[(tid + q * 256) * 8]);
            glds16(Wt + sB[q] + kt, &Bs[(tid + q * 256) * 8]);
        }
        __syncthreads();
#pragma unroll
        for (int kk = 0; kk < 2; ++kk) {
            shortx8 af[4], bf[4];
#pragma unroll
            for (int i = 0; i < 4; ++i)
                af[i] = *reinterpret_cast<const shortx8*>(&As[offA[kk][i]]);
#pragma unroll
            for (int j = 0; j < 4; ++j)
                bf[j] = *reinterpret_cast<const shortx8*>(&Bs[offB[kk][j]]);
#pragma unroll
            for (int i = 0; i < 4; ++i)
#pragma unroll
                for (int j = 0; j < 4; ++j)
                    acc[i][j] = __builtin_amdgcn_mfma_f32_16x16x32_bf16(af[i], bf[j], acc[i][j], 0, 0, 0);
        }
        __syncthreads();
    }

    const int cq = (lane >> 4) * 4;
    const int cn = lane & 15;
#pragma unroll
    for (int i = 0; i < 4; ++i)
#pragma unroll
        for (int j = 0; j < 4; ++j) {
            const int n = col0 + wc + j * 16 + cn;
#pragma unroll
            for (int r = 0; r < 4; ++r) {
                const int m = row0 + wr + i * 16 + cq + r;
                outp[(size_t)m * N + n] = f2bf(acc[i][j][r]);
            }
        }
}

// ---------- combine: out = p0 + p1 + bias + res ----------
__global__ __launch_bounds__(256) void combine_kernel(const unsigned short* __restrict__ p0,
                                                      const unsigned short* __restrict__ p1,
                                                      const float* __restrict__ bias,
                                                      const float* __restrict__ res,
                                                      float* __restrict__ out) {
    const size_t e0 = ((size_t)blockIdx.x * 256 + threadIdx.x) * 4;
    const int col = (int)(e0 & 1023);
    ushort4 a = *reinterpret_cast<const ushort4*>(&p0[e0]);
    ushort4 b = *reinterpret_cast<const ushort4*>(&p1[e0]);
    float4 r = *reinterpret_cast<const float4*>(&res[e0]);
    float4 o;
    o.x = bf2f(a.x) + bf2f(b.x) + bias[col + 0] + r.x;
    o.y = bf2f(a.y) + bf2f(b.y) + bias[col + 1] + r.y;
    o.z = bf2f(a.z) + bf2f(b.z) + bias[col + 2] + r.z;
    o.w = bf2f(a.w) + bf2f(b.w) + bias[col + 3] + r.w;
    *reinterpret_cast<float4*>(&out[e0]) = o;
}

// ---------- MFMA attention: R5 structure (QBLK=128, 8 waves) + R6 XCD-chunked remap.
// Chunk of 64 consecutive tiles = 16 q-tiles x 4 heads (one batch) -> per-XCD K/V
// working set 2 MB, L2-resident (verified R6: FETCH 69.7 -> 12.4 MB).
__global__ __launch_bounds__(512) void attn_mfma(const unsigned short* __restrict__ Q,
                                                 const unsigned short* __restrict__ K,
                                                 const unsigned short* __restrict__ Vt,
                                                 const int* __restrict__ mask,
                                                 unsigned short* __restrict__ att) {
    const int tid  = threadIdx.x;
    const int lane = tid & 63;
    const int wave = tid >> 6;          // 0..7
    // plain chunked XCD remap (row-major decode: q-tile fastest -> chunk shares K/V)
    const int o = blockIdx.x + gridDim.x * (blockIdx.y + gridDim.y * blockIdx.z);
    const int nwg = gridDim.x * gridDim.y * gridDim.z;
    const int t = (o & 7) * (nwg >> 3) + (o >> 3);
    const int qx = t % gridDim.x;
    const int h  = (t / gridDim.x) % gridDim.y;
    const int b  = t / (gridDim.x * gridDim.y);
    const int q0 = qx * 128;

    __shared__ unsigned short Qs[128 * PST];
    __shared__ unsigned short Ks[64 * 64];
    __shared__ unsigned short Vs[64 * 64];
    __shared__ unsigned short Ps[128 * PST];
    __shared__ int mk[64];

    const int am = lane & 15;
    const int aq = (lane >> 4) * 8;
    const int cq = (lane >> 4) * 4;
    const int cn = lane & 15;

    // stage Q tile (once, via VGPR; padded layout): 128 rows x 8 chunks = 1024 chunks
    for (int c = tid; c < 1024; c += 512) {
        const int r = c >> 3, off = (c & 7) * 8;
        *reinterpret_cast<uint4*>(&Qs[r * PST + off]) =
            *reinterpret_cast<const uint4*>(&Q[(size_t)(b * L_SEQ + q0 + r) * D_MODEL + h * D_K + off]);
    }

    // swizzled staging: LDS chunk p holds (row=p>>3, c8=((p&7)-row)&7); 512 chunks,
    // exactly one per thread for each of Ks and Vs.
    const int p0 = tid, sr0 = p0 >> 3, sc0 = (((p0 & 7) - sr0) & 7) * 8;
    const unsigned short* K0 = K + (size_t)(b * L_SEQ + sr0) * D_MODEL + h * D_K + sc0;
    const unsigned short* V0 = Vt + (size_t)(h * D_K + sr0) * ROWS + b * L_SEQ + sc0;

    // fragment read offsets (loop-invariant): row R = t*16+am, chunk c8 = kt*4 + (lane>>4)
    int offF[2][4];
#pragma unroll
    for (int kt = 0; kt < 2; ++kt)
#pragma unroll
        for (int tt = 0; tt < 4; ++tt) {
            const int R = tt * 16 + am;
            offF[kt][tt] = R * 64 + (((kt * 4 + (lane >> 4)) + R) & 7) * 8;
        }

    __syncthreads();

    shortx8 aQ[2];
    aQ[0] = *reinterpret_cast<const shortx8*>(&Qs[(wave * 16 + am) * PST + aq]);
    aQ[1] = *reinterpret_cast<const shortx8*>(&Qs[(wave * 16 + am) * PST + 32 + aq]);

    floatx4 oacc[4] = {};
    float lsum[4] = {0.0f, 0.0f, 0.0f, 0.0f};

    for (int j0 = 0; j0 < L_SEQ; j0 += 64) {
        __syncthreads();
        glds16(K0 + (size_t)j0 * D_MODEL, &Ks[p0 * 8]);
        glds16(V0 + j0, &Vs[p0 * 8]);
        if (tid < 64) mk[tid] = mask[b * L_SEQ + j0 + tid];
        __syncthreads();

        floatx4 sacc[4] = {};
#pragma unroll
        for (int kt = 0; kt < 2; ++kt)
#pragma unroll
            for (int jt = 0; jt < 4; ++jt) {
                shortx8 bK = *reinterpret_cast<const shortx8*>(&Ks[offF[kt][jt]]);
                sacc[jt] = __builtin_amdgcn_mfma_f32_16x16x32_bf16(aQ[kt], bK, sacc[jt], 0, 0, 0);
            }
        // P = exp2(S) masked (Q pre-scaled by log2e/8 -> single v_exp_f32);
        // truncate-cast to bf16
#pragma unroll
        for (int jt = 0; jt < 4; ++jt) {
            const int mv = mk[jt * 16 + cn];
#pragma unroll
            for (int r = 0; r < 4; ++r) {
                float p = mv ? __builtin_amdgcn_exp2f(sacc[jt][r]) : 0.0f;
                lsum[r] += p;
                Ps[(wave * 16 + cq + r) * PST + jt * 16 + cn] =
                    (unsigned short)(__float_as_uint(p) >> 16);
            }
        }
        // O += P x V (wave-private Ps rows)
#pragma unroll
        for (int kt = 0; kt < 2; ++kt) {
            shortx8 aP = *reinterpret_cast<const shortx8*>(&Ps[(wave * 16 + am) * PST + kt * 32 + aq]);
#pragma unroll
            for (int dt = 0; dt < 4; ++dt) {
                shortx8 bV = *reinterpret_cast<const shortx8*>(&Vs[offF[kt][dt]]);
                oacc[dt] = __builtin_amdgcn_mfma_f32_16x16x32_bf16(aP, bV, oacc[dt], 0, 0, 0);
            }
        }
    }

#pragma unroll
    for (int r = 0; r < 4; ++r) {
        float t2 = lsum[r];
        t2 += __shfl_xor(t2, 1);
        t2 += __shfl_xor(t2, 2);
        t2 += __shfl_xor(t2, 4);
        t2 += __shfl_xor(t2, 8);
        lsum[r] = 1.0f / t2;
    }
#pragma unroll
    for (int dt = 0; dt < 4; ++dt)
#pragma unroll
        for (int r = 0; r < 4; ++r) {
            att[(size_t)(b * L_SEQ + q0 + wave * 16 + cq + r) * D_MODEL + h * D_K + dt * 16 + cn] =
                f2bf(oacc[dt][r] * lsum[r]);
        }
}

extern "C" void kernel_launch(void* const* d_in, const int* in_sizes, int n_in,
                              void* d_out, int out_size, void* d_ws, size_t ws_size,
                              hipStream_t stream) {
    const float* x     = (const float*)d_in[0];
    const int*   mask  = (const int*)d_in[1];
    const float* ln1_g = (const float*)d_in[2];
    const float* ln1_b = (const float*)d_in[3];
    const float* Wq    = (const float*)d_in[4];
    const float* bq    = (const float*)d_in[5];
    const float* Wk    = (const float*)d_in[6];
    const float* bk    = (const float*)d_in[7];
    const float* Wv    = (const float*)d_in[8];
    const float* bv    = (const float*)d_in[9];
    const float* Wo    = (const float*)d_in[10];
    const float* bo    = (const float*)d_in[11];
    const float* ln2_g = (const float*)d_in[12];
    const float* ln2_b = (const float*)d_in[13];
    const float* W1    = (const float*)d_in[14];
    const float* b1    = (const float*)d_in[15];
    const float* W2    = (const float*)d_in[16];
    const float* b2    = (const float*)d_in[17];
    float* out = (float*)d_out;

    float* ws = (float*)d_ws;
    const size_t SZ = (size_t)ROWS * D_MODEL;  // 4M elements; fp32 slot = 16 MB

    unsigned short* nx  = (unsigned short*)(ws + 0 * SZ);   // 0-8 MB: LN1/LN2 out bf16
    unsigned short* qb  = (unsigned short*)(ws + 1 * SZ);   // 16-24: Q bf16 (pre-scaled)
    unsigned short* kb  = qb + SZ;                          // 24-32: K bf16
    unsigned short* vtb = (unsigned short*)(ws + 2 * SZ);   // 32-40: V^T bf16
    unsigned short* attb = vtb + SZ;                        // 40-48: att bf16
    float* x1  = out;                                       // residual stream in d_out
    unsigned short* nx2 = nx;                               // slot0 reuse
    unsigned short* h = (unsigned short*)(ws + 2 * SZ);     // 32-64: FFN hidden bf16
    unsigned short* parts = (unsigned short*)(ws + 0 * SZ); // 0-16: FFN2 split-K partials

    unsigned short* WqkvT = (unsigned short*)(ws + 4 * SZ); // 64-70: concat [3072][1024]
    unsigned short* WqT = WqkvT;
    unsigned short* WkT = WqkvT + (size_t)D_MODEL * D_MODEL;
    unsigned short* WvT = WkT + (size_t)D_MODEL * D_MODEL;
    unsigned short* WoT = WvT + (size_t)D_MODEL * D_MODEL;  // 70-72
    unsigned short* W1T = (unsigned short*)(ws + 1 * SZ);   // 16-24 (qb/kb dead after attn)
    unsigned short* W2T = W1T + (size_t)D_MODEL * FFN_DIM;  // 24-32

    ln_kernel<<<ROWS, 256, 0, stream>>>(x, ln1_g, ln1_b, nx);

    transpose_cast4<<<dim3(32, 32, 4), 256, 0, stream>>>(Wq, Wk, Wv, Wo, WqT, WkT, WvT, WoT);

    mfma_gemm_qkv<<<dim3(3072 / 128, ROWS / 128), 256, 0, stream>>>(
        nx, WqkvT, bq, bk, bv, qb, kb, vtb);

    attn_mfma<<<dim3(L_SEQ / 128, N_HEAD, B_SZ), 512, 0, stream>>>(qb, kb, vtb, mask, attb);

    transpose_cast<<<dim3(FFN_DIM / 32, D_MODEL / 32), 256, 0, stream>>>(W1, W1T, D_MODEL, FFN_DIM);
    transpose_cast<<<dim3(D_MODEL / 32, FFN_DIM / 32), 256, 0, stream>>>(W2, W2T, FFN_DIM, D_MODEL);

    mfma_gemm<0, 1, 0><<<dim3(D_MODEL / 128, ROWS / 128), 256, 0, stream>>>(
        attb, WoT, bo, x, x1, ROWS, D_MODEL, D_MODEL);

    ln_kernel<<<ROWS, 256, 0, stream>>>(x1, ln2_g, ln2_b, nx2);

    mfma_gemm<1, 0, 1><<<dim3(FFN_DIM / 128, ROWS / 128), 256, 0, stream>>>(
        nx2, W1T, b1, nullptr, h, ROWS, FFN_DIM, D_MODEL);

    mfma_gemm_splitk<<<dim3(D_MODEL / 128, ROWS / 128, 2), 256, 0, stream>>>(
        h, W2T, parts, ROWS, D_MODEL, FFN_DIM / 2);
    combine_kernel<<<(ROWS * D_MODEL) / 1024, 256, 0, stream>>>(
        parts, parts + SZ, b2, x1, out);
}

// Round 8
// 368.711 us; speedup vs baseline: 1.1609x; 1.0071x over previous
//
#include <hip/hip_runtime.h>
#include <hip/hip_bf16.h>

#define D_MODEL 1024
#define N_HEAD  16
#define D_K     64
#define FFN_DIM 4096
#define B_SZ    2
#define L_SEQ   2048
#define ROWS    (B_SZ * L_SEQ)   // 4096
#define PST     68               // Ps/Qs LDS row stride (shorts): proven 0-conflict (R9/R10)

typedef float  floatx4 __attribute__((ext_vector_type(4)));
typedef short  shortx8 __attribute__((ext_vector_type(8)));

__device__ __forceinline__ unsigned short f2bf(float f) {
    unsigned int u = __float_as_uint(f);
    unsigned int rounding = 0x7fffu + ((u >> 16) & 1u);
    return (unsigned short)((u + rounding) >> 16);
}
__device__ __forceinline__ float bf2f(unsigned short u) {
    return __uint_as_float(((unsigned int)u) << 16);
}

// async global->LDS 16B copy; LDS dest is wave-uniform base + lane*16
__device__ __forceinline__ void glds16(const unsigned short* g, unsigned short* l) {
    __builtin_amdgcn_global_load_lds(
        (const __attribute__((address_space(1))) unsigned int*)g,
        (__attribute__((address_space(3))) unsigned int*)l, 16, 0, 0);
}

// ---- T1: XCD-chunked blockIdx remap (R6, verified: attn FETCH 69.7->12.4 MB).
// Linear wg id round-robins the 8 XCDs (id%8 = XCD). Decode groups of 8 col-tiles x
// consecutive row-tiles so blocks sharing A-strips/B-panels co-reside per-XCD L2.
// Bijective when nwg%8==0 and gx%8==0 (all our grids).
__device__ __forceinline__ void xcd_remap_gemm(int& bx, int& by, int& bz) {
    const int gx = gridDim.x, gy = gridDim.y, gz = gridDim.z;
    const int o = blockIdx.x + gx * (blockIdx.y + gy * blockIdx.z);
    const int nwg = gx * gy * gz;
    const int t = (o & 7) * (nwg >> 3) + (o >> 3);
    const int zsz = gx * gy;
    bz = t / zsz;
    const int w = t - bz * zsz;
    const int grp = w / (8 * gy);
    const int in  = w - grp * (8 * gy);
    by = in >> 3;
    bx = grp * 8 + (in & 7);
}

// ---------- LayerNorm: one block per row of 1024, fp32 in -> bf16 out ----------
__global__ __launch_bounds__(256) void ln_kernel(const float* __restrict__ x,
                                                 const float* __restrict__ g,
                                                 const float* __restrict__ b,
                                                 unsigned short* __restrict__ out) {
    const int row = blockIdx.x;
    const int tid = threadIdx.x;
    const float* xr = x + (size_t)row * D_MODEL;
    float4 xv = *reinterpret_cast<const float4*>(&xr[tid * 4]);
    float v[4] = {xv.x, xv.y, xv.z, xv.w};
    float s = v[0] + v[1] + v[2] + v[3];
    float ss = v[0] * v[0] + v[1] * v[1] + v[2] * v[2] + v[3] * v[3];
    __shared__ float r1[256], r2[256];
    r1[tid] = s; r2[tid] = ss;
    __syncthreads();
    for (int off = 128; off > 0; off >>= 1) {
        if (tid < off) { r1[tid] += r1[tid + off]; r2[tid] += r2[tid + off]; }
        __syncthreads();
    }
    const float mean = r1[0] * (1.0f / D_MODEL);
    const float var  = r2[0] * (1.0f / D_MODEL) - mean * mean;
    const float inv  = rsqrtf(var + 1e-5f);
    unsigned short* orow = out + (size_t)row * D_MODEL;
    ushort4 o;
    o.x = f2bf((v[0] - mean) * inv * g[tid * 4 + 0] + b[tid * 4 + 0]);
    o.y = f2bf((v[1] - mean) * inv * g[tid * 4 + 1] + b[tid * 4 + 1]);
    o.z = f2bf((v[2] - mean) * inv * g[tid * 4 + 2] + b[tid * 4 + 2]);
    o.w = f2bf((v[3] - mean) * inv * g[tid * 4 + 3] + b[tid * 4 + 3]);
    *reinterpret_cast<ushort4*>(&orow[tid * 4]) = o;
}

// ---------- Transpose+cast: W fp32 [K][N] -> Wt bf16 [N][K] ----------
__global__ __launch_bounds__(256) void transpose_cast(const float* __restrict__ W,
                                                      unsigned short* __restrict__ Wt,
                                                      int K, int N) {
    __shared__ unsigned short T[32][33];
    const int t = threadIdx.x;
    const int k0 = blockIdx.y * 32, n0 = blockIdx.x * 32;
    const int kr = t >> 3, nc = (t & 7) * 4;
    float4 w = *reinterpret_cast<const float4*>(&W[(size_t)(k0 + kr) * N + n0 + nc]);
    T[kr][nc + 0] = f2bf(w.x); T[kr][nc + 1] = f2bf(w.y);
    T[kr][nc + 2] = f2bf(w.z); T[kr][nc + 3] = f2bf(w.w);
    __syncthreads();
    const int nr = t >> 3, kc = (t & 7) * 4;
    ushort4 o;
    o.x = T[kc + 0][nr]; o.y = T[kc + 1][nr];
    o.z = T[kc + 2][nr]; o.w = T[kc + 3][nr];
    *reinterpret_cast<ushort4*>(&Wt[(size_t)(n0 + nr) * K + k0 + kc]) = o;
}

// ---------- 4x square (1024x1024) transpose in one dispatch, z selects matrix ----------
__global__ __launch_bounds__(256) void transpose_cast4(const float* s0, const float* s1,
                                                       const float* s2, const float* s3,
                                                       unsigned short* d0, unsigned short* d1,
                                                       unsigned short* d2, unsigned short* d3) {
    const int z = blockIdx.z;
    const float* W = (z == 0) ? s0 : (z == 1) ? s1 : (z == 2) ? s2 : s3;
    unsigned short* Wt = (z == 0) ? d0 : (z == 1) ? d1 : (z == 2) ? d2 : d3;
    __shared__ unsigned short T[32][33];
    const int t = threadIdx.x;
    const int k0 = blockIdx.y * 32, n0 = blockIdx.x * 32;
    const int kr = t >> 3, nc = (t & 7) * 4;
    float4 w = *reinterpret_cast<const float4*>(&W[(size_t)(k0 + kr) * D_MODEL + n0 + nc]);
    T[kr][nc + 0] = f2bf(w.x); T[kr][nc + 1] = f2bf(w.y);
    T[kr][nc + 2] = f2bf(w.z); T[kr][nc + 3] = f2bf(w.w);
    __syncthreads();
    const int nr = t >> 3, kc = (t & 7) * 4;
    ushort4 o;
    o.x = T[kc + 0][nr]; o.y = T[kc + 1][nr];
    o.z = T[kc + 2][nr]; o.w = T[kc + 3][nr];
    *reinterpret_cast<ushort4*>(&Wt[(size_t)(n0 + nr) * D_MODEL + k0 + kc]) = o;
}

// ===== R7 GEMM tile: 128 rows x 64 shorts (BK=64), 8x16B chunks/row. Swizzle is the
// attn Ks/Vs pattern (proven 0-conflict): LDS pos p holds (row=p>>3, c8=((p&7)-row)&7);
// read of (R, c8) at R*64 + ((c8+R)&7)*8. Halves barrier/vmcnt-drain count vs BK=32.

// ---------- MFMA bf16 GEMM (async swizzled staging). A [M][K]; Wt [N][K]. 128x128, BK=64. ----------
template <int SILU, int HAS_RES, int OUT_BF16>
__global__ __launch_bounds__(256) void mfma_gemm(const unsigned short* __restrict__ A,
                                                 const unsigned short* __restrict__ Wt,
                                                 const float* __restrict__ bias,
                                                 const float* __restrict__ res,
                                                 void* __restrict__ outP,
                                                 int M, int N, int K) {
    __shared__ unsigned short As[128 * 64];
    __shared__ unsigned short Bs[128 * 64];
    const int tid  = threadIdx.x;
    const int lane = tid & 63;
    const int wave = tid >> 6;
    int bx, by, bz;
    xcd_remap_gemm(bx, by, bz);
    const int row0 = by * 128, col0 = bx * 128;
    const int wr = (wave >> 1) * 64, wc = (wave & 1) * 64;

    floatx4 acc[4][4] = {};
    const int am = (lane & 15);

    // staging source offsets: 4 positions/thread/matrix
    size_t sA[4], sB[4];
#pragma unroll
    for (int q = 0; q < 4; ++q) {
        const int p = tid + q * 256;
        const int rs = p >> 3, c8 = (((p & 7) - rs) & 7) * 8;
        sA[q] = (size_t)(row0 + rs) * K + c8;
        sB[q] = (size_t)(col0 + rs) * K + c8;
    }

    int offA[2][4], offB[2][4];
#pragma unroll
    for (int kk = 0; kk < 2; ++kk)
#pragma unroll
        for (int i = 0; i < 4; ++i) {
            const int Ra = wr + i * 16 + am;
            offA[kk][i] = Ra * 64 + (((kk * 4 + (lane >> 4)) + Ra) & 7) * 8;
            const int Rb = wc + i * 16 + am;
            offB[kk][i] = Rb * 64 + (((kk * 4 + (lane >> 4)) + Rb) & 7) * 8;
        }

    for (int kt = 0; kt < K; kt += 64) {
#pragma unroll
        for (int q = 0; q < 4; ++q) {
            glds16(A  + sA[q] + kt, &As[(tid + q * 256) * 8]);
            glds16(Wt + sB[q] + kt, &Bs[(tid + q * 256) * 8]);
        }
        __syncthreads();
#pragma unroll
        for (int kk = 0; kk < 2; ++kk) {
            shortx8 af[4], bf[4];
#pragma unroll
            for (int i = 0; i < 4; ++i)
                af[i] = *reinterpret_cast<const shortx8*>(&As[offA[kk][i]]);
#pragma unroll
            for (int j = 0; j < 4; ++j)
                bf[j] = *reinterpret_cast<const shortx8*>(&Bs[offB[kk][j]]);
#pragma unroll
            for (int i = 0; i < 4; ++i)
#pragma unroll
                for (int j = 0; j < 4; ++j)
                    acc[i][j] = __builtin_amdgcn_mfma_f32_16x16x32_bf16(af[i], bf[j], acc[i][j], 0, 0, 0);
        }
        __syncthreads();
    }

    const int cq = (lane >> 4) * 4;
    const int cn = lane & 15;
#pragma unroll
    for (int i = 0; i < 4; ++i) {
#pragma unroll
        for (int j = 0; j < 4; ++j) {
            const int n = col0 + wc + j * 16 + cn;
            const float bb = bias[n];
#pragma unroll
            for (int r = 0; r < 4; ++r) {
                const int m = row0 + wr + i * 16 + cq + r;
                float v = acc[i][j][r] + bb;
                if (SILU) v = v / (1.0f + __expf(-v));
                if (HAS_RES) v += res[(size_t)m * N + n];
                if (OUT_BF16) ((unsigned short*)outP)[(size_t)m * N + n] = f2bf(v);
                else          ((float*)outP)[(size_t)m * N + n] = v;
            }
        }
    }
}

// ---------- Fused QKV GEMM: N=3072 over concatenated [3072][1024] weights ----------
__global__ __launch_bounds__(256) void mfma_gemm_qkv(const unsigned short* __restrict__ A,
                                                     const unsigned short* __restrict__ Wt,
                                                     const float* __restrict__ bq,
                                                     const float* __restrict__ bk,
                                                     const float* __restrict__ bv,
                                                     unsigned short* __restrict__ qb,
                                                     unsigned short* __restrict__ kb,
                                                     unsigned short* __restrict__ vtb) {
    const int K = D_MODEL, M = ROWS;
    __shared__ unsigned short As[128 * 64];
    __shared__ unsigned short Bs[128 * 64];
    const int tid  = threadIdx.x;
    const int lane = tid & 63;
    const int wave = tid >> 6;
    int bx, by, bz;
    xcd_remap_gemm(bx, by, bz);
    const int row0 = by * 128, col0 = bx * 128;
    const int wr = (wave >> 1) * 64, wc = (wave & 1) * 64;

    floatx4 acc[4][4] = {};
    const int am = (lane & 15);

    size_t sA[4], sB[4];
#pragma unroll
    for (int q = 0; q < 4; ++q) {
        const int p = tid + q * 256;
        const int rs = p >> 3, c8 = (((p & 7) - rs) & 7) * 8;
        sA[q] = (size_t)(row0 + rs) * K + c8;
        sB[q] = (size_t)(col0 + rs) * K + c8;
    }

    int offA[2][4], offB[2][4];
#pragma unroll
    for (int kk = 0; kk < 2; ++kk)
#pragma unroll
        for (int i = 0; i < 4; ++i) {
            const int Ra = wr + i * 16 + am;
            offA[kk][i] = Ra * 64 + (((kk * 4 + (lane >> 4)) + Ra) & 7) * 8;
            const int Rb = wc + i * 16 + am;
            offB[kk][i] = Rb * 64 + (((kk * 4 + (lane >> 4)) + Rb) & 7) * 8;
        }

    for (int kt = 0; kt < K; kt += 64) {
#pragma unroll
        for (int q = 0; q < 4; ++q) {
            glds16(A  + sA[q] + kt, &As[(tid + q * 256) * 8]);
            glds16(Wt + sB[q] + kt, &Bs[(tid + q * 256) * 8]);
        }
        __syncthreads();
#pragma unroll
        for (int kk = 0; kk < 2; ++kk) {
            shortx8 af[4], bf[4];
#pragma unroll
            for (int i = 0; i < 4; ++i)
                af[i] = *reinterpret_cast<const shortx8*>(&As[offA[kk][i]]);
#pragma unroll
            for (int j = 0; j < 4; ++j)
                bf[j] = *reinterpret_cast<const shortx8*>(&Bs[offB[kk][j]]);
#pragma unroll
            for (int i = 0; i < 4; ++i)
#pragma unroll
                for (int j = 0; j < 4; ++j)
                    acc[i][j] = __builtin_amdgcn_mfma_f32_16x16x32_bf16(af[i], bf[j], acc[i][j], 0, 0, 0);
        }
        __syncthreads();
    }

    const int cq = (lane >> 4) * 4;
    const int cn = lane & 15;
    const int sel = col0 >> 10;                 // 0=Q 1=K 2=V (block-uniform)
    const int nbase = col0 & 1023;
    const float* bias = (sel == 0) ? bq : (sel == 1) ? bk : bv;
    // fold 1/sqrt(Dk) AND log2(e) into Q so attention uses a single v_exp_f32
    // (exact: softmax(S) == softmax-base-2(S*log2e)); 0.125 * 1.4426950408889634
    const float scl = (sel == 0) ? 0.18033688511157292f : 1.0f;
#pragma unroll
    for (int i = 0; i < 4; ++i) {
#pragma unroll
        for (int j = 0; j < 4; ++j) {
            const int n = nbase + wc + j * 16 + cn;
            const float bb = bias[n];
            if (sel == 2) {
                const int m0 = row0 + wr + i * 16 + cq;
                ushort4 o;
                o.x = f2bf(acc[i][j][0] + bb);
                o.y = f2bf(acc[i][j][1] + bb);
                o.z = f2bf(acc[i][j][2] + bb);
                o.w = f2bf(acc[i][j][3] + bb);
                *reinterpret_cast<ushort4*>(&vtb[(size_t)n * M + m0]) = o;
            } else {
                unsigned short* dst = (sel == 0) ? qb : kb;
#pragma unroll
                for (int r = 0; r < 4; ++r) {
                    const int m = row0 + wr + i * 16 + cq + r;
                    dst[(size_t)m * D_MODEL + n] = f2bf((acc[i][j][r] + bb) * scl);
                }
            }
        }
    }
}

// ---------- Split-K GEMM: z = K-slice; raw bf16 partials ----------
__global__ __launch_bounds__(256) void mfma_gemm_splitk(const unsigned short* __restrict__ A,
                                                        const unsigned short* __restrict__ Wt,
                                                        unsigned short* __restrict__ parts,
                                                        int M, int N, int KS) {
    __shared__ unsigned short As[128 * 64];
    __shared__ unsigned short Bs[128 * 64];
    const int tid  = threadIdx.x;
    const int lane = tid & 63;
    const int wave = tid >> 6;
    int bx, by, bz;
    xcd_remap_gemm(bx, by, bz);
    const int row0 = by * 128, col0 = bx * 128;
    const int wr = (wave >> 1) * 64, wc = (wave & 1) * 64;
    const int K = KS * gridDim.z;
    const int kbeg = bz * KS;
    unsigned short* outp = parts + (size_t)bz * M * N;

    floatx4 acc[4][4] = {};
    const int am = (lane & 15);

    size_t sA[4], sB[4];
#pragma unroll
    for (int q = 0; q < 4; ++q) {
        const int p = tid + q * 256;
        const int rs = p >> 3, c8 = (((p & 7) - rs) & 7) * 8;
        sA[q] = (size_t)(row0 + rs) * K + c8;
        sB[q] = (size_t)(col0 + rs) * K + c8;
    }

    int offA[2][4], offB[2][4];
#pragma unroll
    for (int kk = 0; kk < 2; ++kk)
#pragma unroll
        for (int i = 0; i < 4; ++i) {
            const int Ra = wr + i * 16 + am;
            offA[kk][i] = Ra * 64 + (((kk * 4 + (lane >> 4)) + Ra) & 7) * 8;
            const int Rb = wc + i * 16 + am;
            offB[kk][i] = Rb * 64 + (((kk * 4 + (lane >> 4)) + Rb) & 7) * 8;
        }

    for (int kt = kbeg; kt < kbeg + KS; kt += 64) {
#pragma unroll
        for (int q = 0; q < 4; ++q) {
            glds16(A  + sA[q] + kt, &As[(tid + q * 256) * 8]);
            glds16(Wt + sB[q] + kt, &Bs[(tid + q * 256) * 8]);
        }
        __syncthreads();
#pragma unroll
        for (int kk = 0; kk < 2; ++kk) {
            shortx8 af[4], bf[4];
#pragma unroll
            for (int i = 0; i < 4; ++i)
                af[i] = *reinterpret_cast<const shortx8*>(&As[offA[kk][i]]);
#pragma unroll
            for (int j = 0; j < 4; ++j)
                bf[j] = *reinterpret_cast<const shortx8*>(&Bs[offB[kk][j]]);
#pragma unroll
            for (int i = 0; i < 4; ++i)
#pragma unroll
                for (int j = 0; j < 4; ++j)
                    acc[i][j] = __builtin_amdgcn_mfma_f32_16x16x32_bf16(af[i], bf[j], acc[i][j], 0, 0, 0);
        }
        __syncthreads();
    }

    const int cq = (lane >> 4) * 4;
    const int cn = lane & 15;
#pragma unroll
    for (int i = 0; i < 4; ++i)
#pragma unroll
        for (int j = 0; j < 4; ++j) {
            const int n = col0 + wc + j * 16 + cn;
#pragma unroll
            for (int r = 0; r < 4; ++r) {
                const int m = row0 + wr + i * 16 + cq + r;
                outp[(size_t)m * N + n] = f2bf(acc[i][j][r]);
            }
        }
}

// ---------- combine: out = p0 + p1 + bias + res ----------
__global__ __launch_bounds__(256) void combine_kernel(const unsigned short* __restrict__ p0,
                                                      const unsigned short* __restrict__ p1,
                                                      const float* __restrict__ bias,
                                                      const float* __restrict__ res,
                                                      float* __restrict__ out) {
    const size_t e0 = ((size_t)blockIdx.x * 256 + threadIdx.x) * 4;
    const int col = (int)(e0 & 1023);
    ushort4 a = *reinterpret_cast<const ushort4*>(&p0[e0]);
    ushort4 b = *reinterpret_cast<const ushort4*>(&p1[e0]);
    float4 r = *reinterpret_cast<const float4*>(&res[e0]);
    float4 o;
    o.x = bf2f(a.x) + bf2f(b.x) + bias[col + 0] + r.x;
    o.y = bf2f(a.y) + bf2f(b.y) + bias[col + 1] + r.y;
    o.z = bf2f(a.z) + bf2f(b.z) + bias[col + 2] + r.z;
    o.w = bf2f(a.w) + bf2f(b.w) + bias[col + 3] + r.w;
    *reinterpret_cast<float4*>(&out[e0]) = o;
}

// ---------- MFMA attention: R8 = two 64-row K/V sub-tiles per barrier pair (the R7
// BK-doubling recipe applied to attn). Ks/Vs double-sized; Ps (wave-private rows,
// written+read by the same wave -> DS in-order, no cross-wave dep) is REUSED across
// sub-tiles, so no Ps growth. Barriers per unit work halve. LDS ~66.5 KB -> still
// 2 blocks/CU (grid-limited at 512 blocks), occupancy unchanged vs R7.
__global__ __launch_bounds__(512) void attn_mfma(const unsigned short* __restrict__ Q,
                                                 const unsigned short* __restrict__ K,
                                                 const unsigned short* __restrict__ Vt,
                                                 const int* __restrict__ mask,
                                                 unsigned short* __restrict__ att) {
    const int tid  = threadIdx.x;
    const int lane = tid & 63;
    const int wave = tid >> 6;          // 0..7
    // plain chunked XCD remap (row-major decode: q-tile fastest -> chunk shares K/V)
    const int o = blockIdx.x + gridDim.x * (blockIdx.y + gridDim.y * blockIdx.z);
    const int nwg = gridDim.x * gridDim.y * gridDim.z;
    const int t = (o & 7) * (nwg >> 3) + (o >> 3);
    const int qx = t % gridDim.x;
    const int h  = (t / gridDim.x) % gridDim.y;
    const int b  = t / (gridDim.x * gridDim.y);
    const int q0 = qx * 128;

    __shared__ unsigned short Qs[128 * PST];
    __shared__ unsigned short Ks[2][64 * 64];
    __shared__ unsigned short Vs[2][64 * 64];
    __shared__ unsigned short Ps[128 * PST];
    __shared__ int mk[128];

    const int am = lane & 15;
    const int aq = (lane >> 4) * 8;
    const int cq = (lane >> 4) * 4;
    const int cn = lane & 15;

    // stage Q tile (once, via VGPR; padded layout): 128 rows x 8 chunks = 1024 chunks
    for (int c = tid; c < 1024; c += 512) {
        const int r = c >> 3, off = (c & 7) * 8;
        *reinterpret_cast<uint4*>(&Qs[r * PST + off]) =
            *reinterpret_cast<const uint4*>(&Q[(size_t)(b * L_SEQ + q0 + r) * D_MODEL + h * D_K + off]);
    }

    // swizzled staging: LDS chunk p holds (row=p>>3, c8=((p&7)-row)&7); 512 chunks
    // per sub-tile, one per thread per sub-tile for each of Ks and Vs.
    const int p0 = tid, sr0 = p0 >> 3, sc0 = (((p0 & 7) - sr0) & 7) * 8;
    const unsigned short* K0 = K + (size_t)(b * L_SEQ + sr0) * D_MODEL + h * D_K + sc0;
    const unsigned short* V0 = Vt + (size_t)(h * D_K + sr0) * ROWS + b * L_SEQ + sc0;

    // fragment read offsets (loop-invariant): row R = t*16+am, chunk c8 = kt*4 + (lane>>4)
    int offF[2][4];
#pragma unroll
    for (int kt = 0; kt < 2; ++kt)
#pragma unroll
        for (int tt = 0; tt < 4; ++tt) {
            const int R = tt * 16 + am;
            offF[kt][tt] = R * 64 + (((kt * 4 + (lane >> 4)) + R) & 7) * 8;
        }

    __syncthreads();

    shortx8 aQ[2];
    aQ[0] = *reinterpret_cast<const shortx8*>(&Qs[(wave * 16 + am) * PST + aq]);
    aQ[1] = *reinterpret_cast<const shortx8*>(&Qs[(wave * 16 + am) * PST + 32 + aq]);

    floatx4 oacc[4] = {};
    float lsum[4] = {0.0f, 0.0f, 0.0f, 0.0f};

    for (int j0 = 0; j0 < L_SEQ; j0 += 128) {
        __syncthreads();
        glds16(K0 + (size_t)j0 * D_MODEL,        &Ks[0][p0 * 8]);
        glds16(K0 + (size_t)(j0 + 64) * D_MODEL, &Ks[1][p0 * 8]);
        glds16(V0 + j0,      &Vs[0][p0 * 8]);
        glds16(V0 + j0 + 64, &Vs[1][p0 * 8]);
        if (tid < 128) mk[tid] = mask[b * L_SEQ + j0 + tid];
        __syncthreads();

#pragma unroll
        for (int u = 0; u < 2; ++u) {
            floatx4 sacc[4] = {};
#pragma unroll
            for (int kt = 0; kt < 2; ++kt)
#pragma unroll
                for (int jt = 0; jt < 4; ++jt) {
                    shortx8 bK = *reinterpret_cast<const shortx8*>(&Ks[u][offF[kt][jt]]);
                    sacc[jt] = __builtin_amdgcn_mfma_f32_16x16x32_bf16(aQ[kt], bK, sacc[jt], 0, 0, 0);
                }
            // P = exp2(S) masked (Q pre-scaled by log2e/8 -> single v_exp_f32);
            // truncate-cast to bf16
#pragma unroll
            for (int jt = 0; jt < 4; ++jt) {
                const int mv = mk[u * 64 + jt * 16 + cn];
#pragma unroll
                for (int r = 0; r < 4; ++r) {
                    float p = mv ? __builtin_amdgcn_exp2f(sacc[jt][r]) : 0.0f;
                    lsum[r] += p;
                    Ps[(wave * 16 + cq + r) * PST + jt * 16 + cn] =
                        (unsigned short)(__float_as_uint(p) >> 16);
                }
            }
            // O += P x V (wave-private Ps rows; DS in-order within wave -> safe reuse)
#pragma unroll
            for (int kt = 0; kt < 2; ++kt) {
                shortx8 aP = *reinterpret_cast<const shortx8*>(&Ps[(wave * 16 + am) * PST + kt * 32 + aq]);
#pragma unroll
                for (int dt = 0; dt < 4; ++dt) {
                    shortx8 bV = *reinterpret_cast<const shortx8*>(&Vs[u][offF[kt][dt]]);
                    oacc[dt] = __builtin_amdgcn_mfma_f32_16x16x32_bf16(aP, bV, oacc[dt], 0, 0, 0);
                }
            }
        }
    }

#pragma unroll
    for (int r = 0; r < 4; ++r) {
        float t2 = lsum[r];
        t2 += __shfl_xor(t2, 1);
        t2 += __shfl_xor(t2, 2);
        t2 += __shfl_xor(t2, 4);
        t2 += __shfl_xor(t2, 8);
        lsum[r] = 1.0f / t2;
    }
#pragma unroll
    for (int dt = 0; dt < 4; ++dt)
#pragma unroll
        for (int r = 0; r < 4; ++r) {
            att[(size_t)(b * L_SEQ + q0 + wave * 16 + cq + r) * D_MODEL + h * D_K + dt * 16 + cn] =
                f2bf(oacc[dt][r] * lsum[r]);
        }
}

extern "C" void kernel_launch(void* const* d_in, const int* in_sizes, int n_in,
                              void* d_out, int out_size, void* d_ws, size_t ws_size,
                              hipStream_t stream) {
    const float* x     = (const float*)d_in[0];
    const int*   mask  = (const int*)d_in[1];
    const float* ln1_g = (const float*)d_in[2];
    const float* ln1_b = (const float*)d_in[3];
    const float* Wq    = (const float*)d_in[4];
    const float* bq    = (const float*)d_in[5];
    const float* Wk    = (const float*)d_in[6];
    const float* bk    = (const float*)d_in[7];
    const float* Wv    = (const float*)d_in[8];
    const float* bv    = (const float*)d_in[9];
    const float* Wo    = (const float*)d_in[10];
    const float* bo    = (const float*)d_in[11];
    const float* ln2_g = (const float*)d_in[12];
    const float* ln2_b = (const float*)d_in[13];
    const float* W1    = (const float*)d_in[14];
    const float* b1    = (const float*)d_in[15];
    const float* W2    = (const float*)d_in[16];
    const float* b2    = (const float*)d_in[17];
    float* out = (float*)d_out;

    float* ws = (float*)d_ws;
    const size_t SZ = (size_t)ROWS * D_MODEL;  // 4M elements; fp32 slot = 16 MB

    unsigned short* nx  = (unsigned short*)(ws + 0 * SZ);   // 0-8 MB: LN1/LN2 out bf16
    unsigned short* qb  = (unsigned short*)(ws + 1 * SZ);   // 16-24: Q bf16 (pre-scaled)
    unsigned short* kb  = qb + SZ;                          // 24-32: K bf16
    unsigned short* vtb = (unsigned short*)(ws + 2 * SZ);   // 32-40: V^T bf16
    unsigned short* attb = vtb + SZ;                        // 40-48: att bf16
    float* x1  = out;                                       // residual stream in d_out
    unsigned short* nx2 = nx;                               // slot0 reuse
    unsigned short* h = (unsigned short*)(ws + 2 * SZ);     // 32-64: FFN hidden bf16
    unsigned short* parts = (unsigned short*)(ws + 0 * SZ); // 0-16: FFN2 split-K partials

    unsigned short* WqkvT = (unsigned short*)(ws + 4 * SZ); // 64-70: concat [3072][1024]
    unsigned short* WqT = WqkvT;
    unsigned short* WkT = WqkvT + (size_t)D_MODEL * D_MODEL;
    unsigned short* WvT = WkT + (size_t)D_MODEL * D_MODEL;
    unsigned short* WoT = WvT + (size_t)D_MODEL * D_MODEL;  // 70-72
    unsigned short* W1T = (unsigned short*)(ws + 1 * SZ);   // 16-24 (qb/kb dead after attn)
    unsigned short* W2T = W1T + (size_t)D_MODEL * FFN_DIM;  // 24-32

    ln_kernel<<<ROWS, 256, 0, stream>>>(x, ln1_g, ln1_b, nx);

    transpose_cast4<<<dim3(32, 32, 4), 256, 0, stream>>>(Wq, Wk, Wv, Wo, WqT, WkT, WvT, WoT);

    mfma_gemm_qkv<<<dim3(3072 / 128, ROWS / 128), 256, 0, stream>>>(
        nx, WqkvT, bq, bk, bv, qb, kb, vtb);

    attn_mfma<<<dim3(L_SEQ / 128, N_HEAD, B_SZ), 512, 0, stream>>>(qb, kb, vtb, mask, attb);

    transpose_cast<<<dim3(FFN_DIM / 32, D_MODEL / 32), 256, 0, stream>>>(W1, W1T, D_MODEL, FFN_DIM);
    transpose_cast<<<dim3(D_MODEL / 32, FFN_DIM / 32), 256, 0, stream>>>(W2, W2T, FFN_DIM, D_MODEL);

    mfma_gemm<0, 1, 0><<<dim3(D_MODEL / 128, ROWS / 128), 256, 0, stream>>>(
        attb, WoT, bo, x, x1, ROWS, D_MODEL, D_MODEL);

    ln_kernel<<<ROWS, 256, 0, stream>>>(x1, ln2_g, ln2_b, nx2);

    mfma_gemm<1, 0, 1><<<dim3(FFN_DIM / 128, ROWS / 128), 256, 0, stream>>>(
        nx2, W1T, b1, nullptr, h, ROWS, FFN_DIM, D_MODEL);

    mfma_gemm_splitk<<<dim3(D_MODEL / 128, ROWS / 128, 2), 256, 0, stream>>>(
        h, W2T, parts, ROWS, D_MODEL, FFN_DIM / 2);
    combine_kernel<<<(ROWS * D_MODEL) / 1024, 256, 0, stream>>>(
        parts, parts + SZ, b2, x1, out);
}

// Round 9
// 366.336 us; speedup vs baseline: 1.1684x; 1.0065x over previous
//
#include <hip/hip_runtime.h>
#include <hip/hip_bf16.h>

#define D_MODEL 1024
#define N_HEAD  16
#define D_K     64
#define FFN_DIM 4096
#define B_SZ    2
#define L_SEQ   2048
#define ROWS    (B_SZ * L_SEQ)   // 4096
#define PST     68               // Ps/Qs LDS row stride (shorts): proven 0-conflict (R9/R10)

typedef float  floatx4 __attribute__((ext_vector_type(4)));
typedef short  shortx8 __attribute__((ext_vector_type(8)));

__device__ __forceinline__ unsigned short f2bf(float f) {
    unsigned int u = __float_as_uint(f);
    unsigned int rounding = 0x7fffu + ((u >> 16) & 1u);
    return (unsigned short)((u + rounding) >> 16);
}
__device__ __forceinline__ float bf2f(unsigned short u) {
    return __uint_as_float(((unsigned int)u) << 16);
}

// async global->LDS 16B copy; LDS dest is wave-uniform base + lane*16
__device__ __forceinline__ void glds16(const unsigned short* g, unsigned short* l) {
    __builtin_amdgcn_global_load_lds(
        (const __attribute__((address_space(1))) unsigned int*)g,
        (__attribute__((address_space(3))) unsigned int*)l, 16, 0, 0);
}

// ---- T1: XCD-chunked blockIdx remap (R6, verified: attn FETCH 69.7->12.4 MB).
// Linear wg id round-robins the 8 XCDs (id%8 = XCD). Decode groups of 8 col-tiles x
// consecutive row-tiles so blocks sharing A-strips/B-panels co-reside per-XCD L2.
// Bijective when nwg%8==0 and gx%8==0 (all our grids).
__device__ __forceinline__ void xcd_remap_gemm(int& bx, int& by, int& bz) {
    const int gx = gridDim.x, gy = gridDim.y, gz = gridDim.z;
    const int o = blockIdx.x + gx * (blockIdx.y + gy * blockIdx.z);
    const int nwg = gx * gy * gz;
    const int t = (o & 7) * (nwg >> 3) + (o >> 3);
    const int zsz = gx * gy;
    bz = t / zsz;
    const int w = t - bz * zsz;
    const int grp = w / (8 * gy);
    const int in  = w - grp * (8 * gy);
    by = in >> 3;
    bx = grp * 8 + (in & 7);
}

// ---------- LayerNorm: one block per row of 1024, fp32 in -> bf16 out ----------
__global__ __launch_bounds__(256) void ln_kernel(const float* __restrict__ x,
                                                 const float* __restrict__ g,
                                                 const float* __restrict__ b,
                                                 unsigned short* __restrict__ out) {
    const int row = blockIdx.x;
    const int tid = threadIdx.x;
    const float* xr = x + (size_t)row * D_MODEL;
    float4 xv = *reinterpret_cast<const float4*>(&xr[tid * 4]);
    float v[4] = {xv.x, xv.y, xv.z, xv.w};
    float s = v[0] + v[1] + v[2] + v[3];
    float ss = v[0] * v[0] + v[1] * v[1] + v[2] * v[2] + v[3] * v[3];
    __shared__ float r1[256], r2[256];
    r1[tid] = s; r2[tid] = ss;
    __syncthreads();
    for (int off = 128; off > 0; off >>= 1) {
        if (tid < off) { r1[tid] += r1[tid + off]; r2[tid] += r2[tid + off]; }
        __syncthreads();
    }
    const float mean = r1[0] * (1.0f / D_MODEL);
    const float var  = r2[0] * (1.0f / D_MODEL) - mean * mean;
    const float inv  = rsqrtf(var + 1e-5f);
    unsigned short* orow = out + (size_t)row * D_MODEL;
    ushort4 o;
    o.x = f2bf((v[0] - mean) * inv * g[tid * 4 + 0] + b[tid * 4 + 0]);
    o.y = f2bf((v[1] - mean) * inv * g[tid * 4 + 1] + b[tid * 4 + 1]);
    o.z = f2bf((v[2] - mean) * inv * g[tid * 4 + 2] + b[tid * 4 + 2]);
    o.w = f2bf((v[3] - mean) * inv * g[tid * 4 + 3] + b[tid * 4 + 3]);
    *reinterpret_cast<ushort4*>(&orow[tid * 4]) = o;
}

// ---------- Transpose+cast: W fp32 [K][N] -> Wt bf16 [N][K] ----------
__global__ __launch_bounds__(256) void transpose_cast(const float* __restrict__ W,
                                                      unsigned short* __restrict__ Wt,
                                                      int K, int N) {
    __shared__ unsigned short T[32][33];
    const int t = threadIdx.x;
    const int k0 = blockIdx.y * 32, n0 = blockIdx.x * 32;
    const int kr = t >> 3, nc = (t & 7) * 4;
    float4 w = *reinterpret_cast<const float4*>(&W[(size_t)(k0 + kr) * N + n0 + nc]);
    T[kr][nc + 0] = f2bf(w.x); T[kr][nc + 1] = f2bf(w.y);
    T[kr][nc + 2] = f2bf(w.z); T[kr][nc + 3] = f2bf(w.w);
    __syncthreads();
    const int nr = t >> 3, kc = (t & 7) * 4;
    ushort4 o;
    o.x = T[kc + 0][nr]; o.y = T[kc + 1][nr];
    o.z = T[kc + 2][nr]; o.w = T[kc + 3][nr];
    *reinterpret_cast<ushort4*>(&Wt[(size_t)(n0 + nr) * K + k0 + kc]) = o;
}

// ---------- 4x square (1024x1024) transpose in one dispatch, z selects matrix ----------
__global__ __launch_bounds__(256) void transpose_cast4(const float* s0, const float* s1,
                                                       const float* s2, const float* s3,
                                                       unsigned short* d0, unsigned short* d1,
                                                       unsigned short* d2, unsigned short* d3) {
    const int z = blockIdx.z;
    const float* W = (z == 0) ? s0 : (z == 1) ? s1 : (z == 2) ? s2 : s3;
    unsigned short* Wt = (z == 0) ? d0 : (z == 1) ? d1 : (z == 2) ? d2 : d3;
    __shared__ unsigned short T[32][33];
    const int t = threadIdx.x;
    const int k0 = blockIdx.y * 32, n0 = blockIdx.x * 32;
    const int kr = t >> 3, nc = (t & 7) * 4;
    float4 w = *reinterpret_cast<const float4*>(&W[(size_t)(k0 + kr) * D_MODEL + n0 + nc]);
    T[kr][nc + 0] = f2bf(w.x); T[kr][nc + 1] = f2bf(w.y);
    T[kr][nc + 2] = f2bf(w.z); T[kr][nc + 3] = f2bf(w.w);
    __syncthreads();
    const int nr = t >> 3, kc = (t & 7) * 4;
    ushort4 o;
    o.x = T[kc + 0][nr]; o.y = T[kc + 1][nr];
    o.z = T[kc + 2][nr]; o.w = T[kc + 3][nr];
    *reinterpret_cast<ushort4*>(&Wt[(size_t)(n0 + nr) * D_MODEL + k0 + kc]) = o;
}

// ===== R9 GEMM: BK=32, T3 minimum-2-phase double-buffer with STATIC buffer names
// (As0/As1/Bs0/Bs1 -> compiler can disambiguate glds16-writes vs other-buffer ds_reads).
// stage(next) issued BEFORE compute(cur); ONE barrier per 32-K tile -> the compiler's
// mandatory vmcnt(0) drain lands AFTER compute, hiding glds16 latency under 16 MFMAs.
// LDS total 32 KB (4 x 8 KB) = same as R7 -> occupancy unchanged (the R1 trap avoided).
// Swizzle: tile 128x32 shorts; LDS pos p holds (row=p>>2, kc=((p&3)-(row>>1))&3);
// read (R,kc) at R*32+((kc+(R>>1))&3)*8 -> 2-way max (free). Proven R0-R6.

#define GEMM_STAGE(AS, BS, KT)                                            \
    do {                                                                  \
        glds16(A  + sA0 + (KT), &AS[p0 * 8]);                             \
        glds16(A  + sA1 + (KT), &AS[p1 * 8]);                             \
        glds16(Wt + sB0 + (KT), &BS[p0 * 8]);                             \
        glds16(Wt + sB1 + (KT), &BS[p1 * 8]);                             \
    } while (0)

#define GEMM_COMPUTE(AS, BS)                                              \
    do {                                                                  \
        shortx8 af[4], bf[4];                                             \
        _Pragma("unroll")                                                 \
        for (int i = 0; i < 4; ++i)                                       \
            af[i] = *reinterpret_cast<const shortx8*>(&AS[offA[i]]);      \
        _Pragma("unroll")                                                 \
        for (int j = 0; j < 4; ++j)                                       \
            bf[j] = *reinterpret_cast<const shortx8*>(&BS[offB[j]]);      \
        _Pragma("unroll")                                                 \
        for (int i = 0; i < 4; ++i)                                       \
            _Pragma("unroll")                                             \
            for (int j = 0; j < 4; ++j)                                   \
                acc[i][j] = __builtin_amdgcn_mfma_f32_16x16x32_bf16(af[i], bf[j], acc[i][j], 0, 0, 0); \
    } while (0)

#define GEMM_PREAMBLE                                                     \
    const int tid  = threadIdx.x;                                         \
    const int lane = tid & 63;                                            \
    const int wave = tid >> 6;                                            \
    int bx, by, bz;                                                       \
    xcd_remap_gemm(bx, by, bz);                                           \
    const int row0 = by * 128, col0 = bx * 128;                           \
    const int wr = (wave >> 1) * 64, wc = (wave & 1) * 64;                \
    floatx4 acc[4][4] = {};                                               \
    const int p0 = tid,       r0s = p0 >> 2, k0s = (((p0 & 3) - (r0s >> 1)) & 3) * 8; \
    const int p1 = tid + 256, r1s = p1 >> 2, k1s = (((p1 & 3) - (r1s >> 1)) & 3) * 8; \
    const int am = (lane & 15);                                           \
    const size_t sA0 = (size_t)(row0 + r0s) * K + k0s;                    \
    const size_t sA1 = (size_t)(row0 + r1s) * K + k1s;                    \
    const size_t sB0 = (size_t)(col0 + r0s) * K + k0s;                    \
    const size_t sB1 = (size_t)(col0 + r1s) * K + k1s;                    \
    int offA[4], offB[4];                                                 \
    _Pragma("unroll")                                                     \
    for (int i = 0; i < 4; ++i) {                                         \
        const int Ra = wr + i * 16 + am;                                  \
        offA[i] = Ra * 32 + (((lane >> 4) + (Ra >> 1)) & 3) * 8;          \
        const int Rb = wc + i * 16 + am;                                  \
        offB[i] = Rb * 32 + (((lane >> 4) + (Rb >> 1)) & 3) * 8;          \
    }

// ---------- MFMA bf16 GEMM (2-phase dbuf). A [M][K]; Wt [N][K]. 128x128. ----------
template <int SILU, int HAS_RES, int OUT_BF16>
__global__ __launch_bounds__(256) void mfma_gemm(const unsigned short* __restrict__ A,
                                                 const unsigned short* __restrict__ Wt,
                                                 const float* __restrict__ bias,
                                                 const float* __restrict__ res,
                                                 void* __restrict__ outP,
                                                 int M, int N, int K) {
    __shared__ unsigned short As0[128 * 32], As1[128 * 32];
    __shared__ unsigned short Bs0[128 * 32], Bs1[128 * 32];
    GEMM_PREAMBLE

    GEMM_STAGE(As0, Bs0, 0);
    __syncthreads();
    for (int kt = 0; kt < K; kt += 64) {
        GEMM_STAGE(As1, Bs1, kt + 32);
        GEMM_COMPUTE(As0, Bs0);
        __syncthreads();
        if (kt + 64 < K) GEMM_STAGE(As0, Bs0, kt + 64);
        GEMM_COMPUTE(As1, Bs1);
        __syncthreads();
    }

    const int cq = (lane >> 4) * 4;
    const int cn = lane & 15;
#pragma unroll
    for (int i = 0; i < 4; ++i) {
#pragma unroll
        for (int j = 0; j < 4; ++j) {
            const int n = col0 + wc + j * 16 + cn;
            const float bb = bias[n];
#pragma unroll
            for (int r = 0; r < 4; ++r) {
                const int m = row0 + wr + i * 16 + cq + r;
                float v = acc[i][j][r] + bb;
                if (SILU) v = v / (1.0f + __expf(-v));
                if (HAS_RES) v += res[(size_t)m * N + n];
                if (OUT_BF16) ((unsigned short*)outP)[(size_t)m * N + n] = f2bf(v);
                else          ((float*)outP)[(size_t)m * N + n] = v;
            }
        }
    }
}

// ---------- Fused QKV GEMM: N=3072 over concatenated [3072][1024] weights ----------
__global__ __launch_bounds__(256) void mfma_gemm_qkv(const unsigned short* __restrict__ A,
                                                     const unsigned short* __restrict__ Wt,
                                                     const float* __restrict__ bq,
                                                     const float* __restrict__ bk,
                                                     const float* __restrict__ bv,
                                                     unsigned short* __restrict__ qb,
                                                     unsigned short* __restrict__ kb,
                                                     unsigned short* __restrict__ vtb) {
    const int K = D_MODEL, M = ROWS;
    __shared__ unsigned short As0[128 * 32], As1[128 * 32];
    __shared__ unsigned short Bs0[128 * 32], Bs1[128 * 32];
    GEMM_PREAMBLE

    GEMM_STAGE(As0, Bs0, 0);
    __syncthreads();
    for (int kt = 0; kt < K; kt += 64) {
        GEMM_STAGE(As1, Bs1, kt + 32);
        GEMM_COMPUTE(As0, Bs0);
        __syncthreads();
        if (kt + 64 < K) GEMM_STAGE(As0, Bs0, kt + 64);
        GEMM_COMPUTE(As1, Bs1);
        __syncthreads();
    }

    const int cq = (lane >> 4) * 4;
    const int cn = lane & 15;
    const int sel = col0 >> 10;                 // 0=Q 1=K 2=V (block-uniform)
    const int nbase = col0 & 1023;
    const float* bias = (sel == 0) ? bq : (sel == 1) ? bk : bv;
    // fold 1/sqrt(Dk) AND log2(e) into Q so attention uses a single v_exp_f32
    // (exact: softmax(S) == softmax-base-2(S*log2e)); 0.125 * 1.4426950408889634
    const float scl = (sel == 0) ? 0.18033688511157292f : 1.0f;
#pragma unroll
    for (int i = 0; i < 4; ++i) {
#pragma unroll
        for (int j = 0; j < 4; ++j) {
            const int n = nbase + wc + j * 16 + cn;
            const float bb = bias[n];
            if (sel == 2) {
                const int m0 = row0 + wr + i * 16 + cq;
                ushort4 o;
                o.x = f2bf(acc[i][j][0] + bb);
                o.y = f2bf(acc[i][j][1] + bb);
                o.z = f2bf(acc[i][j][2] + bb);
                o.w = f2bf(acc[i][j][3] + bb);
                *reinterpret_cast<ushort4*>(&vtb[(size_t)n * M + m0]) = o;
            } else {
                unsigned short* dst = (sel == 0) ? qb : kb;
#pragma unroll
                for (int r = 0; r < 4; ++r) {
                    const int m = row0 + wr + i * 16 + cq + r;
                    dst[(size_t)m * D_MODEL + n] = f2bf((acc[i][j][r] + bb) * scl);
                }
            }
        }
    }
}

// ---------- Split-K GEMM: z = K-slice; raw bf16 partials ----------
__global__ __launch_bounds__(256) void mfma_gemm_splitk(const unsigned short* __restrict__ A,
                                                        const unsigned short* __restrict__ Wt,
                                                        unsigned short* __restrict__ parts,
                                                        int M, int N, int KS) {
    __shared__ unsigned short As0[128 * 32], As1[128 * 32];
    __shared__ unsigned short Bs0[128 * 32], Bs1[128 * 32];
    const int K = KS * gridDim.z;
    GEMM_PREAMBLE
    const int kbeg = bz * KS;
    unsigned short* outp = parts + (size_t)bz * M * N;

    GEMM_STAGE(As0, Bs0, kbeg);
    __syncthreads();
    for (int kt = kbeg; kt < kbeg + KS; kt += 64) {
        GEMM_STAGE(As1, Bs1, kt + 32);
        GEMM_COMPUTE(As0, Bs0);
        __syncthreads();
        if (kt + 64 < kbeg + KS) GEMM_STAGE(As0, Bs0, kt + 64);
        GEMM_COMPUTE(As1, Bs1);
        __syncthreads();
    }

    const int cq = (lane >> 4) * 4;
    const int cn = lane & 15;
#pragma unroll
    for (int i = 0; i < 4; ++i)
#pragma unroll
        for (int j = 0; j < 4; ++j) {
            const int n = col0 + wc + j * 16 + cn;
#pragma unroll
            for (int r = 0; r < 4; ++r) {
                const int m = row0 + wr + i * 16 + cq + r;
                outp[(size_t)m * N + n] = f2bf(acc[i][j][r]);
            }
        }
}

// ---------- combine: out = p0 + p1 + bias + res ----------
__global__ __launch_bounds__(256) void combine_kernel(const unsigned short* __restrict__ p0,
                                                      const unsigned short* __restrict__ p1,
                                                      const float* __restrict__ bias,
                                                      const float* __restrict__ res,
                                                      float* __restrict__ out) {
    const size_t e0 = ((size_t)blockIdx.x * 256 + threadIdx.x) * 4;
    const int col = (int)(e0 & 1023);
    ushort4 a = *reinterpret_cast<const ushort4*>(&p0[e0]);
    ushort4 b = *reinterpret_cast<const ushort4*>(&p1[e0]);
    float4 r = *reinterpret_cast<const float4*>(&res[e0]);
    float4 o;
    o.x = bf2f(a.x) + bf2f(b.x) + bias[col + 0] + r.x;
    o.y = bf2f(a.y) + bf2f(b.y) + bias[col + 1] + r.y;
    o.z = bf2f(a.z) + bf2f(b.z) + bias[col + 2] + r.z;
    o.w = bf2f(a.w) + bf2f(b.w) + bias[col + 3] + r.w;
    *reinterpret_cast<float4*>(&out[e0]) = o;
}

// ---------- MFMA attention: R8 structure unchanged (CONTROL this round).
// Two 64-row K/V sub-tiles per barrier pair; Ps wave-private reuse; XCD remap;
// single-v_exp_f32 path. 68 KB LDS, 2 blocks/CU (grid-limited).
__global__ __launch_bounds__(512) void attn_mfma(const unsigned short* __restrict__ Q,
                                                 const unsigned short* __restrict__ K,
                                                 const unsigned short* __restrict__ Vt,
                                                 const int* __restrict__ mask,
                                                 unsigned short* __restrict__ att) {
    const int tid  = threadIdx.x;
    const int lane = tid & 63;
    const int wave = tid >> 6;          // 0..7
    // plain chunked XCD remap (row-major decode: q-tile fastest -> chunk shares K/V)
    const int o = blockIdx.x + gridDim.x * (blockIdx.y + gridDim.y * blockIdx.z);
    const int nwg = gridDim.x * gridDim.y * gridDim.z;
    const int t = (o & 7) * (nwg >> 3) + (o >> 3);
    const int qx = t % gridDim.x;
    const int h  = (t / gridDim.x) % gridDim.y;
    const int b  = t / (gridDim.x * gridDim.y);
    const int q0 = qx * 128;

    __shared__ unsigned short Qs[128 * PST];
    __shared__ unsigned short Ks[2][64 * 64];
    __shared__ unsigned short Vs[2][64 * 64];
    __shared__ unsigned short Ps[128 * PST];
    __shared__ int mk[128];

    const int am = lane & 15;
    const int aq = (lane >> 4) * 8;
    const int cq = (lane >> 4) * 4;
    const int cn = lane & 15;

    // stage Q tile (once, via VGPR; padded layout): 128 rows x 8 chunks = 1024 chunks
    for (int c = tid; c < 1024; c += 512) {
        const int r = c >> 3, off = (c & 7) * 8;
        *reinterpret_cast<uint4*>(&Qs[r * PST + off]) =
            *reinterpret_cast<const uint4*>(&Q[(size_t)(b * L_SEQ + q0 + r) * D_MODEL + h * D_K + off]);
    }

    // swizzled staging: LDS chunk p holds (row=p>>3, c8=((p&7)-row)&7); 512 chunks
    // per sub-tile, one per thread per sub-tile for each of Ks and Vs.
    const int p0 = tid, sr0 = p0 >> 3, sc0 = (((p0 & 7) - sr0) & 7) * 8;
    const unsigned short* K0 = K + (size_t)(b * L_SEQ + sr0) * D_MODEL + h * D_K + sc0;
    const unsigned short* V0 = Vt + (size_t)(h * D_K + sr0) * ROWS + b * L_SEQ + sc0;

    // fragment read offsets (loop-invariant): row R = t*16+am, chunk c8 = kt*4 + (lane>>4)
    int offF[2][4];
#pragma unroll
    for (int kt = 0; kt < 2; ++kt)
#pragma unroll
        for (int tt = 0; tt < 4; ++tt) {
            const int R = tt * 16 + am;
            offF[kt][tt] = R * 64 + (((kt * 4 + (lane >> 4)) + R) & 7) * 8;
        }

    __syncthreads();

    shortx8 aQ[2];
    aQ[0] = *reinterpret_cast<const shortx8*>(&Qs[(wave * 16 + am) * PST + aq]);
    aQ[1] = *reinterpret_cast<const shortx8*>(&Qs[(wave * 16 + am) * PST + 32 + aq]);

    floatx4 oacc[4] = {};
    float lsum[4] = {0.0f, 0.0f, 0.0f, 0.0f};

    for (int j0 = 0; j0 < L_SEQ; j0 += 128) {
        __syncthreads();
        glds16(K0 + (size_t)j0 * D_MODEL,        &Ks[0][p0 * 8]);
        glds16(K0 + (size_t)(j0 + 64) * D_MODEL, &Ks[1][p0 * 8]);
        glds16(V0 + j0,      &Vs[0][p0 * 8]);
        glds16(V0 + j0 + 64, &Vs[1][p0 * 8]);
        if (tid < 128) mk[tid] = mask[b * L_SEQ + j0 + tid];
        __syncthreads();

#pragma unroll
        for (int u = 0; u < 2; ++u) {
            floatx4 sacc[4] = {};
#pragma unroll
            for (int kt = 0; kt < 2; ++kt)
#pragma unroll
                for (int jt = 0; jt < 4; ++jt) {
                    shortx8 bK = *reinterpret_cast<const shortx8*>(&Ks[u][offF[kt][jt]]);
                    sacc[jt] = __builtin_amdgcn_mfma_f32_16x16x32_bf16(aQ[kt], bK, sacc[jt], 0, 0, 0);
                }
            // P = exp2(S) masked (Q pre-scaled by log2e/8 -> single v_exp_f32);
            // truncate-cast to bf16
#pragma unroll
            for (int jt = 0; jt < 4; ++jt) {
                const int mv = mk[u * 64 + jt * 16 + cn];
#pragma unroll
                for (int r = 0; r < 4; ++r) {
                    float p = mv ? __builtin_amdgcn_exp2f(sacc[jt][r]) : 0.0f;
                    lsum[r] += p;
                    Ps[(wave * 16 + cq + r) * PST + jt * 16 + cn] =
                        (unsigned short)(__float_as_uint(p) >> 16);
                }
            }
            // O += P x V (wave-private Ps rows; DS in-order within wave -> safe reuse)
#pragma unroll
            for (int kt = 0; kt < 2; ++kt) {
                shortx8 aP = *reinterpret_cast<const shortx8*>(&Ps[(wave * 16 + am) * PST + kt * 32 + aq]);
#pragma unroll
                for (int dt = 0; dt < 4; ++dt) {
                    shortx8 bV = *reinterpret_cast<const shortx8*>(&Vs[u][offF[kt][dt]]);
                    oacc[dt] = __builtin_amdgcn_mfma_f32_16x16x32_bf16(aP, bV, oacc[dt], 0, 0, 0);
                }
            }
        }
    }

#pragma unroll
    for (int r = 0; r < 4; ++r) {
        float t2 = lsum[r];
        t2 += __shfl_xor(t2, 1);
        t2 += __shfl_xor(t2, 2);
        t2 += __shfl_xor(t2, 4);
        t2 += __shfl_xor(t2, 8);
        lsum[r] = 1.0f / t2;
    }
#pragma unroll
    for (int dt = 0; dt < 4; ++dt)
#pragma unroll
        for (int r = 0; r < 4; ++r) {
            att[(size_t)(b * L_SEQ + q0 + wave * 16 + cq + r) * D_MODEL + h * D_K + dt * 16 + cn] =
                f2bf(oacc[dt][r] * lsum[r]);
        }
}

extern "C" void kernel_launch(void* const* d_in, const int* in_sizes, int n_in,
                              void* d_out, int out_size, void* d_ws, size_t ws_size,
                              hipStream_t stream) {
    const float* x     = (const float*)d_in[0];
    const int*   mask  = (const int*)d_in[1];
    const float* ln1_g = (const float*)d_in[2];
    const float* ln1_b = (const float*)d_in[3];
    const float* Wq    = (const float*)d_in[4];
    const float* bq    = (const float*)d_in[5];
    const float* Wk    = (const float*)d_in[6];
    const float* bk    = (const float*)d_in[7];
    const float* Wv    = (const float*)d_in[8];
    const float* bv    = (const float*)d_in[9];
    const float* Wo    = (const float*)d_in[10];
    const float* bo    = (const float*)d_in[11];
    const float* ln2_g = (const float*)d_in[12];
    const float* ln2_b = (const float*)d_in[13];
    const float* W1    = (const float*)d_in[14];
    const float* b1    = (const float*)d_in[15];
    const float* W2    = (const float*)d_in[16];
    const float* b2    = (const float*)d_in[17];
    float* out = (float*)d_out;

    float* ws = (float*)d_ws;
    const size_t SZ = (size_t)ROWS * D_MODEL;  // 4M elements; fp32 slot = 16 MB

    unsigned short* nx  = (unsigned short*)(ws + 0 * SZ);   // 0-8 MB: LN1/LN2 out bf16
    unsigned short* qb  = (unsigned short*)(ws + 1 * SZ);   // 16-24: Q bf16 (pre-scaled)
    unsigned short* kb  = qb + SZ;                          // 24-32: K bf16
    unsigned short* vtb = (unsigned short*)(ws + 2 * SZ);   // 32-40: V^T bf16
    unsigned short* attb = vtb + SZ;                        // 40-48: att bf16
    float* x1  = out;                                       // residual stream in d_out
    unsigned short* nx2 = nx;                               // slot0 reuse
    unsigned short* h = (unsigned short*)(ws + 2 * SZ);     // 32-64: FFN hidden bf16
    unsigned short* parts = (unsigned short*)(ws + 0 * SZ); // 0-16: FFN2 split-K partials

    unsigned short* WqkvT = (unsigned short*)(ws + 4 * SZ); // 64-70: concat [3072][1024]
    unsigned short* WqT = WqkvT;
    unsigned short* WkT = WqkvT + (size_t)D_MODEL * D_MODEL;
    unsigned short* WvT = WkT + (size_t)D_MODEL * D_MODEL;
    unsigned short* WoT = WvT + (size_t)D_MODEL * D_MODEL;  // 70-72
    unsigned short* W1T = (unsigned short*)(ws + 1 * SZ);   // 16-24 (qb/kb dead after attn)
    unsigned short* W2T = W1T + (size_t)D_MODEL * FFN_DIM;  // 24-32

    ln_kernel<<<ROWS, 256, 0, stream>>>(x, ln1_g, ln1_b, nx);

    transpose_cast4<<<dim3(32, 32, 4), 256, 0, stream>>>(Wq, Wk, Wv, Wo, WqT, WkT, WvT, WoT);

    mfma_gemm_qkv<<<dim3(3072 / 128, ROWS / 128), 256, 0, stream>>>(
        nx, WqkvT, bq, bk, bv, qb, kb, vtb);

    attn_mfma<<<dim3(L_SEQ / 128, N_HEAD, B_SZ), 512, 0, stream>>>(qb, kb, vtb, mask, attb);

    transpose_cast<<<dim3(FFN_DIM / 32, D_MODEL / 32), 256, 0, stream>>>(W1, W1T, D_MODEL, FFN_DIM);
    transpose_cast<<<dim3(D_MODEL / 32, FFN_DIM / 32), 256, 0, stream>>>(W2, W2T, FFN_DIM, D_MODEL);

    mfma_gemm<0, 1, 0><<<dim3(D_MODEL / 128, ROWS / 128), 256, 0, stream>>>(
        attb, WoT, bo, x, x1, ROWS, D_MODEL, D_MODEL);

    ln_kernel<<<ROWS, 256, 0, stream>>>(x1, ln2_g, ln2_b, nx2);

    mfma_gemm<1, 0, 1><<<dim3(FFN_DIM / 128, ROWS / 128), 256, 0, stream>>>(
        nx2, W1T, b1, nullptr, h, ROWS, FFN_DIM, D_MODEL);

    mfma_gemm_splitk<<<dim3(D_MODEL / 128, ROWS / 128, 2), 256, 0, stream>>>(
        h, W2T, parts, ROWS, D_MODEL, FFN_DIM / 2);
    combine_kernel<<<(ROWS * D_MODEL) / 1024, 256, 0, stream>>>(
        parts, parts + SZ, b2, x1, out);
}

// Round 10
// 364.194 us; speedup vs baseline: 1.1753x; 1.0059x over previous
//
#include <hip/hip_runtime.h>
#include <hip/hip_bf16.h>

#define D_MODEL 1024
#define N_HEAD  16
#define D_K     64
#define FFN_DIM 4096
#define B_SZ    2
#define L_SEQ   2048
#define ROWS    (B_SZ * L_SEQ)   // 4096
#define PST     68               // Ps/Qs LDS row stride (shorts): proven 0-conflict (R9/R10)

typedef float  floatx4 __attribute__((ext_vector_type(4)));
typedef short  shortx8 __attribute__((ext_vector_type(8)));

__device__ __forceinline__ unsigned short f2bf(float f) {
    unsigned int u = __float_as_uint(f);
    unsigned int rounding = 0x7fffu + ((u >> 16) & 1u);
    return (unsigned short)((u + rounding) >> 16);
}
__device__ __forceinline__ float bf2f(unsigned short u) {
    return __uint_as_float(((unsigned int)u) << 16);
}

// async global->LDS 16B copy; LDS dest is wave-uniform base + lane*16
__device__ __forceinline__ void glds16(const unsigned short* g, unsigned short* l) {
    __builtin_amdgcn_global_load_lds(
        (const __attribute__((address_space(1))) unsigned int*)g,
        (__attribute__((address_space(3))) unsigned int*)l, 16, 0, 0);
}

// ---- T1: XCD-chunked blockIdx remap (R6, verified: attn FETCH 69.7->12.4 MB).
// Linear wg id round-robins the 8 XCDs (id%8 = XCD). Decode groups of 8 col-tiles x
// consecutive row-tiles so blocks sharing A-strips/B-panels co-reside per-XCD L2.
// Bijective when nwg%8==0 and gx%8==0 (all our grids).
__device__ __forceinline__ void xcd_remap_gemm(int& bx, int& by, int& bz) {
    const int gx = gridDim.x, gy = gridDim.y, gz = gridDim.z;
    const int o = blockIdx.x + gx * (blockIdx.y + gy * blockIdx.z);
    const int nwg = gx * gy * gz;
    const int t = (o & 7) * (nwg >> 3) + (o >> 3);
    const int zsz = gx * gy;
    bz = t / zsz;
    const int w = t - bz * zsz;
    const int grp = w / (8 * gy);
    const int in  = w - grp * (8 * gy);
    by = in >> 3;
    bx = grp * 8 + (in & 7);
}

// ---------- LayerNorm: one block per row of 1024, fp32 in -> bf16 out ----------
__global__ __launch_bounds__(256) void ln_kernel(const float* __restrict__ x,
                                                 const float* __restrict__ g,
                                                 const float* __restrict__ b,
                                                 unsigned short* __restrict__ out) {
    const int row = blockIdx.x;
    const int tid = threadIdx.x;
    const float* xr = x + (size_t)row * D_MODEL;
    float4 xv = *reinterpret_cast<const float4*>(&xr[tid * 4]);
    float v[4] = {xv.x, xv.y, xv.z, xv.w};
    float s = v[0] + v[1] + v[2] + v[3];
    float ss = v[0] * v[0] + v[1] * v[1] + v[2] * v[2] + v[3] * v[3];
    __shared__ float r1[256], r2[256];
    r1[tid] = s; r2[tid] = ss;
    __syncthreads();
    for (int off = 128; off > 0; off >>= 1) {
        if (tid < off) { r1[tid] += r1[tid + off]; r2[tid] += r2[tid + off]; }
        __syncthreads();
    }
    const float mean = r1[0] * (1.0f / D_MODEL);
    const float var  = r2[0] * (1.0f / D_MODEL) - mean * mean;
    const float inv  = rsqrtf(var + 1e-5f);
    unsigned short* orow = out + (size_t)row * D_MODEL;
    ushort4 o;
    o.x = f2bf((v[0] - mean) * inv * g[tid * 4 + 0] + b[tid * 4 + 0]);
    o.y = f2bf((v[1] - mean) * inv * g[tid * 4 + 1] + b[tid * 4 + 1]);
    o.z = f2bf((v[2] - mean) * inv * g[tid * 4 + 2] + b[tid * 4 + 2]);
    o.w = f2bf((v[3] - mean) * inv * g[tid * 4 + 3] + b[tid * 4 + 3]);
    *reinterpret_cast<ushort4*>(&orow[tid * 4]) = o;
}

// ---------- Transpose+cast: W fp32 [K][N] -> Wt bf16 [N][K] ----------
__global__ __launch_bounds__(256) void transpose_cast(const float* __restrict__ W,
                                                      unsigned short* __restrict__ Wt,
                                                      int K, int N) {
    __shared__ unsigned short T[32][33];
    const int t = threadIdx.x;
    const int k0 = blockIdx.y * 32, n0 = blockIdx.x * 32;
    const int kr = t >> 3, nc = (t & 7) * 4;
    float4 w = *reinterpret_cast<const float4*>(&W[(size_t)(k0 + kr) * N + n0 + nc]);
    T[kr][nc + 0] = f2bf(w.x); T[kr][nc + 1] = f2bf(w.y);
    T[kr][nc + 2] = f2bf(w.z); T[kr][nc + 3] = f2bf(w.w);
    __syncthreads();
    const int nr = t >> 3, kc = (t & 7) * 4;
    ushort4 o;
    o.x = T[kc + 0][nr]; o.y = T[kc + 1][nr];
    o.z = T[kc + 2][nr]; o.w = T[kc + 3][nr];
    *reinterpret_cast<ushort4*>(&Wt[(size_t)(n0 + nr) * K + k0 + kc]) = o;
}

// ---------- 4x square (1024x1024) transpose in one dispatch, z selects matrix ----------
__global__ __launch_bounds__(256) void transpose_cast4(const float* s0, const float* s1,
                                                       const float* s2, const float* s3,
                                                       unsigned short* d0, unsigned short* d1,
                                                       unsigned short* d2, unsigned short* d3) {
    const int z = blockIdx.z;
    const float* W = (z == 0) ? s0 : (z == 1) ? s1 : (z == 2) ? s2 : s3;
    unsigned short* Wt = (z == 0) ? d0 : (z == 1) ? d1 : (z == 2) ? d2 : d3;
    __shared__ unsigned short T[32][33];
    const int t = threadIdx.x;
    const int k0 = blockIdx.y * 32, n0 = blockIdx.x * 32;
    const int kr = t >> 3, nc = (t & 7) * 4;
    float4 w = *reinterpret_cast<const float4*>(&W[(size_t)(k0 + kr) * D_MODEL + n0 + nc]);
    T[kr][nc + 0] = f2bf(w.x); T[kr][nc + 1] = f2bf(w.y);
    T[kr][nc + 2] = f2bf(w.z); T[kr][nc + 3] = f2bf(w.w);
    __syncthreads();
    const int nr = t >> 3, kc = (t & 7) * 4;
    ushort4 o;
    o.x = T[kc + 0][nr]; o.y = T[kc + 1][nr];
    o.z = T[kc + 2][nr]; o.w = T[kc + 3][nr];
    *reinterpret_cast<ushort4*>(&Wt[(size_t)(n0 + nr) * D_MODEL + k0 + kc]) = o;
}

// ===== R9 GEMM: BK=32, 2-phase dbuf (kept: marginal win, no risk). Swizzle proven R0-R6.

#define GEMM_STAGE(AS, BS, KT)                                            \
    do {                                                                  \
        glds16(A  + sA0 + (KT), &AS[p0 * 8]);                             \
        glds16(A  + sA1 + (KT), &AS[p1 * 8]);                             \
        glds16(Wt + sB0 + (KT), &BS[p0 * 8]);                             \
        glds16(Wt + sB1 + (KT), &BS[p1 * 8]);                             \
    } while (0)

#define GEMM_COMPUTE(AS, BS)                                              \
    do {                                                                  \
        shortx8 af[4], bf[4];                                             \
        _Pragma("unroll")                                                 \
        for (int i = 0; i < 4; ++i)                                       \
            af[i] = *reinterpret_cast<const shortx8*>(&AS[offA[i]]);      \
        _Pragma("unroll")                                                 \
        for (int j = 0; j < 4; ++j)                                       \
            bf[j] = *reinterpret_cast<const shortx8*>(&BS[offB[j]]);      \
        _Pragma("unroll")                                                 \
        for (int i = 0; i < 4; ++i)                                       \
            _Pragma("unroll")                                             \
            for (int j = 0; j < 4; ++j)                                   \
                acc[i][j] = __builtin_amdgcn_mfma_f32_16x16x32_bf16(af[i], bf[j], acc[i][j], 0, 0, 0); \
    } while (0)

#define GEMM_PREAMBLE                                                     \
    const int tid  = threadIdx.x;                                         \
    const int lane = tid & 63;                                            \
    const int wave = tid >> 6;                                            \
    int bx, by, bz;                                                       \
    xcd_remap_gemm(bx, by, bz);                                           \
    const int row0 = by * 128, col0 = bx * 128;                           \
    const int wr = (wave >> 1) * 64, wc = (wave & 1) * 64;                \
    floatx4 acc[4][4] = {};                                               \
    const int p0 = tid,       r0s = p0 >> 2, k0s = (((p0 & 3) - (r0s >> 1)) & 3) * 8; \
    const int p1 = tid + 256, r1s = p1 >> 2, k1s = (((p1 & 3) - (r1s >> 1)) & 3) * 8; \
    const int am = (lane & 15);                                           \
    const size_t sA0 = (size_t)(row0 + r0s) * K + k0s;                    \
    const size_t sA1 = (size_t)(row0 + r1s) * K + k1s;                    \
    const size_t sB0 = (size_t)(col0 + r0s) * K + k0s;                    \
    const size_t sB1 = (size_t)(col0 + r1s) * K + k1s;                    \
    int offA[4], offB[4];                                                 \
    _Pragma("unroll")                                                     \
    for (int i = 0; i < 4; ++i) {                                         \
        const int Ra = wr + i * 16 + am;                                  \
        offA[i] = Ra * 32 + (((lane >> 4) + (Ra >> 1)) & 3) * 8;          \
        const int Rb = wc + i * 16 + am;                                  \
        offB[i] = Rb * 32 + (((lane >> 4) + (Rb >> 1)) & 3) * 8;          \
    }

// ---------- MFMA bf16 GEMM (2-phase dbuf). A [M][K]; Wt [N][K]. 128x128. ----------
template <int SILU, int HAS_RES, int OUT_BF16>
__global__ __launch_bounds__(256) void mfma_gemm(const unsigned short* __restrict__ A,
                                                 const unsigned short* __restrict__ Wt,
                                                 const float* __restrict__ bias,
                                                 const float* __restrict__ res,
                                                 void* __restrict__ outP,
                                                 int M, int N, int K) {
    __shared__ unsigned short As0[128 * 32], As1[128 * 32];
    __shared__ unsigned short Bs0[128 * 32], Bs1[128 * 32];
    GEMM_PREAMBLE

    GEMM_STAGE(As0, Bs0, 0);
    __syncthreads();
    for (int kt = 0; kt < K; kt += 64) {
        GEMM_STAGE(As1, Bs1, kt + 32);
        GEMM_COMPUTE(As0, Bs0);
        __syncthreads();
        if (kt + 64 < K) GEMM_STAGE(As0, Bs0, kt + 64);
        GEMM_COMPUTE(As1, Bs1);
        __syncthreads();
    }

    const int cq = (lane >> 4) * 4;
    const int cn = lane & 15;
#pragma unroll
    for (int i = 0; i < 4; ++i) {
#pragma unroll
        for (int j = 0; j < 4; ++j) {
            const int n = col0 + wc + j * 16 + cn;
            const float bb = bias[n];
#pragma unroll
            for (int r = 0; r < 4; ++r) {
                const int m = row0 + wr + i * 16 + cq + r;
                float v = acc[i][j][r] + bb;
                if (SILU) v = v / (1.0f + __expf(-v));
                if (HAS_RES) v += res[(size_t)m * N + n];
                if (OUT_BF16) ((unsigned short*)outP)[(size_t)m * N + n] = f2bf(v);
                else          ((float*)outP)[(size_t)m * N + n] = v;
            }
        }
    }
}

// ---------- Fused QKV GEMM: N=3072 over concatenated [3072][1024] weights ----------
__global__ __launch_bounds__(256) void mfma_gemm_qkv(const unsigned short* __restrict__ A,
                                                     const unsigned short* __restrict__ Wt,
                                                     const float* __restrict__ bq,
                                                     const float* __restrict__ bk,
                                                     const float* __restrict__ bv,
                                                     unsigned short* __restrict__ qb,
                                                     unsigned short* __restrict__ kb,
                                                     unsigned short* __restrict__ vtb) {
    const int K = D_MODEL, M = ROWS;
    __shared__ unsigned short As0[128 * 32], As1[128 * 32];
    __shared__ unsigned short Bs0[128 * 32], Bs1[128 * 32];
    GEMM_PREAMBLE

    GEMM_STAGE(As0, Bs0, 0);
    __syncthreads();
    for (int kt = 0; kt < K; kt += 64) {
        GEMM_STAGE(As1, Bs1, kt + 32);
        GEMM_COMPUTE(As0, Bs0);
        __syncthreads();
        if (kt + 64 < K) GEMM_STAGE(As0, Bs0, kt + 64);
        GEMM_COMPUTE(As1, Bs1);
        __syncthreads();
    }

    const int cq = (lane >> 4) * 4;
    const int cn = lane & 15;
    const int sel = col0 >> 10;                 // 0=Q 1=K 2=V (block-uniform)
    const int nbase = col0 & 1023;
    const float* bias = (sel == 0) ? bq : (sel == 1) ? bk : bv;
    // fold 1/sqrt(Dk) AND log2(e) into Q so attention uses a single v_exp_f32
    // (exact: softmax(S) == softmax-base-2(S*log2e)); 0.125 * 1.4426950408889634
    const float scl = (sel == 0) ? 0.18033688511157292f : 1.0f;
#pragma unroll
    for (int i = 0; i < 4; ++i) {
#pragma unroll
        for (int j = 0; j < 4; ++j) {
            const int n = nbase + wc + j * 16 + cn;
            const float bb = bias[n];
            if (sel == 2) {
                const int m0 = row0 + wr + i * 16 + cq;
                ushort4 o;
                o.x = f2bf(acc[i][j][0] + bb);
                o.y = f2bf(acc[i][j][1] + bb);
                o.z = f2bf(acc[i][j][2] + bb);
                o.w = f2bf(acc[i][j][3] + bb);
                *reinterpret_cast<ushort4*>(&vtb[(size_t)n * M + m0]) = o;
            } else {
                unsigned short* dst = (sel == 0) ? qb : kb;
#pragma unroll
                for (int r = 0; r < 4; ++r) {
                    const int m = row0 + wr + i * 16 + cq + r;
                    dst[(size_t)m * D_MODEL + n] = f2bf((acc[i][j][r] + bb) * scl);
                }
            }
        }
    }
}

// ---------- Split-K GEMM: z = K-slice; raw bf16 partials ----------
__global__ __launch_bounds__(256) void mfma_gemm_splitk(const unsigned short* __restrict__ A,
                                                        const unsigned short* __restrict__ Wt,
                                                        unsigned short* __restrict__ parts,
                                                        int M, int N, int KS) {
    __shared__ unsigned short As0[128 * 32], As1[128 * 32];
    __shared__ unsigned short Bs0[128 * 32], Bs1[128 * 32];
    const int K = KS * gridDim.z;
    GEMM_PREAMBLE
    const int kbeg = bz * KS;
    unsigned short* outp = parts + (size_t)bz * M * N;

    GEMM_STAGE(As0, Bs0, kbeg);
    __syncthreads();
    for (int kt = kbeg; kt < kbeg + KS; kt += 64) {
        GEMM_STAGE(As1, Bs1, kt + 32);
        GEMM_COMPUTE(As0, Bs0);
        __syncthreads();
        if (kt + 64 < kbeg + KS) GEMM_STAGE(As0, Bs0, kt + 64);
        GEMM_COMPUTE(As1, Bs1);
        __syncthreads();
    }

    const int cq = (lane >> 4) * 4;
    const int cn = lane & 15;
#pragma unroll
    for (int i = 0; i < 4; ++i)
#pragma unroll
        for (int j = 0; j < 4; ++j) {
            const int n = col0 + wc + j * 16 + cn;
#pragma unroll
            for (int r = 0; r < 4; ++r) {
                const int m = row0 + wr + i * 16 + cq + r;
                outp[(size_t)m * N + n] = f2bf(acc[i][j][r]);
            }
        }
}

// ---------- combine: out = p0 + p1 + bias + res ----------
__global__ __launch_bounds__(256) void combine_kernel(const unsigned short* __restrict__ p0,
                                                      const unsigned short* __restrict__ p1,
                                                      const float* __restrict__ bias,
                                                      const float* __restrict__ res,
                                                      float* __restrict__ out) {
    const size_t e0 = ((size_t)blockIdx.x * 256 + threadIdx.x) * 4;
    const int col = (int)(e0 & 1023);
    ushort4 a = *reinterpret_cast<const ushort4*>(&p0[e0]);
    ushort4 b = *reinterpret_cast<const ushort4*>(&p1[e0]);
    float4 r = *reinterpret_cast<const float4*>(&res[e0]);
    float4 o;
    o.x = bf2f(a.x) + bf2f(b.x) + bias[col + 0] + r.x;
    o.y = bf2f(a.y) + bf2f(b.y) + bias[col + 1] + r.y;
    o.z = bf2f(a.z) + bf2f(b.z) + bias[col + 2] + r.z;
    o.w = bf2f(a.w) + bf2f(b.w) + bias[col + 3] + r.w;
    *reinterpret_cast<float4*>(&out[e0]) = o;
}

// ---------- MFMA attention: R10 = swapped QK^T + packed Ps writes.
// mfma(bK, aQ) computes S^T with identical fragment reads (A/B frag layouts are
// symmetric for 16x16x32); C-layout then gives each thread 4 CONSECUTIVE k for one
// q (k=16jt+cq+r, q=wave*16+cn). exp -> v_cvt_pk_bf16_f32 pairs -> ONE ds_write_b64
// per jt (4 writes/subtile vs 16 scalar b16) into the SAME Ps[q][k] layout as before,
// so the PV side (aP b128 read, bV, oacc, output) is byte-identical to the proven
// code. Mask repacked as bytes (uchar4/jt). lsum: thread-scalar over k, reduced via
// shfl_xor(16,32), redistributed per-r via shfl(lt, cq+r).
__global__ __launch_bounds__(512) void attn_mfma(const unsigned short* __restrict__ Q,
                                                 const unsigned short* __restrict__ K,
                                                 const unsigned short* __restrict__ Vt,
                                                 const int* __restrict__ mask,
                                                 unsigned short* __restrict__ att) {
    const int tid  = threadIdx.x;
    const int lane = tid & 63;
    const int wave = tid >> 6;          // 0..7
    // plain chunked XCD remap (row-major decode: q-tile fastest -> chunk shares K/V)
    const int o = blockIdx.x + gridDim.x * (blockIdx.y + gridDim.y * blockIdx.z);
    const int nwg = gridDim.x * gridDim.y * gridDim.z;
    const int t = (o & 7) * (nwg >> 3) + (o >> 3);
    const int qx = t % gridDim.x;
    const int h  = (t / gridDim.x) % gridDim.y;
    const int b  = t / (gridDim.x * gridDim.y);
    const int q0 = qx * 128;

    __shared__ unsigned short Qs[128 * PST];
    __shared__ unsigned short Ks[2][64 * 64];
    __shared__ unsigned short Vs[2][64 * 64];
    __shared__ unsigned short Ps[128 * PST];
    __shared__ unsigned char mkb[128];

    const int am = lane & 15;
    const int aq = (lane >> 4) * 8;
    const int cq = (lane >> 4) * 4;
    const int cn = lane & 15;

    // stage Q tile (once, via VGPR; padded layout): 128 rows x 8 chunks = 1024 chunks
    for (int c = tid; c < 1024; c += 512) {
        const int r = c >> 3, off = (c & 7) * 8;
        *reinterpret_cast<uint4*>(&Qs[r * PST + off]) =
            *reinterpret_cast<const uint4*>(&Q[(size_t)(b * L_SEQ + q0 + r) * D_MODEL + h * D_K + off]);
    }

    // swizzled staging: LDS chunk p holds (row=p>>3, c8=((p&7)-row)&7); 512 chunks
    // per sub-tile, one per thread per sub-tile for each of Ks and Vs.
    const int p0 = tid, sr0 = p0 >> 3, sc0 = (((p0 & 7) - sr0) & 7) * 8;
    const unsigned short* K0 = K + (size_t)(b * L_SEQ + sr0) * D_MODEL + h * D_K + sc0;
    const unsigned short* V0 = Vt + (size_t)(h * D_K + sr0) * ROWS + b * L_SEQ + sc0;

    // fragment read offsets (loop-invariant): row R = t*16+am, chunk c8 = kt*4 + (lane>>4)
    int offF[2][4];
#pragma unroll
    for (int kt = 0; kt < 2; ++kt)
#pragma unroll
        for (int tt = 0; tt < 4; ++tt) {
            const int R = tt * 16 + am;
            offF[kt][tt] = R * 64 + (((kt * 4 + (lane >> 4)) + R) & 7) * 8;
        }

    __syncthreads();

    shortx8 aQ[2];
    aQ[0] = *reinterpret_cast<const shortx8*>(&Qs[(wave * 16 + am) * PST + aq]);
    aQ[1] = *reinterpret_cast<const shortx8*>(&Qs[(wave * 16 + am) * PST + 32 + aq]);

    floatx4 oacc[4] = {};
    float lsum = 0.0f;

    for (int j0 = 0; j0 < L_SEQ; j0 += 128) {
        __syncthreads();
        glds16(K0 + (size_t)j0 * D_MODEL,        &Ks[0][p0 * 8]);
        glds16(K0 + (size_t)(j0 + 64) * D_MODEL, &Ks[1][p0 * 8]);
        glds16(V0 + j0,      &Vs[0][p0 * 8]);
        glds16(V0 + j0 + 64, &Vs[1][p0 * 8]);
        if (tid < 128) mkb[tid] = (unsigned char)(mask[b * L_SEQ + j0 + tid] != 0);
        __syncthreads();

#pragma unroll
        for (int u = 0; u < 2; ++u) {
            // S^T = K x Q^T: sacc[jt][r] = S[k = u*64 + 16jt + cq + r][q = wave*16 + cn]
            floatx4 sacc[4] = {};
#pragma unroll
            for (int kt = 0; kt < 2; ++kt)
#pragma unroll
                for (int jt = 0; jt < 4; ++jt) {
                    shortx8 bK = *reinterpret_cast<const shortx8*>(&Ks[u][offF[kt][jt]]);
                    sacc[jt] = __builtin_amdgcn_mfma_f32_16x16x32_bf16(bK, aQ[kt], sacc[jt], 0, 0, 0);
                }
            // P = exp2(S^T) masked; pack k-pairs via v_cvt_pk_bf16_f32 -> ds_write_b64
            // into Ps[q][k] (same layout the PV reads expect).
#pragma unroll
            for (int jt = 0; jt < 4; ++jt) {
                uchar4 mb = *reinterpret_cast<const uchar4*>(&mkb[u * 64 + jt * 16 + cq]);
                float pv0 = mb.x ? __builtin_amdgcn_exp2f(sacc[jt][0]) : 0.0f;
                float pv1 = mb.y ? __builtin_amdgcn_exp2f(sacc[jt][1]) : 0.0f;
                float pv2 = mb.z ? __builtin_amdgcn_exp2f(sacc[jt][2]) : 0.0f;
                float pv3 = mb.w ? __builtin_amdgcn_exp2f(sacc[jt][3]) : 0.0f;
                lsum += (pv0 + pv1) + (pv2 + pv3);
                unsigned int pk0, pk1;
                asm("v_cvt_pk_bf16_f32 %0, %1, %2" : "=v"(pk0) : "v"(pv0), "v"(pv1));
                asm("v_cvt_pk_bf16_f32 %0, %1, %2" : "=v"(pk1) : "v"(pv2), "v"(pv3));
                uint2 w; w.x = pk0; w.y = pk1;
                *reinterpret_cast<uint2*>(&Ps[(wave * 16 + cn) * PST + jt * 16 + cq]) = w;
            }
            // O += P x V (wave-private Ps rows; DS in-order within wave -> safe reuse)
#pragma unroll
            for (int kt = 0; kt < 2; ++kt) {
                shortx8 aP = *reinterpret_cast<const shortx8*>(&Ps[(wave * 16 + am) * PST + kt * 32 + aq]);
#pragma unroll
                for (int dt = 0; dt < 4; ++dt) {
                    shortx8 bV = *reinterpret_cast<const shortx8*>(&Vs[u][offF[kt][dt]]);
                    oacc[dt] = __builtin_amdgcn_mfma_f32_16x16x32_bf16(aP, bV, oacc[dt], 0, 0, 0);
                }
            }
        }
    }

    // lsum: thread holds partial for q = wave*16+cn over its k; reduce across the
    // 4 lanes sharing cn (bits 4,5), then redistribute to the oacc layout (q=cq+r).
    float lt = lsum;
    lt += __shfl_xor(lt, 16);
    lt += __shfl_xor(lt, 32);
    float linv[4];
#pragma unroll
    for (int r = 0; r < 4; ++r)
        linv[r] = 1.0f / __shfl(lt, cq + r);

#pragma unroll
    for (int dt = 0; dt < 4; ++dt)
#pragma unroll
        for (int r = 0; r < 4; ++r) {
            att[(size_t)(b * L_SEQ + q0 + wave * 16 + cq + r) * D_MODEL + h * D_K + dt * 16 + cn] =
                f2bf(oacc[dt][r] * linv[r]);
        }
}

extern "C" void kernel_launch(void* const* d_in, const int* in_sizes, int n_in,
                              void* d_out, int out_size, void* d_ws, size_t ws_size,
                              hipStream_t stream) {
    const float* x     = (const float*)d_in[0];
    const int*   mask  = (const int*)d_in[1];
    const float* ln1_g = (const float*)d_in[2];
    const float* ln1_b = (const float*)d_in[3];
    const float* Wq    = (const float*)d_in[4];
    const float* bq    = (const float*)d_in[5];
    const float* Wk    = (const float*)d_in[6];
    const float* bk    = (const float*)d_in[7];
    const float* Wv    = (const float*)d_in[8];
    const float* bv    = (const float*)d_in[9];
    const float* Wo    = (const float*)d_in[10];
    const float* bo    = (const float*)d_in[11];
    const float* ln2_g = (const float*)d_in[12];
    const float* ln2_b = (const float*)d_in[13];
    const float* W1    = (const float*)d_in[14];
    const float* b1    = (const float*)d_in[15];
    const float* W2    = (const float*)d_in[16];
    const float* b2    = (const float*)d_in[17];
    float* out = (float*)d_out;

    float* ws = (float*)d_ws;
    const size_t SZ = (size_t)ROWS * D_MODEL;  // 4M elements; fp32 slot = 16 MB

    unsigned short* nx  = (unsigned short*)(ws + 0 * SZ);   // 0-8 MB: LN1/LN2 out bf16
    unsigned short* qb  = (unsigned short*)(ws + 1 * SZ);   // 16-24: Q bf16 (pre-scaled)
    unsigned short* kb  = qb + SZ;                          // 24-32: K bf16
    unsigned short* vtb = (unsigned short*)(ws + 2 * SZ);   // 32-40: V^T bf16
    unsigned short* attb = vtb + SZ;                        // 40-48: att bf16
    float* x1  = out;                                       // residual stream in d_out
    unsigned short* nx2 = nx;                               // slot0 reuse
    unsigned short* h = (unsigned short*)(ws + 2 * SZ);     // 32-64: FFN hidden bf16
    unsigned short* parts = (unsigned short*)(ws + 0 * SZ); // 0-16: FFN2 split-K partials

    unsigned short* WqkvT = (unsigned short*)(ws + 4 * SZ); // 64-70: concat [3072][1024]
    unsigned short* WqT = WqkvT;
    unsigned short* WkT = WqkvT + (size_t)D_MODEL * D_MODEL;
    unsigned short* WvT = WkT + (size_t)D_MODEL * D_MODEL;
    unsigned short* WoT = WvT + (size_t)D_MODEL * D_MODEL;  // 70-72
    unsigned short* W1T = (unsigned short*)(ws + 1 * SZ);   // 16-24 (qb/kb dead after attn)
    unsigned short* W2T = W1T + (size_t)D_MODEL * FFN_DIM;  // 24-32

    ln_kernel<<<ROWS, 256, 0, stream>>>(x, ln1_g, ln1_b, nx);

    transpose_cast4<<<dim3(32, 32, 4), 256, 0, stream>>>(Wq, Wk, Wv, Wo, WqT, WkT, WvT, WoT);

    mfma_gemm_qkv<<<dim3(3072 / 128, ROWS / 128), 256, 0, stream>>>(
        nx, WqkvT, bq, bk, bv, qb, kb, vtb);

    attn_mfma<<<dim3(L_SEQ / 128, N_HEAD, B_SZ), 512, 0, stream>>>(qb, kb, vtb, mask, attb);

    transpose_cast<<<dim3(FFN_DIM / 32, D_MODEL / 32), 256, 0, stream>>>(W1, W1T, D_MODEL, FFN_DIM);
    transpose_cast<<<dim3(D_MODEL / 32, FFN_DIM / 32), 256, 0, stream>>>(W2, W2T, FFN_DIM, D_MODEL);

    mfma_gemm<0, 1, 0><<<dim3(D_MODEL / 128, ROWS / 128), 256, 0, stream>>>(
        attb, WoT, bo, x, x1, ROWS, D_MODEL, D_MODEL);

    ln_kernel<<<ROWS, 256, 0, stream>>>(x1, ln2_g, ln2_b, nx2);

    mfma_gemm<1, 0, 1><<<dim3(FFN_DIM / 128, ROWS / 128), 256, 0, stream>>>(
        nx2, W1T, b1, nullptr, h, ROWS, FFN_DIM, D_MODEL);

    mfma_gemm_splitk<<<dim3(D_MODEL / 128, ROWS / 128, 2), 256, 0, stream>>>(
        h, W2T, parts, ROWS, D_MODEL, FFN_DIM / 2);
    combine_kernel<<<(ROWS * D_MODEL) / 1024, 256, 0, stream>>>(
        parts, parts + SZ, b2, x1, out);
}